// Round 4
// baseline (702.081 us; speedup 1.0000x reference)
//
#include <hip/hip_runtime.h>
#include <cstdint>
#include <cstddef>

#define DD 128
#define LSTMH 256
#define ZG 1024
#define LROWS 128

typedef __attribute__((ext_vector_type(8))) short short8v;
typedef __attribute__((ext_vector_type(4))) float float4v;

static inline int cdiv_(int a, int b) { return (a + b - 1) / b; }

__device__ __forceinline__ float sigm_(float x) { return 1.f / (1.f + __expf(-x)); }
__device__ __forceinline__ float tanh_(float x) {
  float e = __expf(-2.f * fabsf(x));
  float r = (1.f - e) / (1.f + e);
  return copysignf(r, x);
}

__device__ __forceinline__ unsigned short f2bf(float f) {
  uint32_t u = __float_as_uint(f);
  u += 0x7fffu + ((u >> 16) & 1u);
  return (unsigned short)(u >> 16);
}
__device__ __forceinline__ float bflo(uint32_t u) { return __uint_as_float(u << 16); }
__device__ __forceinline__ float bfhi(uint32_t u) { return __uint_as_float(u & 0xffff0000u); }
__device__ __forceinline__ float bfu(unsigned short u) { return __uint_as_float((uint32_t)u << 16); }

// ---------------- weight conversion ----------------
__global__ void cvt_direct(const float* __restrict__ W, unsigned short* __restrict__ o, int n) {
  int i = blockIdx.x * 256 + threadIdx.x;
  if (i < n) o[i] = f2bf(W[i]);
}

// W[K][M] row-major -> o[M][K] bf16
__global__ void cvt_transpose(const float* __restrict__ W, unsigned short* __restrict__ o,
                              int K, int M) {
  int i = blockIdx.x * 256 + threadIdx.x;
  if (i >= K * M) return;
  int m = i / K, k = i - m * K;
  o[i] = f2bf(W[(size_t)k * M + m]);
}

// bias concat + lstm bias sums
__global__ void prep_small(const float* g1bl, const float* g1br, const float* g2bl,
                           const float* g2br, const float* bres, const float* l1bih,
                           const float* l1bhh, const float* l2bih, const float* l2bhh,
                           float* bcat1, float* bcat2, float* bsum1, float* bsum2) {
  int t = blockIdx.x * 256 + threadIdx.x;
  if (t < 256) bcat1[t] = t < 128 ? g1bl[t] : g1br[t - 128];
  if (t < 384) bcat2[t] = t < 128 ? g2bl[t] : (t < 256 ? g2br[t - 128] : bres[t - 256]);
  if (t < ZG) { bsum1[t] = l1bih[t] + l1bhh[t]; bsum2[t] = l2bih[t] + l2bhh[t]; }
}

// ---------------- input embedding + W_in GEMV (K=33) -> bf16 ----------------
__global__ __launch_bounds__(128) void embed_in(
    const int* __restrict__ labels, const int* __restrict__ types,
    const float* __restrict__ nf, const float* __restrict__ embL,
    const float* __restrict__ embT, const float* __restrict__ W,
    const float* __restrict__ b, unsigned short* __restrict__ x, int N) {
  int n = blockIdx.x;
  if (n >= N) return;
  int t = threadIdx.x;
  __shared__ float f[33];
  if (t < 16) f[t] = embL[labels[n] * 16 + t];
  else if (t < 32) f[t] = embT[types[n] * 16 + (t - 16)];
  else if (t == 32) f[32] = nf[n];
  __syncthreads();
  float acc = b[t];
#pragma unroll
  for (int k = 0; k < 33; ++k) acc += f[k] * W[k * DD + t];
  x[(size_t)n * DD + t] = f2bf(acc);
}

// ---------------- CSR build ----------------
__global__ void count_deg(const int* __restrict__ ei, int* __restrict__ deg, int E_, int N_) {
  int i = blockIdx.x * 256 + threadIdx.x;
  if (i < E_) atomicAdd(&deg[ei[E_ + i]], 1);
  else if (i < E_ + N_) atomicAdd(&deg[i - E_], 1);
}

__global__ __launch_bounds__(256) void scan1(const int* __restrict__ deg, int* __restrict__ offs,
                                             int* __restrict__ partials, int N_) {
  __shared__ int buf[2][256];
  int tid = threadIdx.x;
  int i = blockIdx.x * 256 + tid;
  int v = (i < N_) ? deg[i] : 0;
  buf[0][tid] = v;
  __syncthreads();
  int cur = 0;
#pragma unroll
  for (int d = 1; d < 256; d <<= 1) {
    int xv = buf[cur][tid];
    if (tid >= d) xv += buf[cur][tid - d];
    buf[cur ^ 1][tid] = xv;
    cur ^= 1;
    __syncthreads();
  }
  int incl = buf[cur][tid];
  if (i < N_) offs[i] = incl - v;
  if (tid == 255) partials[blockIdx.x] = incl;
}

__global__ __launch_bounds__(256) void scan2(int* __restrict__ partials, int* __restrict__ offs,
                                             int nb, int N_) {
  __shared__ int buf[2][256];
  int tid = threadIdx.x;
  int v = (tid < nb) ? partials[tid] : 0;
  buf[0][tid] = v;
  __syncthreads();
  int cur = 0;
#pragma unroll
  for (int d = 1; d < 256; d <<= 1) {
    int xv = buf[cur][tid];
    if (tid >= d) xv += buf[cur][tid - d];
    buf[cur ^ 1][tid] = xv;
    cur ^= 1;
    __syncthreads();
  }
  int incl = buf[cur][tid];
  if (tid < nb) partials[tid] = incl - v;
  if (tid == 255) offs[N_] = incl;
}

__global__ void scan3(int* __restrict__ offs, const int* __restrict__ partials, int N_) {
  int i = blockIdx.x * 256 + threadIdx.x;
  if (i < N_) offs[i] += partials[blockIdx.x];
}

__global__ void fill_csr(const int* __restrict__ ei, const int* __restrict__ offs,
                         int* __restrict__ cursor, int* __restrict__ csr, int E_, int N_) {
  int i = blockIdx.x * 256 + threadIdx.x;
  int s, d;
  if (i < E_) { s = ei[i]; d = ei[E_ + i]; }
  else if (i < E_ + N_) { s = d = i - E_; }
  else return;
  int pos = offs[d] + atomicAdd(&cursor[d], 1);
  csr[pos] = s;
}

// ---------------- graph ranges ----------------
__global__ void graph_ranges(const int* __restrict__ bids, int* __restrict__ gstart,
                             float* __restrict__ invcnt, int N_, int G_) {
  int t = threadIdx.x;
  if (t <= G_) {
    int lo = 0, hi = N_;
    while (lo < hi) { int mid = (lo + hi) >> 1; if (bids[mid] < t) lo = mid + 1; else hi = mid; }
    gstart[t] = lo;
  }
  __syncthreads();
  if (t < G_) {
    int c = gstart[t + 1] - gstart[t];
    invcnt[t] = (c > 0) ? 1.f / (float)c : 0.f;
  }
}

// ---------------- bf16 MFMA GEMM: C[M,Ncols] bf16 = A[M,K]bf16 @ B'[Ncols,K]^T + bias
__global__ __launch_bounds__(256) void gemm_bf16(
    const unsigned short* __restrict__ A, const unsigned short* __restrict__ Bp,
    const float* __restrict__ bias, unsigned short* __restrict__ C, int M, int K, int Ncols) {
  __shared__ unsigned short As[128 * 40];
  __shared__ unsigned short Bs[128 * 40];
  int tid = threadIdx.x;
  int lane = tid & 63;
  int wid = tid >> 6;
  int rowBase = blockIdx.y * 128, colBase = blockIdx.x * 128;
  int wr = (wid >> 1) * 64, wc = (wid & 1) * 64;
  int fr = lane & 15, fg = lane >> 4;
  float4v acc[4][4];
#pragma unroll
  for (int i = 0; i < 4; ++i)
#pragma unroll
    for (int j = 0; j < 4; ++j) acc[i][j] = (float4v){0.f, 0.f, 0.f, 0.f};

  int sr = tid >> 2;
  int sc = tid & 3;
  int off_lo = (sc < 2) ? 32 * sc : 32 * sc - 56;

  for (int k0 = 0; k0 < K; k0 += 32) {
#pragma unroll
    for (int it = 0; it < 2; ++it) {
      int r = it * 64 + sr;
      uint4 va = make_uint4(0u, 0u, 0u, 0u);
      if (rowBase + r < M)
        va = *(const uint4*)(A + (size_t)(rowBase + r) * K + k0 + sc * 8);
      char* arow = (char*)(As + r * 40);
      *(uint2*)(arow + off_lo) = make_uint2(va.x, va.y);
      *(uint2*)(arow + off_lo + 16) = make_uint2(va.z, va.w);
      uint4 vb = *(const uint4*)(Bp + (size_t)(colBase + r) * K + k0 + sc * 8);
      char* brow = (char*)(Bs + r * 40);
      *(uint2*)(brow + off_lo) = make_uint2(vb.x, vb.y);
      *(uint2*)(brow + off_lo + 16) = make_uint2(vb.z, vb.w);
    }
    __syncthreads();
    short8v af[4], bfv[4];
#pragma unroll
    for (int i = 0; i < 4; ++i)
      af[i] = *(const short8v*)((const char*)As + (wr + 16 * i + fr) * 80 + fg * 16);
#pragma unroll
    for (int j = 0; j < 4; ++j)
      bfv[j] = *(const short8v*)((const char*)Bs + (wc + 16 * j + fr) * 80 + fg * 16);
#pragma unroll
    for (int i = 0; i < 4; ++i)
#pragma unroll
      for (int j = 0; j < 4; ++j)
        acc[i][j] = __builtin_amdgcn_mfma_f32_16x16x32_bf16(af[i], bfv[j], acc[i][j], 0, 0, 0);
    __syncthreads();
  }
#pragma unroll
  for (int j = 0; j < 4; ++j) {
    int gc = colBase + wc + 16 * j + fr;
    float bv = bias[gc];
#pragma unroll
    for (int i = 0; i < 4; ++i) {
      int gr0 = rowBase + wr + 16 * i + fg * 4;
#pragma unroll
      for (int rg = 0; rg < 4; ++rg) {
        int gr = gr0 + rg;
        if (gr < M) C[(size_t)gr * Ncols + gc] = f2bf(acc[i][j][rg] + bv);
      }
    }
  }
}

// ---------------- GATv2 aggregation: 1 wave/node, 2 edges in flight, bf16 gathers --------
__global__ __launch_bounds__(256) void gat_agg(
    const unsigned short* __restrict__ xlr, int stride,
    const int* __restrict__ csr, const int* __restrict__ offs,
    const float* __restrict__ att, const float* __restrict__ bias,
    float* __restrict__ out, int N) {
  int wid = (blockIdx.x * 256 + threadIdx.x) >> 6;
  if (wid >= N) return;
  int lane = threadIdx.x & 63;
  int half = lane >> 5, hl = lane & 31;
  int h = hl >> 3;
  float4 a4 = *(const float4*)&att[h * 32 + (hl & 7) * 4];
  uint2 ur = *(const uint2*)(xlr + (size_t)wid * stride + 128 + hl * 4);
  float r0 = bflo(ur.x), r1 = bfhi(ur.x), r2 = bflo(ur.y), r3 = bfhi(ur.y);
  float m = -1e30f, L = 0.f, s0 = 0.f, s1 = 0.f, s2 = 0.f, s3 = 0.f;
  int js = offs[wid], je = offs[wid + 1];
  for (int j = js + half; j < je; j += 2) {
    int s = csr[j];
    uint2 u = *(const uint2*)(xlr + (size_t)s * stride + hl * 4);
    float x0 = bflo(u.x), x1 = bfhi(u.x), x2 = bflo(u.y), x3 = bfhi(u.y);
    float v0 = r0 + x0; v0 = v0 > 0.f ? v0 : 0.2f * v0;
    float v1 = r1 + x1; v1 = v1 > 0.f ? v1 : 0.2f * v1;
    float v2 = r2 + x2; v2 = v2 > 0.f ? v2 : 0.2f * v2;
    float v3 = r3 + x3; v3 = v3 > 0.f ? v3 : 0.2f * v3;
    float p = a4.x * v0 + a4.y * v1 + a4.z * v2 + a4.w * v3;
    p += __shfl_xor(p, 1); p += __shfl_xor(p, 2); p += __shfl_xor(p, 4);
    float mn = fmaxf(m, p);
    float ea = __expf(p - mn);
    float es = __expf(m - mn);
    L = L * es + ea;
    s0 = s0 * es + ea * x0;
    s1 = s1 * es + ea * x1;
    s2 = s2 * es + ea * x2;
    s3 = s3 * es + ea * x3;
    m = mn;
  }
  float mo = __shfl_xor(m, 32), Lo = __shfl_xor(L, 32);
  float t0 = __shfl_xor(s0, 32), t1 = __shfl_xor(s1, 32);
  float t2 = __shfl_xor(s2, 32), t3 = __shfl_xor(s3, 32);
  float mn = fmaxf(m, mo);
  float e0 = __expf(m - mn), e1 = __expf(mo - mn);
  L = L * e0 + Lo * e1;
  s0 = s0 * e0 + t0 * e1;
  s1 = s1 * e0 + t1 * e1;
  s2 = s2 * e0 + t2 * e1;
  s3 = s3 * e0 + t3 * e1;
  if (half == 0) {
    float inv = 1.f / L;
    float4 b4 = *(const float4*)&bias[hl * 4];
    float4 o4;
    o4.x = s0 * inv + b4.x;
    o4.y = s1 * inv + b4.y;
    o4.z = s2 * inv + b4.z;
    o4.w = s3 * inv + b4.w;
    *(float4*)&out[(size_t)wid * DD + hl * 4] = o4;
  }
}

// ---------------- GraphNorm stats ----------------
__global__ __launch_bounds__(256) void gn_stats2(const float* __restrict__ x,
                                                 const int* __restrict__ bids,
                                                 float* __restrict__ gsum,
                                                 float* __restrict__ gsq, int N) {
  int base = blockIdx.x * 128;
  int ch = threadIdx.x & 127;
  int sub = threadIdx.x >> 7;
  int end = base + 128 < N ? base + 128 : N;
  int curg = -1;
  float s = 0.f, q = 0.f;
  for (int r = base + sub; r < end; r += 2) {
    int g = bids[r];
    if (g != curg) {
      if (curg >= 0) {
        atomicAdd(&gsum[curg * DD + ch], s);
        atomicAdd(&gsq[curg * DD + ch], q);
      }
      curg = g; s = 0.f; q = 0.f;
    }
    float v = x[(size_t)r * DD + ch];
    s += v; q += v * v;
  }
  if (curg >= 0) {
    atomicAdd(&gsum[curg * DD + ch], s);
    atomicAdd(&gsq[curg * DD + ch], q);
  }
}

// ---------------- GraphNorm apply + ELU (+residual bf16) -> bf16 ----------------
template <bool ADDRES>
__global__ void gn_apply(const float* __restrict__ xin, unsigned short* __restrict__ xout,
                         const unsigned short* __restrict__ res, int resStride,
                         const int* __restrict__ bids, const float* __restrict__ gsum,
                         const float* __restrict__ gsq, const float* __restrict__ invcnt,
                         const float* __restrict__ w, const float* __restrict__ b,
                         const float* __restrict__ ms, int N) {
  int idx = blockIdx.x * 256 + threadIdx.x;
  if (idx >= N * DD) return;
  int n = idx >> 7, ch = idx & 127;
  int g = bids[n];
  float ic = invcnt[g];
  float mean = gsum[g * DD + ch] * ic;
  float ex2 = gsq[g * DD + ch] * ic;
  float mm = mean * ms[ch];
  float var = ex2 - mm * (2.f * mean - mm);
  float v = (xin[idx] - mm) * rsqrtf(var + 1e-5f) * w[ch] + b[ch];
  if (ADDRES) v += bfu(res[(size_t)n * resStride + ch]);
  v = v > 0.f ? v : (__expf(v) - 1.f);
  xout[idx] = f2bf(v);
}

// ---------------- fully fused dual LSTM: x2 -> h1 (LDS) -> h2 (global bf16) -------------
// Block: 512 threads (8 waves = 2 row-groups x 4 col-groups), 128 rows.
// Gate cols per 64-ch chunk: 4 groups of 48 = [i(16ch) | g | o] per col-wave.
// f-gate dead (c0 = 0). W stays in L2; A read once; h1 never leaves LDS.
__global__ __launch_bounds__(512) void lstm_dual(
    const unsigned short* __restrict__ A, const unsigned short* __restrict__ W1,
    const unsigned short* __restrict__ W2, const float* __restrict__ bsum1,
    const float* __restrict__ bsum2, unsigned short* __restrict__ H2, int M) {
  __shared__ char As_[LROWS * 272];   // x2 frag layout: 4 chunks x 64B + 16B pad
  __shared__ char H1_[LROWS * 528];   // h1 frag layout: 8 chunks x 64B + 16B pad
  __shared__ char Ws_[192 * 80];      // one 32-k slab of 192 gate rows
  int tid = threadIdx.x;
  int lane = tid & 63;
  int wid = tid >> 6;
  int wr = wid >> 2;        // row-group: 64 rows
  int wc = wid & 3;         // col-group: 16 channels (i,g,o)
  int fr = lane & 15, fg = lane >> 4;
  int rowBase = blockIdx.x * LROWS;

  // per-thread W staging descriptors (rows fixed across k-steps)
  const int goff[3] = {0, 512, 768};
  int r1 = tid >> 2, sc1 = tid & 3;
  int w1g = r1 / 48, r3a = r1 - w1g * 48;
  int growA = goff[r3a >> 4] + 16 * w1g + (r3a & 15);   // + hc0 at use
  int offA = (sc1 < 2) ? 32 * sc1 : 32 * sc1 - 56;
  int ldsA = r1 * 80 + offA;
  int t2 = 512 + tid;
  int r2 = t2 >> 2, sc2 = t2 & 3;
  int w2g = r2 / 48, r3b = r2 - w2g * 48;
  int growB = goff[r3b >> 4] + 16 * w2g + (r3b & 15);
  int offB = (sc2 < 2) ? 32 * sc2 : 32 * sc2 - 56;
  int ldsB = r2 * 80 + offB;
  bool doB = tid < 256;

  // ---- stage x2 (128 x 128) into As_ ----
#pragma unroll
  for (int q = 0; q < 4; ++q) {
    int t = tid + 512 * q;
    int r = t >> 4, kk = t & 15;
    int c = kk >> 2, sc = kk & 3;
    uint4 va = make_uint4(0u, 0u, 0u, 0u);
    if (rowBase + r < M)
      va = *(const uint4*)(A + (size_t)(rowBase + r) * DD + c * 32 + sc * 8);
    int off = (sc < 2) ? 32 * sc : 32 * sc - 56;
    char* p = As_ + r * 272 + c * 64;
    *(uint2*)(p + off) = make_uint2(va.x, va.y);
    *(uint2*)(p + off + 16) = make_uint2(va.z, va.w);
  }

  int chBase = 16 * wc + fr;  // channel within 64-chunk for this lane

  // ================= layer 1: K = 128 =================
#pragma unroll
  for (int chunk = 0; chunk < 4; ++chunk) {
    int hc0 = chunk * 64;
    float4v acc[4][3];
#pragma unroll
    for (int i = 0; i < 4; ++i)
#pragma unroll
      for (int j = 0; j < 3; ++j) acc[i][j] = (float4v){0.f, 0.f, 0.f, 0.f};
#pragma unroll
    for (int ks = 0; ks < 4; ++ks) {
      int k0 = ks * 32;
      {
        uint4 v = *(const uint4*)(W1 + (size_t)(growA + hc0) * DD + k0 + sc1 * 8);
        *(uint2*)(Ws_ + ldsA) = make_uint2(v.x, v.y);
        *(uint2*)(Ws_ + ldsA + 16) = make_uint2(v.z, v.w);
        if (doB) {
          uint4 u = *(const uint4*)(W1 + (size_t)(growB + hc0) * DD + k0 + sc2 * 8);
          *(uint2*)(Ws_ + ldsB) = make_uint2(u.x, u.y);
          *(uint2*)(Ws_ + ldsB + 16) = make_uint2(u.z, u.w);
        }
      }
      __syncthreads();
      short8v af[4], bfv[3];
#pragma unroll
      for (int i = 0; i < 4; ++i)
        af[i] = *(const short8v*)(As_ + (64 * wr + 16 * i + fr) * 272 + ks * 64 + fg * 16);
#pragma unroll
      for (int j = 0; j < 3; ++j)
        bfv[j] = *(const short8v*)(Ws_ + (48 * wc + 16 * j + fr) * 80 + fg * 16);
#pragma unroll
      for (int i = 0; i < 4; ++i)
#pragma unroll
        for (int j = 0; j < 3; ++j)
          acc[i][j] = __builtin_amdgcn_mfma_f32_16x16x32_bf16(af[i], bfv[j], acc[i][j], 0, 0, 0);
      __syncthreads();
    }
    // epilogue -> h1 in LDS (frag layout for layer-2 A operand)
    int ch = hc0 + chBase;
    float bi = bsum1[ch], bg = bsum1[512 + ch], bo = bsum1[768 + ch];
    int c2 = ch >> 5, kk = ch & 31;
    int boff = c2 * 64 + ((kk & 15) >> 2) * 16 + (kk >> 4) * 8 + (kk & 3) * 2;
#pragma unroll
    for (int i = 0; i < 4; ++i) {
#pragma unroll
      for (int rg = 0; rg < 4; ++rg) {
        int row = 64 * wr + 16 * i + 4 * fg + rg;
        float iv = acc[i][0][rg] + bi;
        float gv = acc[i][1][rg] + bg;
        float ov = acc[i][2][rg] + bo;
        float c = sigm_(iv) * tanh_(gv);
        *(unsigned short*)(H1_ + row * 528 + boff) = f2bf(sigm_(ov) * tanh_(c));
      }
    }
  }

  // ================= layer 2: K = 256 =================
#pragma unroll
  for (int chunk = 0; chunk < 4; ++chunk) {
    int hc0 = chunk * 64;
    float4v acc[4][3];
#pragma unroll
    for (int i = 0; i < 4; ++i)
#pragma unroll
      for (int j = 0; j < 3; ++j) acc[i][j] = (float4v){0.f, 0.f, 0.f, 0.f};
#pragma unroll
    for (int ks = 0; ks < 8; ++ks) {
      int k0 = ks * 32;
      {
        uint4 v = *(const uint4*)(W2 + (size_t)(growA + hc0) * LSTMH + k0 + sc1 * 8);
        *(uint2*)(Ws_ + ldsA) = make_uint2(v.x, v.y);
        *(uint2*)(Ws_ + ldsA + 16) = make_uint2(v.z, v.w);
        if (doB) {
          uint4 u = *(const uint4*)(W2 + (size_t)(growB + hc0) * LSTMH + k0 + sc2 * 8);
          *(uint2*)(Ws_ + ldsB) = make_uint2(u.x, u.y);
          *(uint2*)(Ws_ + ldsB + 16) = make_uint2(u.z, u.w);
        }
      }
      __syncthreads();
      short8v af[4], bfv[3];
#pragma unroll
      for (int i = 0; i < 4; ++i)
        af[i] = *(const short8v*)(H1_ + (64 * wr + 16 * i + fr) * 528 + ks * 64 + fg * 16);
#pragma unroll
      for (int j = 0; j < 3; ++j)
        bfv[j] = *(const short8v*)(Ws_ + (48 * wc + 16 * j + fr) * 80 + fg * 16);
#pragma unroll
      for (int i = 0; i < 4; ++i)
#pragma unroll
        for (int j = 0; j < 3; ++j)
          acc[i][j] = __builtin_amdgcn_mfma_f32_16x16x32_bf16(af[i], bfv[j], acc[i][j], 0, 0, 0);
      __syncthreads();
    }
    int ch = hc0 + chBase;
    float bi = bsum2[ch], bg = bsum2[512 + ch], bo = bsum2[768 + ch];
#pragma unroll
    for (int i = 0; i < 4; ++i) {
#pragma unroll
      for (int rg = 0; rg < 4; ++rg) {
        int row = 64 * wr + 16 * i + 4 * fg + rg;
        if (rowBase + row < M) {
          float iv = acc[i][0][rg] + bi;
          float gv = acc[i][1][rg] + bg;
          float ov = acc[i][2][rg] + bo;
          float c = sigm_(iv) * tanh_(gv);
          H2[(size_t)(rowBase + row) * LSTMH + ch] = f2bf(sigm_(ov) * tanh_(c));
        }
      }
    }
  }
}

// ---------------- LayerNorm + mean pool: 1 wave per 8 rows, register pooling ----------
__global__ __launch_bounds__(256) void ln_pool2(
    const unsigned short* __restrict__ h2, const int* __restrict__ bids,
    const float* __restrict__ lnw, const float* __restrict__ lnb,
    const float* __restrict__ invcnt, float* __restrict__ pooled, int N) {
  int wave = (blockIdx.x * 256 + threadIdx.x) >> 6;
  int lane = threadIdx.x & 63;
  int r0 = wave * 8;
  if (r0 >= N) return;
  float4 w4 = *(const float4*)&lnw[lane * 4];
  float4 b4 = *(const float4*)&lnb[lane * 4];
  float p0 = 0.f, p1 = 0.f, p2 = 0.f, p3 = 0.f;
  int curg = bids[r0];
  int rend = r0 + 8 < N ? r0 + 8 : N;
  for (int r = r0; r < rend; ++r) {
    int g = bids[r];
    if (g != curg) {
      float ic = invcnt[curg];
      atomicAdd(&pooled[curg * LSTMH + lane * 4 + 0], p0 * ic);
      atomicAdd(&pooled[curg * LSTMH + lane * 4 + 1], p1 * ic);
      atomicAdd(&pooled[curg * LSTMH + lane * 4 + 2], p2 * ic);
      atomicAdd(&pooled[curg * LSTMH + lane * 4 + 3], p3 * ic);
      p0 = p1 = p2 = p3 = 0.f;
      curg = g;
    }
    uint2 u = *(const uint2*)(h2 + (size_t)r * LSTMH + lane * 4);
    float v0 = bflo(u.x), v1 = bfhi(u.x), v2 = bflo(u.y), v3 = bfhi(u.y);
    float s = v0 + v1 + v2 + v3;
    float q = v0 * v0 + v1 * v1 + v2 * v2 + v3 * v3;
#pragma unroll
    for (int d = 1; d < 64; d <<= 1) { s += __shfl_xor(s, d); q += __shfl_xor(q, d); }
    float mu = s * (1.f / 256.f);
    float var = q * (1.f / 256.f) - mu * mu;
    float rs = rsqrtf(var + 1e-5f);
    p0 += w4.x * (v0 - mu) * rs + b4.x;
    p1 += w4.y * (v1 - mu) * rs + b4.y;
    p2 += w4.z * (v2 - mu) * rs + b4.z;
    p3 += w4.w * (v3 - mu) * rs + b4.w;
  }
  float ic = invcnt[curg];
  atomicAdd(&pooled[curg * LSTMH + lane * 4 + 0], p0 * ic);
  atomicAdd(&pooled[curg * LSTMH + lane * 4 + 1], p1 * ic);
  atomicAdd(&pooled[curg * LSTMH + lane * 4 + 2], p2 * ic);
  atomicAdd(&pooled[curg * LSTMH + lane * 4 + 3], p3 * ic);
}

// ---------------- FC + log_softmax ----------------
__global__ __launch_bounds__(64) void fc_lsm(const float* __restrict__ pooled,
                                             const float* __restrict__ W,
                                             const float* __restrict__ b, float* __restrict__ out) {
  int g = blockIdx.x;
  int t = threadIdx.x;
  float l0 = 0.f, l1 = 0.f, l2 = 0.f, l3 = 0.f;
  for (int k = t; k < LSTMH; k += 64) {
    float p = pooled[g * LSTMH + k];
    l0 += p * W[k * 4 + 0];
    l1 += p * W[k * 4 + 1];
    l2 += p * W[k * 4 + 2];
    l3 += p * W[k * 4 + 3];
  }
#pragma unroll
  for (int d = 1; d < 64; d <<= 1) {
    l0 += __shfl_xor(l0, d); l1 += __shfl_xor(l1, d);
    l2 += __shfl_xor(l2, d); l3 += __shfl_xor(l3, d);
  }
  if (t == 0) {
    float z[4] = {l0 + b[0], l1 + b[1], l2 + b[2], l3 + b[3]};
    float mx = fmaxf(fmaxf(z[0], z[1]), fmaxf(z[2], z[3]));
    float sum = __expf(z[0] - mx) + __expf(z[1] - mx) + __expf(z[2] - mx) + __expf(z[3] - mx);
    float ls = logf(sum);
#pragma unroll
    for (int o = 0; o < 4; ++o) out[g * 4 + o] = z[o] - mx - ls;
  }
}

// ---------------- host launch ----------------
extern "C" void kernel_launch(void* const* d_in, const int* in_sizes, int n_in,
                              void* d_out, int out_size, void* d_ws, size_t ws_size,
                              hipStream_t stream) {
  const int* node_labels = (const int*)d_in[0];
  const int* node_types = (const int*)d_in[1];
  const float* node_feat = (const float*)d_in[2];
  const int* edge_index = (const int*)d_in[3];
  const int* batch_ids = (const int*)d_in[4];
  const float* emb_label = (const float*)d_in[5];
  const float* emb_type = (const float*)d_in[6];
  const float* W_in = (const float*)d_in[7];
  const float* b_in = (const float*)d_in[8];
  const float* g1_Wl = (const float*)d_in[9];
  const float* g1_bl = (const float*)d_in[10];
  const float* g1_Wr = (const float*)d_in[11];
  const float* g1_br = (const float*)d_in[12];
  const float* g1_att = (const float*)d_in[13];
  const float* g1_bias = (const float*)d_in[14];
  const float* gn1_w = (const float*)d_in[15];
  const float* gn1_b = (const float*)d_in[16];
  const float* gn1_ms = (const float*)d_in[17];
  const float* g2_Wl = (const float*)d_in[18];
  const float* g2_bl = (const float*)d_in[19];
  const float* g2_Wr = (const float*)d_in[20];
  const float* g2_br = (const float*)d_in[21];
  const float* g2_att = (const float*)d_in[22];
  const float* g2_bias = (const float*)d_in[23];
  const float* gn2_w = (const float*)d_in[24];
  const float* gn2_b = (const float*)d_in[25];
  const float* gn2_ms = (const float*)d_in[26];
  const float* W_res = (const float*)d_in[27];
  const float* b_res = (const float*)d_in[28];
  const float* l1_Wih = (const float*)d_in[29];
  const float* l1_bih = (const float*)d_in[31];
  const float* l1_bhh = (const float*)d_in[32];
  const float* l2_Wih = (const float*)d_in[33];
  const float* l2_bih = (const float*)d_in[35];
  const float* l2_bhh = (const float*)d_in[36];
  const float* ln_w = (const float*)d_in[37];
  const float* ln_b = (const float*)d_in[38];
  const float* fc_W = (const float*)d_in[39];
  const float* fc_b = (const float*)d_in[40];
  float* out = (float*)d_out;

  const int N = in_sizes[0];
  const int E = in_sizes[3] / 2;
  const int G = out_size / 4;
  const int ET = E + N;

  char* wsb = (char*)d_ws;
  size_t off = 0;
  auto alloc = [&](size_t bytes) -> void* {
    void* p = (void*)(wsb + off);
    off = (off + bytes + 255) & ~(size_t)255;
    return p;
  };
  float* xA = (float*)alloc((size_t)N * DD * 4);                      // gat out f32; later h2 bf16
  unsigned short* xb = (unsigned short*)alloc((size_t)N * DD * 2);    // bf16 x / x1 / x2
  unsigned short* xlr = (unsigned short*)alloc((size_t)N * 384 * 2);  // xl|xr(|res)
  int* deg = (int*)alloc((size_t)N * 4);
  int* offs = (int*)alloc((size_t)(N + 1) * 4);
  int* cursor = (int*)alloc((size_t)N * 4);
  int* partials = (int*)alloc(1024);
  int* csr = (int*)alloc((size_t)ET * 4);
  int* gstart = (int*)alloc((size_t)(G + 1) * 4);
  float* invcnt = (float*)alloc((size_t)G * 4);
  float* gsum = (float*)alloc((size_t)G * DD * 4);
  float* gsq = (float*)alloc((size_t)G * DD * 4);
  float* pooled = (float*)alloc((size_t)G * LSTMH * 4);
  float* bcat1 = (float*)alloc(256 * 4);
  float* bcat2 = (float*)alloc(384 * 4);
  float* bsum1 = (float*)alloc(ZG * 4);
  float* bsum2 = (float*)alloc(ZG * 4);
  unsigned short* wcat1 = (unsigned short*)alloc((size_t)256 * DD * 2);
  unsigned short* wcat2 = (unsigned short*)alloc((size_t)384 * DD * 2);
  unsigned short* wl1b = (unsigned short*)alloc((size_t)ZG * DD * 2);
  unsigned short* wl2b = (unsigned short*)alloc((size_t)ZG * LSTMH * 2);
  (void)ws_size; (void)n_in;

  unsigned short* h2 = (unsigned short*)xA;  // [N][256] bf16, written after xA dead

  hipMemsetAsync(deg, 0, (size_t)N * 4, stream);
  hipMemsetAsync(cursor, 0, (size_t)N * 4, stream);
  hipMemsetAsync(pooled, 0, (size_t)G * LSTMH * 4, stream);

  // weight prep
  cvt_transpose<<<cdiv_(DD * DD, 256), 256, 0, stream>>>(g1_Wl, wcat1, DD, DD);
  cvt_transpose<<<cdiv_(DD * DD, 256), 256, 0, stream>>>(g1_Wr, wcat1 + DD * DD, DD, DD);
  cvt_transpose<<<cdiv_(DD * DD, 256), 256, 0, stream>>>(g2_Wl, wcat2, DD, DD);
  cvt_transpose<<<cdiv_(DD * DD, 256), 256, 0, stream>>>(g2_Wr, wcat2 + DD * DD, DD, DD);
  cvt_transpose<<<cdiv_(DD * DD, 256), 256, 0, stream>>>(W_res, wcat2 + 2 * DD * DD, DD, DD);
  cvt_direct<<<cdiv_(ZG * DD, 256), 256, 0, stream>>>(l1_Wih, wl1b, ZG * DD);
  cvt_direct<<<cdiv_(ZG * LSTMH, 256), 256, 0, stream>>>(l2_Wih, wl2b, ZG * LSTMH);
  prep_small<<<4, 256, 0, stream>>>(g1_bl, g1_br, g2_bl, g2_br, b_res, l1_bih, l1_bhh,
                                    l2_bih, l2_bhh, bcat1, bcat2, bsum1, bsum2);

  graph_ranges<<<1, 128, 0, stream>>>(batch_ids, gstart, invcnt, N, G);
  embed_in<<<N, 128, 0, stream>>>(node_labels, node_types, node_feat, emb_label, emb_type,
                                  W_in, b_in, xb, N);

  // CSR by dst
  count_deg<<<cdiv_(ET, 256), 256, 0, stream>>>(edge_index, deg, E, N);
  int nb1 = cdiv_(N, 256);
  scan1<<<nb1, 256, 0, stream>>>(deg, offs, partials, N);
  scan2<<<1, 256, 0, stream>>>(partials, offs, nb1, N);
  scan3<<<nb1, 256, 0, stream>>>(offs, partials, N);
  fill_csr<<<cdiv_(ET, 256), 256, 0, stream>>>(edge_index, offs, cursor, csr, E, N);

  int mb = cdiv_(N, 128);
  // ---- GAT layer 1: [xl|xr] in one GEMM ----
  gemm_bf16<<<dim3(2, mb), 256, 0, stream>>>(xb, wcat1, bcat1, xlr, N, DD, 256);
  gat_agg<<<cdiv_(N, 4), 256, 0, stream>>>(xlr, 256, csr, offs, g1_att, g1_bias, xA, N);
  hipMemsetAsync(gsum, 0, (size_t)G * DD * 8, stream);  // gsum+gsq contiguous
  gn_stats2<<<cdiv_(N, 128), 256, 0, stream>>>(xA, batch_ids, gsum, gsq, N);
  gn_apply<false><<<cdiv_(N * DD, 256), 256, 0, stream>>>(
      xA, xb, nullptr, 0, batch_ids, gsum, gsq, invcnt, gn1_w, gn1_b, gn1_ms, N);
  // ---- GAT layer 2: [xl|xr|res] in one GEMM ----
  gemm_bf16<<<dim3(3, mb), 256, 0, stream>>>(xb, wcat2, bcat2, xlr, N, DD, 384);
  gat_agg<<<cdiv_(N, 4), 256, 0, stream>>>(xlr, 384, csr, offs, g2_att, g2_bias, xA, N);
  hipMemsetAsync(gsum, 0, (size_t)G * DD * 8, stream);
  gn_stats2<<<cdiv_(N, 128), 256, 0, stream>>>(xA, batch_ids, gsum, gsq, N);
  gn_apply<true><<<cdiv_(N * DD, 256), 256, 0, stream>>>(
      xA, xb, xlr + 256, 384, batch_ids, gsum, gsq, invcnt, gn2_w, gn2_b, gn2_ms, N);
  // ---- fused dual LSTM (h1 in LDS) ----
  lstm_dual<<<cdiv_(N, LROWS), 512, 0, stream>>>(xb, wl1b, wl2b, bsum1, bsum2, h2, N);
  // ---- LN + mean pool + FC ----
  ln_pool2<<<cdiv_(N, 32), 256, 0, stream>>>(h2, batch_ids, ln_w, ln_b, invcnt, pooled, N);
  fc_lsm<<<G, 64, 0, stream>>>(pooled, fc_W, fc_b, out);
}

// Round 5
// 586.790 us; speedup vs baseline: 1.1965x; 1.1965x over previous
//
#include <hip/hip_runtime.h>
#include <cstdint>
#include <cstddef>

#define DD 128
#define LSTMH 256
#define ZG 1024

typedef __attribute__((ext_vector_type(8))) short short8v;
typedef __attribute__((ext_vector_type(4))) float float4v;

static inline int cdiv_(int a, int b) { return (a + b - 1) / b; }

__device__ __forceinline__ float sigm_(float x) { return 1.f / (1.f + __expf(-x)); }
__device__ __forceinline__ float tanh_(float x) {
  float e = __expf(-2.f * fabsf(x));
  float r = (1.f - e) / (1.f + e);
  return copysignf(r, x);
}

__device__ __forceinline__ unsigned short f2bf(float f) {
  uint32_t u = __float_as_uint(f);
  u += 0x7fffu + ((u >> 16) & 1u);
  return (unsigned short)(u >> 16);
}
__device__ __forceinline__ float bflo(uint32_t u) { return __uint_as_float(u << 16); }
__device__ __forceinline__ float bfhi(uint32_t u) { return __uint_as_float(u & 0xffff0000u); }
__device__ __forceinline__ float bfu(unsigned short u) { return __uint_as_float((uint32_t)u << 16); }

// ---------------- weight conversion ----------------
__global__ void cvt_direct(const float* __restrict__ W, unsigned short* __restrict__ o, int n) {
  int i = blockIdx.x * 256 + threadIdx.x;
  if (i < n) o[i] = f2bf(W[i]);
}

// W[K][M] row-major -> o[M][K] bf16
__global__ void cvt_transpose(const float* __restrict__ W, unsigned short* __restrict__ o,
                              int K, int M) {
  int i = blockIdx.x * 256 + threadIdx.x;
  if (i >= K * M) return;
  int m = i / K, k = i - m * K;
  o[i] = f2bf(W[(size_t)k * M + m]);
}

// bias concat + lstm bias sums
__global__ void prep_small(const float* g1bl, const float* g1br, const float* g2bl,
                           const float* g2br, const float* bres, const float* l1bih,
                           const float* l1bhh, const float* l2bih, const float* l2bhh,
                           float* bcat1, float* bcat2, float* bsum1, float* bsum2) {
  int t = blockIdx.x * 256 + threadIdx.x;
  if (t < 256) bcat1[t] = t < 128 ? g1bl[t] : g1br[t - 128];
  if (t < 384) bcat2[t] = t < 128 ? g2bl[t] : (t < 256 ? g2br[t - 128] : bres[t - 256]);
  if (t < ZG) { bsum1[t] = l1bih[t] + l1bhh[t]; bsum2[t] = l2bih[t] + l2bhh[t]; }
}

// ---------------- input embedding + W_in GEMV (K=33) -> bf16 ----------------
__global__ __launch_bounds__(128) void embed_in(
    const int* __restrict__ labels, const int* __restrict__ types,
    const float* __restrict__ nf, const float* __restrict__ embL,
    const float* __restrict__ embT, const float* __restrict__ W,
    const float* __restrict__ b, unsigned short* __restrict__ x, int N) {
  int n = blockIdx.x;
  if (n >= N) return;
  int t = threadIdx.x;
  __shared__ float f[33];
  if (t < 16) f[t] = embL[labels[n] * 16 + t];
  else if (t < 32) f[t] = embT[types[n] * 16 + (t - 16)];
  else if (t == 32) f[32] = nf[n];
  __syncthreads();
  float acc = b[t];
#pragma unroll
  for (int k = 0; k < 33; ++k) acc += f[k] * W[k * DD + t];
  x[(size_t)n * DD + t] = f2bf(acc);
}

// ---------------- CSR build ----------------
__global__ void count_deg(const int* __restrict__ ei, int* __restrict__ deg, int E_, int N_) {
  int i = blockIdx.x * 256 + threadIdx.x;
  if (i < E_) atomicAdd(&deg[ei[E_ + i]], 1);
  else if (i < E_ + N_) atomicAdd(&deg[i - E_], 1);
}

__global__ __launch_bounds__(256) void scan1(const int* __restrict__ deg, int* __restrict__ offs,
                                             int* __restrict__ partials, int N_) {
  __shared__ int buf[2][256];
  int tid = threadIdx.x;
  int i = blockIdx.x * 256 + tid;
  int v = (i < N_) ? deg[i] : 0;
  buf[0][tid] = v;
  __syncthreads();
  int cur = 0;
#pragma unroll
  for (int d = 1; d < 256; d <<= 1) {
    int xv = buf[cur][tid];
    if (tid >= d) xv += buf[cur][tid - d];
    buf[cur ^ 1][tid] = xv;
    cur ^= 1;
    __syncthreads();
  }
  int incl = buf[cur][tid];
  if (i < N_) offs[i] = incl - v;
  if (tid == 255) partials[blockIdx.x] = incl;
}

__global__ __launch_bounds__(256) void scan2(int* __restrict__ partials, int* __restrict__ offs,
                                             int nb, int N_) {
  __shared__ int buf[2][256];
  int tid = threadIdx.x;
  int v = (tid < nb) ? partials[tid] : 0;
  buf[0][tid] = v;
  __syncthreads();
  int cur = 0;
#pragma unroll
  for (int d = 1; d < 256; d <<= 1) {
    int xv = buf[cur][tid];
    if (tid >= d) xv += buf[cur][tid - d];
    buf[cur ^ 1][tid] = xv;
    cur ^= 1;
    __syncthreads();
  }
  int incl = buf[cur][tid];
  if (tid < nb) partials[tid] = incl - v;
  if (tid == 255) offs[N_] = incl;
}

__global__ void scan3(int* __restrict__ offs, const int* __restrict__ partials, int N_) {
  int i = blockIdx.x * 256 + threadIdx.x;
  if (i < N_) offs[i] += partials[blockIdx.x];
}

__global__ void fill_csr(const int* __restrict__ ei, const int* __restrict__ offs,
                         int* __restrict__ cursor, int* __restrict__ csr, int E_, int N_) {
  int i = blockIdx.x * 256 + threadIdx.x;
  int s, d;
  if (i < E_) { s = ei[i]; d = ei[E_ + i]; }
  else if (i < E_ + N_) { s = d = i - E_; }
  else return;
  int pos = offs[d] + atomicAdd(&cursor[d], 1);
  csr[pos] = s;
}

// ---------------- graph ranges ----------------
__global__ void graph_ranges(const int* __restrict__ bids, int* __restrict__ gstart,
                             float* __restrict__ invcnt, int N_, int G_) {
  int t = threadIdx.x;
  if (t <= G_) {
    int lo = 0, hi = N_;
    while (lo < hi) { int mid = (lo + hi) >> 1; if (bids[mid] < t) lo = mid + 1; else hi = mid; }
    gstart[t] = lo;
  }
  __syncthreads();
  if (t < G_) {
    int c = gstart[t + 1] - gstart[t];
    invcnt[t] = (c > 0) ? 1.f / (float)c : 0.f;
  }
}

// ---------------- bf16 MFMA GEMM: C[M,Ncols] bf16 = A[M,K]bf16 @ B'[Ncols,K]^T + bias
__global__ __launch_bounds__(256) void gemm_bf16(
    const unsigned short* __restrict__ A, const unsigned short* __restrict__ Bp,
    const float* __restrict__ bias, unsigned short* __restrict__ C, int M, int K, int Ncols) {
  __shared__ unsigned short As[128 * 40];
  __shared__ unsigned short Bs[128 * 40];
  int tid = threadIdx.x;
  int lane = tid & 63;
  int wid = tid >> 6;
  int rowBase = blockIdx.y * 128, colBase = blockIdx.x * 128;
  int wr = (wid >> 1) * 64, wc = (wid & 1) * 64;
  int fr = lane & 15, fg = lane >> 4;
  float4v acc[4][4];
#pragma unroll
  for (int i = 0; i < 4; ++i)
#pragma unroll
    for (int j = 0; j < 4; ++j) acc[i][j] = (float4v){0.f, 0.f, 0.f, 0.f};

  int sr = tid >> 2;
  int sc = tid & 3;
  int off_lo = (sc < 2) ? 32 * sc : 32 * sc - 56;

  for (int k0 = 0; k0 < K; k0 += 32) {
#pragma unroll
    for (int it = 0; it < 2; ++it) {
      int r = it * 64 + sr;
      uint4 va = make_uint4(0u, 0u, 0u, 0u);
      if (rowBase + r < M)
        va = *(const uint4*)(A + (size_t)(rowBase + r) * K + k0 + sc * 8);
      char* arow = (char*)(As + r * 40);
      *(uint2*)(arow + off_lo) = make_uint2(va.x, va.y);
      *(uint2*)(arow + off_lo + 16) = make_uint2(va.z, va.w);
      uint4 vb = *(const uint4*)(Bp + (size_t)(colBase + r) * K + k0 + sc * 8);
      char* brow = (char*)(Bs + r * 40);
      *(uint2*)(brow + off_lo) = make_uint2(vb.x, vb.y);
      *(uint2*)(brow + off_lo + 16) = make_uint2(vb.z, vb.w);
    }
    __syncthreads();
    short8v af[4], bfv[4];
#pragma unroll
    for (int i = 0; i < 4; ++i)
      af[i] = *(const short8v*)((const char*)As + (wr + 16 * i + fr) * 80 + fg * 16);
#pragma unroll
    for (int j = 0; j < 4; ++j)
      bfv[j] = *(const short8v*)((const char*)Bs + (wc + 16 * j + fr) * 80 + fg * 16);
#pragma unroll
    for (int i = 0; i < 4; ++i)
#pragma unroll
      for (int j = 0; j < 4; ++j)
        acc[i][j] = __builtin_amdgcn_mfma_f32_16x16x32_bf16(af[i], bfv[j], acc[i][j], 0, 0, 0);
    __syncthreads();
  }
#pragma unroll
  for (int j = 0; j < 4; ++j) {
    int gc = colBase + wc + 16 * j + fr;
    float bv = bias[gc];
#pragma unroll
    for (int i = 0; i < 4; ++i) {
      int gr0 = rowBase + wr + 16 * i + fg * 4;
#pragma unroll
      for (int rg = 0; rg < 4; ++rg) {
        int gr = gr0 + rg;
        if (gr < M) C[(size_t)gr * Ncols + gc] = f2bf(acc[i][j][rg] + bv);
      }
    }
  }
}

// ---------------- GATv2 aggregation: 1 wave/node, 4 edges in flight (16 lanes/edge) ------
__global__ __launch_bounds__(256) void gat_agg(
    const unsigned short* __restrict__ xlr, int stride,
    const int* __restrict__ csr, const int* __restrict__ offs,
    const float* __restrict__ att, const float* __restrict__ bias,
    float* __restrict__ out, int N) {
  int wid = (blockIdx.x * 256 + threadIdx.x) >> 6;
  if (wid >= N) return;
  int lane = threadIdx.x & 63;
  int q = lane >> 4, ql = lane & 15;   // edge slot, channel group (8 ch each)
  float4 aA = *(const float4*)&att[ql * 8];
  float4 aB = *(const float4*)&att[ql * 8 + 4];
  uint4 ur = *(const uint4*)(xlr + (size_t)wid * stride + 128 + ql * 8);
  float r0 = bflo(ur.x), r1 = bfhi(ur.x), r2 = bflo(ur.y), r3 = bfhi(ur.y);
  float r4 = bflo(ur.z), r5 = bfhi(ur.z), r6 = bflo(ur.w), r7 = bfhi(ur.w);
  float m = -1e30f, L = 0.f;
  float s0 = 0.f, s1 = 0.f, s2 = 0.f, s3 = 0.f, s4 = 0.f, s5 = 0.f, s6 = 0.f, s7 = 0.f;
  int js = offs[wid], je = offs[wid + 1];
  for (int j = js + q; j < je; j += 4) {
    int s = csr[j];
    uint4 u = *(const uint4*)(xlr + (size_t)s * stride + ql * 8);
    float x0 = bflo(u.x), x1 = bfhi(u.x), x2 = bflo(u.y), x3 = bfhi(u.y);
    float x4 = bflo(u.z), x5 = bfhi(u.z), x6 = bflo(u.w), x7 = bfhi(u.w);
    // leaky_relu(v, 0.2) == max(v, 0.2*v) for slope in (0,1)
    float v0 = fmaxf(r0 + x0, 0.2f * (r0 + x0));
    float v1 = fmaxf(r1 + x1, 0.2f * (r1 + x1));
    float v2 = fmaxf(r2 + x2, 0.2f * (r2 + x2));
    float v3 = fmaxf(r3 + x3, 0.2f * (r3 + x3));
    float v4 = fmaxf(r4 + x4, 0.2f * (r4 + x4));
    float v5 = fmaxf(r5 + x5, 0.2f * (r5 + x5));
    float v6 = fmaxf(r6 + x6, 0.2f * (r6 + x6));
    float v7 = fmaxf(r7 + x7, 0.2f * (r7 + x7));
    float p = aA.x * v0 + aA.y * v1 + aA.z * v2 + aA.w * v3 +
              aB.x * v4 + aB.y * v5 + aB.z * v6 + aB.w * v7;
    p += __shfl_xor(p, 1); p += __shfl_xor(p, 2);
    p += __shfl_xor(p, 4); p += __shfl_xor(p, 8);
    float mn = fmaxf(m, p);
    float ea = __expf(p - mn);
    float es = __expf(m - mn);
    L = L * es + ea;
    s0 = s0 * es + ea * x0; s1 = s1 * es + ea * x1;
    s2 = s2 * es + ea * x2; s3 = s3 * es + ea * x3;
    s4 = s4 * es + ea * x4; s5 = s5 * es + ea * x5;
    s6 = s6 * es + ea * x6; s7 = s7 * es + ea * x7;
    m = mn;
  }
  // merge the 4 edge-slot states (xor 16, then xor 32)
#pragma unroll
  for (int d = 16; d <= 32; d <<= 1) {
    float mo = __shfl_xor(m, d), Lo = __shfl_xor(L, d);
    float t0 = __shfl_xor(s0, d), t1 = __shfl_xor(s1, d);
    float t2 = __shfl_xor(s2, d), t3 = __shfl_xor(s3, d);
    float t4 = __shfl_xor(s4, d), t5 = __shfl_xor(s5, d);
    float t6 = __shfl_xor(s6, d), t7 = __shfl_xor(s7, d);
    float mn = fmaxf(m, mo);
    float e0 = __expf(m - mn), e1 = __expf(mo - mn);
    L = L * e0 + Lo * e1;
    s0 = s0 * e0 + t0 * e1; s1 = s1 * e0 + t1 * e1;
    s2 = s2 * e0 + t2 * e1; s3 = s3 * e0 + t3 * e1;
    s4 = s4 * e0 + t4 * e1; s5 = s5 * e0 + t5 * e1;
    s6 = s6 * e0 + t6 * e1; s7 = s7 * e0 + t7 * e1;
    m = mn;
  }
  if (q == 0) {
    float inv = 1.f / L;
    float4 bA = *(const float4*)&bias[ql * 8];
    float4 bB = *(const float4*)&bias[ql * 8 + 4];
    float4 oA, oB;
    oA.x = s0 * inv + bA.x; oA.y = s1 * inv + bA.y;
    oA.z = s2 * inv + bA.z; oA.w = s3 * inv + bA.w;
    oB.x = s4 * inv + bB.x; oB.y = s5 * inv + bB.y;
    oB.z = s6 * inv + bB.z; oB.w = s7 * inv + bB.w;
    *(float4*)&out[(size_t)wid * DD + ql * 8] = oA;
    *(float4*)&out[(size_t)wid * DD + ql * 8 + 4] = oB;
  }
}

// ---------------- GraphNorm stats ----------------
__global__ __launch_bounds__(256) void gn_stats2(const float* __restrict__ x,
                                                 const int* __restrict__ bids,
                                                 float* __restrict__ gsum,
                                                 float* __restrict__ gsq, int N) {
  int base = blockIdx.x * 128;
  int ch = threadIdx.x & 127;
  int sub = threadIdx.x >> 7;
  int end = base + 128 < N ? base + 128 : N;
  int curg = -1;
  float s = 0.f, q = 0.f;
  for (int r = base + sub; r < end; r += 2) {
    int g = bids[r];
    if (g != curg) {
      if (curg >= 0) {
        atomicAdd(&gsum[curg * DD + ch], s);
        atomicAdd(&gsq[curg * DD + ch], q);
      }
      curg = g; s = 0.f; q = 0.f;
    }
    float v = x[(size_t)r * DD + ch];
    s += v; q += v * v;
  }
  if (curg >= 0) {
    atomicAdd(&gsum[curg * DD + ch], s);
    atomicAdd(&gsq[curg * DD + ch], q);
  }
}

// ---------------- GraphNorm apply + ELU (+residual bf16) -> bf16 ----------------
template <bool ADDRES>
__global__ void gn_apply(const float* __restrict__ xin, unsigned short* __restrict__ xout,
                         const unsigned short* __restrict__ res, int resStride,
                         const int* __restrict__ bids, const float* __restrict__ gsum,
                         const float* __restrict__ gsq, const float* __restrict__ invcnt,
                         const float* __restrict__ w, const float* __restrict__ b,
                         const float* __restrict__ ms, int N) {
  int idx = blockIdx.x * 256 + threadIdx.x;
  if (idx >= N * DD) return;
  int n = idx >> 7, ch = idx & 127;
  int g = bids[n];
  float ic = invcnt[g];
  float mean = gsum[g * DD + ch] * ic;
  float ex2 = gsq[g * DD + ch] * ic;
  float mm = mean * ms[ch];
  float var = ex2 - mm * (2.f * mean - mm);
  float v = (xin[idx] - mm) * rsqrtf(var + 1e-5f) * w[ch] + b[ch];
  if (ADDRES) v += bfu(res[(size_t)n * resStride + ch]);
  v = v > 0.f ? v : (__expf(v) - 1.f);
  xout[idx] = f2bf(v);
}

// ---------------- fused LSTM step with XCD-swizzled grid ----------------
// h = sig(o)*tanh(sig(i)*tanh(g)); f-gate dead (c0=0).
// Flat grid 64*cdiv(nrb,8); decode keeps all 8 col-chunks of a 256-row panel on ONE XCD
// so the A panel is HBM-fetched once and L2-served for the other 7 blocks.
template <int KDIM>
__global__ __launch_bounds__(256) void lstm_fused(
    const unsigned short* __restrict__ A, const unsigned short* __restrict__ Bp,
    const float* __restrict__ bsum, unsigned short* __restrict__ H, int M) {
  int nrb = (M + 255) >> 8;
  int b = blockIdx.x;
  int g = b & 7, inner = b >> 3;
  int rb = g + 8 * (inner >> 3);
  int cc = inner & 7;
  if (rb >= nrb) return;
  int rowBase = rb * 256;
  int hc0 = cc * 32;

  __shared__ unsigned short As[256 * 40];
  __shared__ unsigned short Bs[96 * 40];
  int tid = threadIdx.x;
  int lane = tid & 63;
  int wid = tid >> 6;
  int wy = wid * 64;
  int fr = lane & 15, fg = lane >> 4;
  float4v acc[4][6];
#pragma unroll
  for (int i = 0; i < 4; ++i)
#pragma unroll
    for (int j = 0; j < 6; ++j) acc[i][j] = (float4v){0.f, 0.f, 0.f, 0.f};

  int sr = tid >> 2;
  int sc = tid & 3;
  int off_lo = (sc < 2) ? 32 * sc : 32 * sc - 56;

  for (int k0 = 0; k0 < KDIM; k0 += 32) {
#pragma unroll
    for (int it = 0; it < 4; ++it) {
      int r = it * 64 + sr;
      uint4 va = make_uint4(0u, 0u, 0u, 0u);
      if (rowBase + r < M)
        va = *(const uint4*)(A + (size_t)(rowBase + r) * KDIM + k0 + sc * 8);
      char* arow = (char*)(As + r * 40);
      *(uint2*)(arow + off_lo) = make_uint2(va.x, va.y);
      *(uint2*)(arow + off_lo + 16) = make_uint2(va.z, va.w);
    }
#pragma unroll
    for (int it = 0; it < 2; ++it) {
      int li = it * 256 + tid;
      if (li < 384) {
        int r = li >> 2, bc = li & 3;
        int q = r >> 5;
        int qmap = (q == 0) ? 0 : (q == 1 ? 2 : 3);
        int grow = qmap * 256 + hc0 + (r & 31);
        uint4 vb = *(const uint4*)(Bp + (size_t)grow * KDIM + k0 + bc * 8);
        int blo = (bc < 2) ? 32 * bc : 32 * bc - 56;
        char* brow = (char*)(Bs + r * 40);
        *(uint2*)(brow + blo) = make_uint2(vb.x, vb.y);
        *(uint2*)(brow + blo + 16) = make_uint2(vb.z, vb.w);
      }
    }
    __syncthreads();
    short8v af[4], bfv[6];
#pragma unroll
    for (int i = 0; i < 4; ++i)
      af[i] = *(const short8v*)((const char*)As + (wy + 16 * i + fr) * 80 + fg * 16);
#pragma unroll
    for (int j = 0; j < 6; ++j)
      bfv[j] = *(const short8v*)((const char*)Bs + (16 * j + fr) * 80 + fg * 16);
#pragma unroll
    for (int i = 0; i < 4; ++i)
#pragma unroll
      for (int j = 0; j < 6; ++j)
        acc[i][j] = __builtin_amdgcn_mfma_f32_16x16x32_bf16(af[i], bfv[j], acc[i][j], 0, 0, 0);
    __syncthreads();
  }
  // epilogue: lane holds i,g,o for channels hc0+fr (cg=0) and hc0+16+fr (cg=1)
#pragma unroll
  for (int cg = 0; cg < 2; ++cg) {
    int hc = hc0 + fr + 16 * cg;
    float bi = bsum[hc], bg = bsum[512 + hc], bo = bsum[768 + hc];
#pragma unroll
    for (int i = 0; i < 4; ++i) {
#pragma unroll
      for (int rg = 0; rg < 4; ++rg) {
        int row = rowBase + wy + 16 * i + fg * 4 + rg;
        if (row < M) {
          float iv = acc[i][cg][rg] + bi;
          float gv = acc[i][2 + cg][rg] + bg;
          float ov = acc[i][4 + cg][rg] + bo;
          float c = sigm_(iv) * tanh_(gv);
          H[(size_t)row * LSTMH + hc] = f2bf(sigm_(ov) * tanh_(c));
        }
      }
    }
  }
}

// ---------------- LayerNorm + mean pool: 1 wave per 8 rows, register pooling ----------
__global__ __launch_bounds__(256) void ln_pool2(
    const unsigned short* __restrict__ h2, const int* __restrict__ bids,
    const float* __restrict__ lnw, const float* __restrict__ lnb,
    const float* __restrict__ invcnt, float* __restrict__ pooled, int N) {
  int wave = (blockIdx.x * 256 + threadIdx.x) >> 6;
  int lane = threadIdx.x & 63;
  int r0 = wave * 8;
  if (r0 >= N) return;
  float4 w4 = *(const float4*)&lnw[lane * 4];
  float4 b4 = *(const float4*)&lnb[lane * 4];
  float p0 = 0.f, p1 = 0.f, p2 = 0.f, p3 = 0.f;
  int curg = bids[r0];
  int rend = r0 + 8 < N ? r0 + 8 : N;
  for (int r = r0; r < rend; ++r) {
    int g = bids[r];
    if (g != curg) {
      float ic = invcnt[curg];
      atomicAdd(&pooled[curg * LSTMH + lane * 4 + 0], p0 * ic);
      atomicAdd(&pooled[curg * LSTMH + lane * 4 + 1], p1 * ic);
      atomicAdd(&pooled[curg * LSTMH + lane * 4 + 2], p2 * ic);
      atomicAdd(&pooled[curg * LSTMH + lane * 4 + 3], p3 * ic);
      p0 = p1 = p2 = p3 = 0.f;
      curg = g;
    }
    uint2 u = *(const uint2*)(h2 + (size_t)r * LSTMH + lane * 4);
    float v0 = bflo(u.x), v1 = bfhi(u.x), v2 = bflo(u.y), v3 = bfhi(u.y);
    float s = v0 + v1 + v2 + v3;
    float q = v0 * v0 + v1 * v1 + v2 * v2 + v3 * v3;
#pragma unroll
    for (int d = 1; d < 64; d <<= 1) { s += __shfl_xor(s, d); q += __shfl_xor(q, d); }
    float mu = s * (1.f / 256.f);
    float var = q * (1.f / 256.f) - mu * mu;
    float rs = rsqrtf(var + 1e-5f);
    p0 += w4.x * (v0 - mu) * rs + b4.x;
    p1 += w4.y * (v1 - mu) * rs + b4.y;
    p2 += w4.z * (v2 - mu) * rs + b4.z;
    p3 += w4.w * (v3 - mu) * rs + b4.w;
  }
  float ic = invcnt[curg];
  atomicAdd(&pooled[curg * LSTMH + lane * 4 + 0], p0 * ic);
  atomicAdd(&pooled[curg * LSTMH + lane * 4 + 1], p1 * ic);
  atomicAdd(&pooled[curg * LSTMH + lane * 4 + 2], p2 * ic);
  atomicAdd(&pooled[curg * LSTMH + lane * 4 + 3], p3 * ic);
}

// ---------------- FC + log_softmax ----------------
__global__ __launch_bounds__(64) void fc_lsm(const float* __restrict__ pooled,
                                             const float* __restrict__ W,
                                             const float* __restrict__ b, float* __restrict__ out) {
  int g = blockIdx.x;
  int t = threadIdx.x;
  float l0 = 0.f, l1 = 0.f, l2 = 0.f, l3 = 0.f;
  for (int k = t; k < LSTMH; k += 64) {
    float p = pooled[g * LSTMH + k];
    l0 += p * W[k * 4 + 0];
    l1 += p * W[k * 4 + 1];
    l2 += p * W[k * 4 + 2];
    l3 += p * W[k * 4 + 3];
  }
#pragma unroll
  for (int d = 1; d < 64; d <<= 1) {
    l0 += __shfl_xor(l0, d); l1 += __shfl_xor(l1, d);
    l2 += __shfl_xor(l2, d); l3 += __shfl_xor(l3, d);
  }
  if (t == 0) {
    float z[4] = {l0 + b[0], l1 + b[1], l2 + b[2], l3 + b[3]};
    float mx = fmaxf(fmaxf(z[0], z[1]), fmaxf(z[2], z[3]));
    float sum = __expf(z[0] - mx) + __expf(z[1] - mx) + __expf(z[2] - mx) + __expf(z[3] - mx);
    float ls = logf(sum);
#pragma unroll
    for (int o = 0; o < 4; ++o) out[g * 4 + o] = z[o] - mx - ls;
  }
}

// ---------------- host launch ----------------
extern "C" void kernel_launch(void* const* d_in, const int* in_sizes, int n_in,
                              void* d_out, int out_size, void* d_ws, size_t ws_size,
                              hipStream_t stream) {
  const int* node_labels = (const int*)d_in[0];
  const int* node_types = (const int*)d_in[1];
  const float* node_feat = (const float*)d_in[2];
  const int* edge_index = (const int*)d_in[3];
  const int* batch_ids = (const int*)d_in[4];
  const float* emb_label = (const float*)d_in[5];
  const float* emb_type = (const float*)d_in[6];
  const float* W_in = (const float*)d_in[7];
  const float* b_in = (const float*)d_in[8];
  const float* g1_Wl = (const float*)d_in[9];
  const float* g1_bl = (const float*)d_in[10];
  const float* g1_Wr = (const float*)d_in[11];
  const float* g1_br = (const float*)d_in[12];
  const float* g1_att = (const float*)d_in[13];
  const float* g1_bias = (const float*)d_in[14];
  const float* gn1_w = (const float*)d_in[15];
  const float* gn1_b = (const float*)d_in[16];
  const float* gn1_ms = (const float*)d_in[17];
  const float* g2_Wl = (const float*)d_in[18];
  const float* g2_bl = (const float*)d_in[19];
  const float* g2_Wr = (const float*)d_in[20];
  const float* g2_br = (const float*)d_in[21];
  const float* g2_att = (const float*)d_in[22];
  const float* g2_bias = (const float*)d_in[23];
  const float* gn2_w = (const float*)d_in[24];
  const float* gn2_b = (const float*)d_in[25];
  const float* gn2_ms = (const float*)d_in[26];
  const float* W_res = (const float*)d_in[27];
  const float* b_res = (const float*)d_in[28];
  const float* l1_Wih = (const float*)d_in[29];
  const float* l1_bih = (const float*)d_in[31];
  const float* l1_bhh = (const float*)d_in[32];
  const float* l2_Wih = (const float*)d_in[33];
  const float* l2_bih = (const float*)d_in[35];
  const float* l2_bhh = (const float*)d_in[36];
  const float* ln_w = (const float*)d_in[37];
  const float* ln_b = (const float*)d_in[38];
  const float* fc_W = (const float*)d_in[39];
  const float* fc_b = (const float*)d_in[40];
  float* out = (float*)d_out;

  const int N = in_sizes[0];
  const int E = in_sizes[3] / 2;
  const int G = out_size / 4;
  const int ET = E + N;

  char* wsb = (char*)d_ws;
  size_t off = 0;
  auto alloc = [&](size_t bytes) -> void* {
    void* p = (void*)(wsb + off);
    off = (off + bytes + 255) & ~(size_t)255;
    return p;
  };
  float* xA = (float*)alloc((size_t)N * DD * 4);                      // gat out f32; later h2 bf16
  unsigned short* xb = (unsigned short*)alloc((size_t)N * DD * 2);    // bf16 x / x1 / x2
  unsigned short* xlr = (unsigned short*)alloc((size_t)N * 384 * 2);  // xl|xr(|res); later h1
  int* deg = (int*)alloc((size_t)N * 4);
  int* offs = (int*)alloc((size_t)(N + 1) * 4);
  int* cursor = (int*)alloc((size_t)N * 4);
  int* partials = (int*)alloc(1024);
  int* csr = (int*)alloc((size_t)ET * 4);
  int* gstart = (int*)alloc((size_t)(G + 1) * 4);
  float* invcnt = (float*)alloc((size_t)G * 4);
  float* gsum = (float*)alloc((size_t)G * DD * 4);
  float* gsq = (float*)alloc((size_t)G * DD * 4);
  float* pooled = (float*)alloc((size_t)G * LSTMH * 4);
  float* bcat1 = (float*)alloc(256 * 4);
  float* bcat2 = (float*)alloc(384 * 4);
  float* bsum1 = (float*)alloc(ZG * 4);
  float* bsum2 = (float*)alloc(ZG * 4);
  unsigned short* wcat1 = (unsigned short*)alloc((size_t)256 * DD * 2);
  unsigned short* wcat2 = (unsigned short*)alloc((size_t)384 * DD * 2);
  unsigned short* wl1b = (unsigned short*)alloc((size_t)ZG * DD * 2);
  unsigned short* wl2b = (unsigned short*)alloc((size_t)ZG * LSTMH * 2);
  (void)ws_size; (void)n_in;

  unsigned short* h1 = xlr;                  // [N][256] bf16, written after xlr dead
  unsigned short* h2 = (unsigned short*)xA;  // [N][256] bf16, written after xA dead

  hipMemsetAsync(deg, 0, (size_t)N * 4, stream);
  hipMemsetAsync(cursor, 0, (size_t)N * 4, stream);
  hipMemsetAsync(pooled, 0, (size_t)G * LSTMH * 4, stream);

  // weight prep
  cvt_transpose<<<cdiv_(DD * DD, 256), 256, 0, stream>>>(g1_Wl, wcat1, DD, DD);
  cvt_transpose<<<cdiv_(DD * DD, 256), 256, 0, stream>>>(g1_Wr, wcat1 + DD * DD, DD, DD);
  cvt_transpose<<<cdiv_(DD * DD, 256), 256, 0, stream>>>(g2_Wl, wcat2, DD, DD);
  cvt_transpose<<<cdiv_(DD * DD, 256), 256, 0, stream>>>(g2_Wr, wcat2 + DD * DD, DD, DD);
  cvt_transpose<<<cdiv_(DD * DD, 256), 256, 0, stream>>>(W_res, wcat2 + 2 * DD * DD, DD, DD);
  cvt_direct<<<cdiv_(ZG * DD, 256), 256, 0, stream>>>(l1_Wih, wl1b, ZG * DD);
  cvt_direct<<<cdiv_(ZG * LSTMH, 256), 256, 0, stream>>>(l2_Wih, wl2b, ZG * LSTMH);
  prep_small<<<4, 256, 0, stream>>>(g1_bl, g1_br, g2_bl, g2_br, b_res, l1_bih, l1_bhh,
                                    l2_bih, l2_bhh, bcat1, bcat2, bsum1, bsum2);

  graph_ranges<<<1, 128, 0, stream>>>(batch_ids, gstart, invcnt, N, G);
  embed_in<<<N, 128, 0, stream>>>(node_labels, node_types, node_feat, emb_label, emb_type,
                                  W_in, b_in, xb, N);

  // CSR by dst
  count_deg<<<cdiv_(ET, 256), 256, 0, stream>>>(edge_index, deg, E, N);
  int nb1 = cdiv_(N, 256);
  scan1<<<nb1, 256, 0, stream>>>(deg, offs, partials, N);
  scan2<<<1, 256, 0, stream>>>(partials, offs, nb1, N);
  scan3<<<nb1, 256, 0, stream>>>(offs, partials, N);
  fill_csr<<<cdiv_(ET, 256), 256, 0, stream>>>(edge_index, offs, cursor, csr, E, N);

  int mb = cdiv_(N, 128);
  // ---- GAT layer 1: [xl|xr] in one GEMM ----
  gemm_bf16<<<dim3(2, mb), 256, 0, stream>>>(xb, wcat1, bcat1, xlr, N, DD, 256);
  gat_agg<<<cdiv_(N, 4), 256, 0, stream>>>(xlr, 256, csr, offs, g1_att, g1_bias, xA, N);
  hipMemsetAsync(gsum, 0, (size_t)G * DD * 8, stream);  // gsum+gsq contiguous
  gn_stats2<<<cdiv_(N, 128), 256, 0, stream>>>(xA, batch_ids, gsum, gsq, N);
  gn_apply<false><<<cdiv_(N * DD, 256), 256, 0, stream>>>(
      xA, xb, nullptr, 0, batch_ids, gsum, gsq, invcnt, gn1_w, gn1_b, gn1_ms, N);
  // ---- GAT layer 2: [xl|xr|res] in one GEMM ----
  gemm_bf16<<<dim3(3, mb), 256, 0, stream>>>(xb, wcat2, bcat2, xlr, N, DD, 384);
  gat_agg<<<cdiv_(N, 4), 256, 0, stream>>>(xlr, 384, csr, offs, g2_att, g2_bias, xA, N);
  hipMemsetAsync(gsum, 0, (size_t)G * DD * 8, stream);
  gn_stats2<<<cdiv_(N, 128), 256, 0, stream>>>(xA, batch_ids, gsum, gsq, N);
  gn_apply<true><<<cdiv_(N * DD, 256), 256, 0, stream>>>(
      xA, xb, xlr + 256, 384, batch_ids, gsum, gsq, invcnt, gn2_w, gn2_b, gn2_ms, N);
  // ---- LSTM x2 (XCD-swizzled grids; h1 reuses xlr, h2 reuses xA) ----
  int nrb = cdiv_(N, 256);
  int lblocks = 64 * cdiv_(nrb, 8);
  lstm_fused<DD><<<lblocks, 256, 0, stream>>>(xb, wl1b, bsum1, h1, N);
  lstm_fused<LSTMH><<<lblocks, 256, 0, stream>>>(h1, wl2b, bsum2, h2, N);
  // ---- LN + mean pool + FC ----
  ln_pool2<<<cdiv_(N, 32), 256, 0, stream>>>(h2, batch_ids, ln_w, ln_b, invcnt, pooled, N);
  fc_lsm<<<G, 64, 0, stream>>>(pooled, fc_W, fc_b, out);
}

// Round 6
// 569.458 us; speedup vs baseline: 1.2329x; 1.0304x over previous
//
#include <hip/hip_runtime.h>
#include <cstdint>
#include <cstddef>

#define DD 128
#define LSTMH 256
#define ZG 1024

typedef __attribute__((ext_vector_type(8))) short short8v;
typedef __attribute__((ext_vector_type(4))) float float4v;

static inline int cdiv_(int a, int b) { return (a + b - 1) / b; }

__device__ __forceinline__ float sigm_(float x) { return 1.f / (1.f + __expf(-x)); }
__device__ __forceinline__ float tanh_(float x) {
  float e = __expf(-2.f * fabsf(x));
  float r = (1.f - e) / (1.f + e);
  return copysignf(r, x);
}

__device__ __forceinline__ unsigned short f2bf(float f) {
  uint32_t u = __float_as_uint(f);
  u += 0x7fffu + ((u >> 16) & 1u);
  return (unsigned short)(u >> 16);
}
__device__ __forceinline__ float bflo(uint32_t u) { return __uint_as_float(u << 16); }
__device__ __forceinline__ float bfhi(uint32_t u) { return __uint_as_float(u & 0xffff0000u); }
__device__ __forceinline__ float bfu(unsigned short u) { return __uint_as_float((uint32_t)u << 16); }

// ---------------- weight conversion ----------------
__global__ void cvt_direct(const float* __restrict__ W, unsigned short* __restrict__ o, int n) {
  int i = blockIdx.x * 256 + threadIdx.x;
  if (i < n) o[i] = f2bf(W[i]);
}

// W[K][M] row-major -> o[M][K] bf16
__global__ void cvt_transpose(const float* __restrict__ W, unsigned short* __restrict__ o,
                              int K, int M) {
  int i = blockIdx.x * 256 + threadIdx.x;
  if (i >= K * M) return;
  int m = i / K, k = i - m * K;
  o[i] = f2bf(W[(size_t)k * M + m]);
}

// bias concat + lstm bias sums
__global__ void prep_small(const float* g1bl, const float* g1br, const float* g2bl,
                           const float* g2br, const float* bres, const float* l1bih,
                           const float* l1bhh, const float* l2bih, const float* l2bhh,
                           float* bcat1, float* bcat2, float* bsum1, float* bsum2) {
  int t = blockIdx.x * 256 + threadIdx.x;
  if (t < 256) bcat1[t] = t < 128 ? g1bl[t] : g1br[t - 128];
  if (t < 384) bcat2[t] = t < 128 ? g2bl[t] : (t < 256 ? g2br[t - 128] : bres[t - 256]);
  if (t < ZG) { bsum1[t] = l1bih[t] + l1bhh[t]; bsum2[t] = l2bih[t] + l2bhh[t]; }
}

// ---------------- input embedding + W_in GEMV (K=33) -> bf16 ----------------
__global__ __launch_bounds__(128) void embed_in(
    const int* __restrict__ labels, const int* __restrict__ types,
    const float* __restrict__ nf, const float* __restrict__ embL,
    const float* __restrict__ embT, const float* __restrict__ W,
    const float* __restrict__ b, unsigned short* __restrict__ x, int N) {
  int n = blockIdx.x;
  if (n >= N) return;
  int t = threadIdx.x;
  __shared__ float f[33];
  if (t < 16) f[t] = embL[labels[n] * 16 + t];
  else if (t < 32) f[t] = embT[types[n] * 16 + (t - 16)];
  else if (t == 32) f[32] = nf[n];
  __syncthreads();
  float acc = b[t];
#pragma unroll
  for (int k = 0; k < 33; ++k) acc += f[k] * W[k * DD + t];
  x[(size_t)n * DD + t] = f2bf(acc);
}

// ---------------- CSR build ----------------
__global__ void count_deg(const int* __restrict__ ei, int* __restrict__ deg, int E_, int N_) {
  int i = blockIdx.x * 256 + threadIdx.x;
  if (i < E_) atomicAdd(&deg[ei[E_ + i]], 1);
  else if (i < E_ + N_) atomicAdd(&deg[i - E_], 1);
}

__global__ __launch_bounds__(256) void scan1(const int* __restrict__ deg, int* __restrict__ offs,
                                             int* __restrict__ partials, int N_) {
  __shared__ int buf[2][256];
  int tid = threadIdx.x;
  int i = blockIdx.x * 256 + tid;
  int v = (i < N_) ? deg[i] : 0;
  buf[0][tid] = v;
  __syncthreads();
  int cur = 0;
#pragma unroll
  for (int d = 1; d < 256; d <<= 1) {
    int xv = buf[cur][tid];
    if (tid >= d) xv += buf[cur][tid - d];
    buf[cur ^ 1][tid] = xv;
    cur ^= 1;
    __syncthreads();
  }
  int incl = buf[cur][tid];
  if (i < N_) offs[i] = incl - v;
  if (tid == 255) partials[blockIdx.x] = incl;
}

__global__ __launch_bounds__(256) void scan2(int* __restrict__ partials, int* __restrict__ offs,
                                             int nb, int N_) {
  __shared__ int buf[2][256];
  int tid = threadIdx.x;
  int v = (tid < nb) ? partials[tid] : 0;
  buf[0][tid] = v;
  __syncthreads();
  int cur = 0;
#pragma unroll
  for (int d = 1; d < 256; d <<= 1) {
    int xv = buf[cur][tid];
    if (tid >= d) xv += buf[cur][tid - d];
    buf[cur ^ 1][tid] = xv;
    cur ^= 1;
    __syncthreads();
  }
  int incl = buf[cur][tid];
  if (tid < nb) partials[tid] = incl - v;
  if (tid == 255) offs[N_] = incl;
}

__global__ void scan3(int* __restrict__ offs, const int* __restrict__ partials, int N_) {
  int i = blockIdx.x * 256 + threadIdx.x;
  if (i < N_) offs[i] += partials[blockIdx.x];
}

__global__ void fill_csr(const int* __restrict__ ei, const int* __restrict__ offs,
                         int* __restrict__ cursor, int* __restrict__ csr, int E_, int N_) {
  int i = blockIdx.x * 256 + threadIdx.x;
  int s, d;
  if (i < E_) { s = ei[i]; d = ei[E_ + i]; }
  else if (i < E_ + N_) { s = d = i - E_; }
  else return;
  int pos = offs[d] + atomicAdd(&cursor[d], 1);
  csr[pos] = s;
}

// ---------------- graph ranges ----------------
__global__ void graph_ranges(const int* __restrict__ bids, int* __restrict__ gstart,
                             float* __restrict__ invcnt, int N_, int G_) {
  int t = threadIdx.x;
  if (t <= G_) {
    int lo = 0, hi = N_;
    while (lo < hi) { int mid = (lo + hi) >> 1; if (bids[mid] < t) lo = mid + 1; else hi = mid; }
    gstart[t] = lo;
  }
  __syncthreads();
  if (t < G_) {
    int c = gstart[t + 1] - gstart[t];
    invcnt[t] = (c > 0) ? 1.f / (float)c : 0.f;
  }
}

// ---------------- bf16 MFMA GEMM: C[M,Ncols] bf16 = A[M,K]bf16 @ B'[Ncols,K]^T + bias
__global__ __launch_bounds__(256) void gemm_bf16(
    const unsigned short* __restrict__ A, const unsigned short* __restrict__ Bp,
    const float* __restrict__ bias, unsigned short* __restrict__ C, int M, int K, int Ncols) {
  __shared__ unsigned short As[128 * 40];
  __shared__ unsigned short Bs[128 * 40];
  int tid = threadIdx.x;
  int lane = tid & 63;
  int wid = tid >> 6;
  int rowBase = blockIdx.y * 128, colBase = blockIdx.x * 128;
  int wr = (wid >> 1) * 64, wc = (wid & 1) * 64;
  int fr = lane & 15, fg = lane >> 4;
  float4v acc[4][4];
#pragma unroll
  for (int i = 0; i < 4; ++i)
#pragma unroll
    for (int j = 0; j < 4; ++j) acc[i][j] = (float4v){0.f, 0.f, 0.f, 0.f};

  int sr = tid >> 2;
  int sc = tid & 3;
  int off_lo = (sc < 2) ? 32 * sc : 32 * sc - 56;

  for (int k0 = 0; k0 < K; k0 += 32) {
#pragma unroll
    for (int it = 0; it < 2; ++it) {
      int r = it * 64 + sr;
      uint4 va = make_uint4(0u, 0u, 0u, 0u);
      if (rowBase + r < M)
        va = *(const uint4*)(A + (size_t)(rowBase + r) * K + k0 + sc * 8);
      char* arow = (char*)(As + r * 40);
      *(uint2*)(arow + off_lo) = make_uint2(va.x, va.y);
      *(uint2*)(arow + off_lo + 16) = make_uint2(va.z, va.w);
      uint4 vb = *(const uint4*)(Bp + (size_t)(colBase + r) * K + k0 + sc * 8);
      char* brow = (char*)(Bs + r * 40);
      *(uint2*)(brow + off_lo) = make_uint2(vb.x, vb.y);
      *(uint2*)(brow + off_lo + 16) = make_uint2(vb.z, vb.w);
    }
    __syncthreads();
    short8v af[4], bfv[4];
#pragma unroll
    for (int i = 0; i < 4; ++i)
      af[i] = *(const short8v*)((const char*)As + (wr + 16 * i + fr) * 80 + fg * 16);
#pragma unroll
    for (int j = 0; j < 4; ++j)
      bfv[j] = *(const short8v*)((const char*)Bs + (wc + 16 * j + fr) * 80 + fg * 16);
#pragma unroll
    for (int i = 0; i < 4; ++i)
#pragma unroll
      for (int j = 0; j < 4; ++j)
        acc[i][j] = __builtin_amdgcn_mfma_f32_16x16x32_bf16(af[i], bfv[j], acc[i][j], 0, 0, 0);
    __syncthreads();
  }
#pragma unroll
  for (int j = 0; j < 4; ++j) {
    int gc = colBase + wc + 16 * j + fr;
    float bv = bias[gc];
#pragma unroll
    for (int i = 0; i < 4; ++i) {
      int gr0 = rowBase + wr + 16 * i + fg * 4;
#pragma unroll
      for (int rg = 0; rg < 4; ++rg) {
        int gr = gr0 + rg;
        if (gr < M) C[(size_t)gr * Ncols + gc] = f2bf(acc[i][j][rg] + bv);
      }
    }
  }
}

// ---------------- GATv2 aggregation: 1 wave/node, 4 edges in flight (16 lanes/edge) ------
__global__ __launch_bounds__(256) void gat_agg(
    const unsigned short* __restrict__ xlr, int stride,
    const int* __restrict__ csr, const int* __restrict__ offs,
    const float* __restrict__ att, const float* __restrict__ bias,
    float* __restrict__ out, int N) {
  int wid = (blockIdx.x * 256 + threadIdx.x) >> 6;
  if (wid >= N) return;
  int lane = threadIdx.x & 63;
  int q = lane >> 4, ql = lane & 15;   // edge slot, channel group (8 ch each)
  float4 aA = *(const float4*)&att[ql * 8];
  float4 aB = *(const float4*)&att[ql * 8 + 4];
  uint4 ur = *(const uint4*)(xlr + (size_t)wid * stride + 128 + ql * 8);
  float r0 = bflo(ur.x), r1 = bfhi(ur.x), r2 = bflo(ur.y), r3 = bfhi(ur.y);
  float r4 = bflo(ur.z), r5 = bfhi(ur.z), r6 = bflo(ur.w), r7 = bfhi(ur.w);
  float m = -1e30f, L = 0.f;
  float s0 = 0.f, s1 = 0.f, s2 = 0.f, s3 = 0.f, s4 = 0.f, s5 = 0.f, s6 = 0.f, s7 = 0.f;
  int js = offs[wid], je = offs[wid + 1];
  for (int j = js + q; j < je; j += 4) {
    int s = csr[j];
    uint4 u = *(const uint4*)(xlr + (size_t)s * stride + ql * 8);
    float x0 = bflo(u.x), x1 = bfhi(u.x), x2 = bflo(u.y), x3 = bfhi(u.y);
    float x4 = bflo(u.z), x5 = bfhi(u.z), x6 = bflo(u.w), x7 = bfhi(u.w);
    float v0 = fmaxf(r0 + x0, 0.2f * (r0 + x0));
    float v1 = fmaxf(r1 + x1, 0.2f * (r1 + x1));
    float v2 = fmaxf(r2 + x2, 0.2f * (r2 + x2));
    float v3 = fmaxf(r3 + x3, 0.2f * (r3 + x3));
    float v4 = fmaxf(r4 + x4, 0.2f * (r4 + x4));
    float v5 = fmaxf(r5 + x5, 0.2f * (r5 + x5));
    float v6 = fmaxf(r6 + x6, 0.2f * (r6 + x6));
    float v7 = fmaxf(r7 + x7, 0.2f * (r7 + x7));
    float p = aA.x * v0 + aA.y * v1 + aA.z * v2 + aA.w * v3 +
              aB.x * v4 + aB.y * v5 + aB.z * v6 + aB.w * v7;
    p += __shfl_xor(p, 1); p += __shfl_xor(p, 2);
    p += __shfl_xor(p, 4); p += __shfl_xor(p, 8);
    float mn = fmaxf(m, p);
    float ea = __expf(p - mn);
    float es = __expf(m - mn);
    L = L * es + ea;
    s0 = s0 * es + ea * x0; s1 = s1 * es + ea * x1;
    s2 = s2 * es + ea * x2; s3 = s3 * es + ea * x3;
    s4 = s4 * es + ea * x4; s5 = s5 * es + ea * x5;
    s6 = s6 * es + ea * x6; s7 = s7 * es + ea * x7;
    m = mn;
  }
#pragma unroll
  for (int d = 16; d <= 32; d <<= 1) {
    float mo = __shfl_xor(m, d), Lo = __shfl_xor(L, d);
    float t0 = __shfl_xor(s0, d), t1 = __shfl_xor(s1, d);
    float t2 = __shfl_xor(s2, d), t3 = __shfl_xor(s3, d);
    float t4 = __shfl_xor(s4, d), t5 = __shfl_xor(s5, d);
    float t6 = __shfl_xor(s6, d), t7 = __shfl_xor(s7, d);
    float mn = fmaxf(m, mo);
    float e0 = __expf(m - mn), e1 = __expf(mo - mn);
    L = L * e0 + Lo * e1;
    s0 = s0 * e0 + t0 * e1; s1 = s1 * e0 + t1 * e1;
    s2 = s2 * e0 + t2 * e1; s3 = s3 * e0 + t3 * e1;
    s4 = s4 * e0 + t4 * e1; s5 = s5 * e0 + t5 * e1;
    s6 = s6 * e0 + t6 * e1; s7 = s7 * e0 + t7 * e1;
    m = mn;
  }
  if (q == 0) {
    float inv = 1.f / L;
    float4 bA = *(const float4*)&bias[ql * 8];
    float4 bB = *(const float4*)&bias[ql * 8 + 4];
    float4 oA, oB;
    oA.x = s0 * inv + bA.x; oA.y = s1 * inv + bA.y;
    oA.z = s2 * inv + bA.z; oA.w = s3 * inv + bA.w;
    oB.x = s4 * inv + bB.x; oB.y = s5 * inv + bB.y;
    oB.z = s6 * inv + bB.z; oB.w = s7 * inv + bB.w;
    *(float4*)&out[(size_t)wid * DD + ql * 8] = oA;
    *(float4*)&out[(size_t)wid * DD + ql * 8 + 4] = oB;
  }
}

// ---------------- GraphNorm stats ----------------
__global__ __launch_bounds__(256) void gn_stats2(const float* __restrict__ x,
                                                 const int* __restrict__ bids,
                                                 float* __restrict__ gsum,
                                                 float* __restrict__ gsq, int N) {
  int base = blockIdx.x * 128;
  int ch = threadIdx.x & 127;
  int sub = threadIdx.x >> 7;
  int end = base + 128 < N ? base + 128 : N;
  int curg = -1;
  float s = 0.f, q = 0.f;
  for (int r = base + sub; r < end; r += 2) {
    int g = bids[r];
    if (g != curg) {
      if (curg >= 0) {
        atomicAdd(&gsum[curg * DD + ch], s);
        atomicAdd(&gsq[curg * DD + ch], q);
      }
      curg = g; s = 0.f; q = 0.f;
    }
    float v = x[(size_t)r * DD + ch];
    s += v; q += v * v;
  }
  if (curg >= 0) {
    atomicAdd(&gsum[curg * DD + ch], s);
    atomicAdd(&gsq[curg * DD + ch], q);
  }
}

// ---------------- GraphNorm apply + ELU (+residual bf16) -> bf16 ----------------
template <bool ADDRES>
__global__ void gn_apply(const float* __restrict__ xin, unsigned short* __restrict__ xout,
                         const unsigned short* __restrict__ res, int resStride,
                         const int* __restrict__ bids, const float* __restrict__ gsum,
                         const float* __restrict__ gsq, const float* __restrict__ invcnt,
                         const float* __restrict__ w, const float* __restrict__ b,
                         const float* __restrict__ ms, int N) {
  int idx = blockIdx.x * 256 + threadIdx.x;
  if (idx >= N * DD) return;
  int n = idx >> 7, ch = idx & 127;
  int g = bids[n];
  float ic = invcnt[g];
  float mean = gsum[g * DD + ch] * ic;
  float ex2 = gsq[g * DD + ch] * ic;
  float mm = mean * ms[ch];
  float var = ex2 - mm * (2.f * mean - mm);
  float v = (xin[idx] - mm) * rsqrtf(var + 1e-5f) * w[ch] + b[ch];
  if (ADDRES) v += bfu(res[(size_t)n * resStride + ch]);
  v = v > 0.f ? v : (__expf(v) - 1.f);
  xout[idx] = f2bf(v);
}

// ---------------- single-stage LSTM step (f-gate dead, c0=0) ----------------
// Block: 256 thr (4 waves = 2 row x 2 col), 128 rows x 32 h-channels (96 gate cols
// laid out [i|g|o for ch 0-15 | i|g|o for ch 16-31]). Whole K-panel staged to LDS
// (A 128x128k @272B stride, W 96x128k @272B), ONE barrier, then 48 MFMA/wave.
// KD=256 runs two 128-k phases. XCD swizzle: 8 col-chunks of a panel on one XCD.
template <int KD>
__global__ __launch_bounds__(256) void lstm_big(
    const unsigned short* __restrict__ A, const unsigned short* __restrict__ Bp,
    const float* __restrict__ bsum, unsigned short* __restrict__ H, int M) {
  __shared__ __attribute__((aligned(16))) char As_[128 * 272];
  __shared__ __attribute__((aligned(16))) char Ws_[96 * 272];
  int npanel = (M + 127) >> 7;
  int b = blockIdx.x;
  int g8 = b & 7, inner = b >> 3;
  int p = g8 + 8 * (inner >> 3);
  int cc = inner & 7;
  if (p >= npanel) return;
  int rowBase = p << 7;
  int ch0 = cc * 32;

  int tid = threadIdx.x;
  int lane = tid & 63;
  int wid = tid >> 6;
  int wr2 = wid >> 1, wc2 = wid & 1;
  int fr = lane & 15, fg = lane >> 4;

  float4v acc[4][3];
#pragma unroll
  for (int i = 0; i < 4; ++i)
#pragma unroll
    for (int j = 0; j < 3; ++j) acc[i][j] = (float4v){0.f, 0.f, 0.f, 0.f};

#pragma unroll
  for (int ph = 0; ph < KD / 128; ++ph) {
    int koff = ph * 128;
    if (ph) __syncthreads();  // protect LDS reuse from previous phase's reads
    // stage A: 128 rows x 128 k (8 iters x 256 thr x 16B)
#pragma unroll
    for (int q = 0; q < 8; ++q) {
      int t = q * 256 + tid;
      int r = t >> 4, c = (t >> 2) & 3, sc = t & 3;
      uint4 va = make_uint4(0u, 0u, 0u, 0u);
      int gr = rowBase + r;
      if (gr < M) va = *(const uint4*)(A + (size_t)gr * KD + koff + c * 32 + sc * 8);
      int olo = (sc < 2) ? 32 * sc : 32 * sc - 56;
      char* dst = As_ + r * 272 + c * 64;
      *(uint2*)(dst + olo) = make_uint2(va.x, va.y);
      *(uint2*)(dst + olo + 16) = make_uint2(va.z, va.w);
    }
    // stage W: 96 gate rows x 128 k (6 iters)
#pragma unroll
    for (int q = 0; q < 6; ++q) {
      int t = q * 256 + tid;
      int wrow = t >> 4, c = (t >> 2) & 3, sc = t & 3;
      int half = wrow >= 48 ? 1 : 0;
      int r3 = wrow - 48 * half;
      int grp = r3 >> 4;
      int goff = (grp == 0) ? 0 : (grp == 1 ? 512 : 768);
      int grow = goff + ch0 + 16 * half + (r3 & 15);
      uint4 vb = *(const uint4*)(Bp + (size_t)grow * KD + koff + c * 32 + sc * 8);
      int olo = (sc < 2) ? 32 * sc : 32 * sc - 56;
      char* dst = Ws_ + wrow * 272 + c * 64;
      *(uint2*)(dst + olo) = make_uint2(vb.x, vb.y);
      *(uint2*)(dst + olo + 16) = make_uint2(vb.z, vb.w);
    }
    __syncthreads();
    // compute: 4 chunks x (4 a-frags x 3 gate-frags)
#pragma unroll
    for (int c = 0; c < 4; ++c) {
      short8v af[4], bf[3];
#pragma unroll
      for (int i = 0; i < 4; ++i)
        af[i] = *(const short8v*)(As_ + (64 * wr2 + 16 * i + fr) * 272 + c * 64 + fg * 16);
#pragma unroll
      for (int j = 0; j < 3; ++j)
        bf[j] = *(const short8v*)(Ws_ + (48 * wc2 + 16 * j + fr) * 272 + c * 64 + fg * 16);
#pragma unroll
      for (int i = 0; i < 4; ++i)
#pragma unroll
        for (int j = 0; j < 3; ++j)
          acc[i][j] = __builtin_amdgcn_mfma_f32_16x16x32_bf16(af[i], bf[j], acc[i][j], 0, 0, 0);
    }
  }
  // epilogue: lane owns (i,g,o) for channel ch, 16 rows
  int ch = ch0 + 16 * wc2 + fr;
  float bi = bsum[ch], bg = bsum[512 + ch], bo = bsum[768 + ch];
#pragma unroll
  for (int i = 0; i < 4; ++i) {
#pragma unroll
    for (int rg = 0; rg < 4; ++rg) {
      int row = rowBase + 64 * wr2 + 16 * i + 4 * fg + rg;
      if (row < M) {
        float iv = acc[i][0][rg] + bi;
        float gv = acc[i][1][rg] + bg;
        float ov = acc[i][2][rg] + bo;
        float c = sigm_(iv) * tanh_(gv);
        H[(size_t)row * LSTMH + ch] = f2bf(sigm_(ov) * tanh_(c));
      }
    }
  }
}

// ---------------- LayerNorm + mean pool: 1 wave per 8 rows, register pooling ----------
__global__ __launch_bounds__(256) void ln_pool2(
    const unsigned short* __restrict__ h2, const int* __restrict__ bids,
    const float* __restrict__ lnw, const float* __restrict__ lnb,
    const float* __restrict__ invcnt, float* __restrict__ pooled, int N) {
  int wave = (blockIdx.x * 256 + threadIdx.x) >> 6;
  int lane = threadIdx.x & 63;
  int r0 = wave * 8;
  if (r0 >= N) return;
  float4 w4 = *(const float4*)&lnw[lane * 4];
  float4 b4 = *(const float4*)&lnb[lane * 4];
  float p0 = 0.f, p1 = 0.f, p2 = 0.f, p3 = 0.f;
  int curg = bids[r0];
  int rend = r0 + 8 < N ? r0 + 8 : N;
  for (int r = r0; r < rend; ++r) {
    int g = bids[r];
    if (g != curg) {
      float ic = invcnt[curg];
      atomicAdd(&pooled[curg * LSTMH + lane * 4 + 0], p0 * ic);
      atomicAdd(&pooled[curg * LSTMH + lane * 4 + 1], p1 * ic);
      atomicAdd(&pooled[curg * LSTMH + lane * 4 + 2], p2 * ic);
      atomicAdd(&pooled[curg * LSTMH + lane * 4 + 3], p3 * ic);
      p0 = p1 = p2 = p3 = 0.f;
      curg = g;
    }
    uint2 u = *(const uint2*)(h2 + (size_t)r * LSTMH + lane * 4);
    float v0 = bflo(u.x), v1 = bfhi(u.x), v2 = bflo(u.y), v3 = bfhi(u.y);
    float s = v0 + v1 + v2 + v3;
    float q = v0 * v0 + v1 * v1 + v2 * v2 + v3 * v3;
#pragma unroll
    for (int d = 1; d < 64; d <<= 1) { s += __shfl_xor(s, d); q += __shfl_xor(q, d); }
    float mu = s * (1.f / 256.f);
    float var = q * (1.f / 256.f) - mu * mu;
    float rs = rsqrtf(var + 1e-5f);
    p0 += w4.x * (v0 - mu) * rs + b4.x;
    p1 += w4.y * (v1 - mu) * rs + b4.y;
    p2 += w4.z * (v2 - mu) * rs + b4.z;
    p3 += w4.w * (v3 - mu) * rs + b4.w;
  }
  float ic = invcnt[curg];
  atomicAdd(&pooled[curg * LSTMH + lane * 4 + 0], p0 * ic);
  atomicAdd(&pooled[curg * LSTMH + lane * 4 + 1], p1 * ic);
  atomicAdd(&pooled[curg * LSTMH + lane * 4 + 2], p2 * ic);
  atomicAdd(&pooled[curg * LSTMH + lane * 4 + 3], p3 * ic);
}

// ---------------- FC + log_softmax ----------------
__global__ __launch_bounds__(64) void fc_lsm(const float* __restrict__ pooled,
                                             const float* __restrict__ W,
                                             const float* __restrict__ b, float* __restrict__ out) {
  int g = blockIdx.x;
  int t = threadIdx.x;
  float l0 = 0.f, l1 = 0.f, l2 = 0.f, l3 = 0.f;
  for (int k = t; k < LSTMH; k += 64) {
    float p = pooled[g * LSTMH + k];
    l0 += p * W[k * 4 + 0];
    l1 += p * W[k * 4 + 1];
    l2 += p * W[k * 4 + 2];
    l3 += p * W[k * 4 + 3];
  }
#pragma unroll
  for (int d = 1; d < 64; d <<= 1) {
    l0 += __shfl_xor(l0, d); l1 += __shfl_xor(l1, d);
    l2 += __shfl_xor(l2, d); l3 += __shfl_xor(l3, d);
  }
  if (t == 0) {
    float z[4] = {l0 + b[0], l1 + b[1], l2 + b[2], l3 + b[3]};
    float mx = fmaxf(fmaxf(z[0], z[1]), fmaxf(z[2], z[3]));
    float sum = __expf(z[0] - mx) + __expf(z[1] - mx) + __expf(z[2] - mx) + __expf(z[3] - mx);
    float ls = logf(sum);
#pragma unroll
    for (int o = 0; o < 4; ++o) out[g * 4 + o] = z[o] - mx - ls;
  }
}

// ---------------- host launch ----------------
extern "C" void kernel_launch(void* const* d_in, const int* in_sizes, int n_in,
                              void* d_out, int out_size, void* d_ws, size_t ws_size,
                              hipStream_t stream) {
  const int* node_labels = (const int*)d_in[0];
  const int* node_types = (const int*)d_in[1];
  const float* node_feat = (const float*)d_in[2];
  const int* edge_index = (const int*)d_in[3];
  const int* batch_ids = (const int*)d_in[4];
  const float* emb_label = (const float*)d_in[5];
  const float* emb_type = (const float*)d_in[6];
  const float* W_in = (const float*)d_in[7];
  const float* b_in = (const float*)d_in[8];
  const float* g1_Wl = (const float*)d_in[9];
  const float* g1_bl = (const float*)d_in[10];
  const float* g1_Wr = (const float*)d_in[11];
  const float* g1_br = (const float*)d_in[12];
  const float* g1_att = (const float*)d_in[13];
  const float* g1_bias = (const float*)d_in[14];
  const float* gn1_w = (const float*)d_in[15];
  const float* gn1_b = (const float*)d_in[16];
  const float* gn1_ms = (const float*)d_in[17];
  const float* g2_Wl = (const float*)d_in[18];
  const float* g2_bl = (const float*)d_in[19];
  const float* g2_Wr = (const float*)d_in[20];
  const float* g2_br = (const float*)d_in[21];
  const float* g2_att = (const float*)d_in[22];
  const float* g2_bias = (const float*)d_in[23];
  const float* gn2_w = (const float*)d_in[24];
  const float* gn2_b = (const float*)d_in[25];
  const float* gn2_ms = (const float*)d_in[26];
  const float* W_res = (const float*)d_in[27];
  const float* b_res = (const float*)d_in[28];
  const float* l1_Wih = (const float*)d_in[29];
  const float* l1_bih = (const float*)d_in[31];
  const float* l1_bhh = (const float*)d_in[32];
  const float* l2_Wih = (const float*)d_in[33];
  const float* l2_bih = (const float*)d_in[35];
  const float* l2_bhh = (const float*)d_in[36];
  const float* ln_w = (const float*)d_in[37];
  const float* ln_b = (const float*)d_in[38];
  const float* fc_W = (const float*)d_in[39];
  const float* fc_b = (const float*)d_in[40];
  float* out = (float*)d_out;

  const int N = in_sizes[0];
  const int E = in_sizes[3] / 2;
  const int G = out_size / 4;
  const int ET = E + N;

  char* wsb = (char*)d_ws;
  size_t off = 0;
  auto alloc = [&](size_t bytes) -> void* {
    void* p = (void*)(wsb + off);
    off = (off + bytes + 255) & ~(size_t)255;
    return p;
  };
  float* xA = (float*)alloc((size_t)N * DD * 4);                      // gat out f32; later h2 bf16
  unsigned short* xb = (unsigned short*)alloc((size_t)N * DD * 2);    // bf16 x / x1 / x2
  unsigned short* xlr = (unsigned short*)alloc((size_t)N * 384 * 2);  // xl|xr(|res); later h1
  int* deg = (int*)alloc((size_t)N * 4);
  int* offs = (int*)alloc((size_t)(N + 1) * 4);
  int* cursor = (int*)alloc((size_t)N * 4);
  int* partials = (int*)alloc(1024);
  int* csr = (int*)alloc((size_t)ET * 4);
  int* gstart = (int*)alloc((size_t)(G + 1) * 4);
  float* invcnt = (float*)alloc((size_t)G * 4);
  float* gsum = (float*)alloc((size_t)G * DD * 4);
  float* gsq = (float*)alloc((size_t)G * DD * 4);
  float* pooled = (float*)alloc((size_t)G * LSTMH * 4);
  float* bcat1 = (float*)alloc(256 * 4);
  float* bcat2 = (float*)alloc(384 * 4);
  float* bsum1 = (float*)alloc(ZG * 4);
  float* bsum2 = (float*)alloc(ZG * 4);
  unsigned short* wcat1 = (unsigned short*)alloc((size_t)256 * DD * 2);
  unsigned short* wcat2 = (unsigned short*)alloc((size_t)384 * DD * 2);
  unsigned short* wl1b = (unsigned short*)alloc((size_t)ZG * DD * 2);
  unsigned short* wl2b = (unsigned short*)alloc((size_t)ZG * LSTMH * 2);
  (void)ws_size; (void)n_in;

  unsigned short* h1 = xlr;                  // [N][256] bf16, written after xlr dead
  unsigned short* h2 = (unsigned short*)xA;  // [N][256] bf16, written after xA dead

  hipMemsetAsync(deg, 0, (size_t)N * 4, stream);
  hipMemsetAsync(cursor, 0, (size_t)N * 4, stream);
  hipMemsetAsync(pooled, 0, (size_t)G * LSTMH * 4, stream);

  // weight prep
  cvt_transpose<<<cdiv_(DD * DD, 256), 256, 0, stream>>>(g1_Wl, wcat1, DD, DD);
  cvt_transpose<<<cdiv_(DD * DD, 256), 256, 0, stream>>>(g1_Wr, wcat1 + DD * DD, DD, DD);
  cvt_transpose<<<cdiv_(DD * DD, 256), 256, 0, stream>>>(g2_Wl, wcat2, DD, DD);
  cvt_transpose<<<cdiv_(DD * DD, 256), 256, 0, stream>>>(g2_Wr, wcat2 + DD * DD, DD, DD);
  cvt_transpose<<<cdiv_(DD * DD, 256), 256, 0, stream>>>(W_res, wcat2 + 2 * DD * DD, DD, DD);
  cvt_direct<<<cdiv_(ZG * DD, 256), 256, 0, stream>>>(l1_Wih, wl1b, ZG * DD);
  cvt_direct<<<cdiv_(ZG * LSTMH, 256), 256, 0, stream>>>(l2_Wih, wl2b, ZG * LSTMH);
  prep_small<<<4, 256, 0, stream>>>(g1_bl, g1_br, g2_bl, g2_br, b_res, l1_bih, l1_bhh,
                                    l2_bih, l2_bhh, bcat1, bcat2, bsum1, bsum2);

  graph_ranges<<<1, 128, 0, stream>>>(batch_ids, gstart, invcnt, N, G);
  embed_in<<<N, 128, 0, stream>>>(node_labels, node_types, node_feat, emb_label, emb_type,
                                  W_in, b_in, xb, N);

  // CSR by dst
  count_deg<<<cdiv_(ET, 256), 256, 0, stream>>>(edge_index, deg, E, N);
  int nb1 = cdiv_(N, 256);
  scan1<<<nb1, 256, 0, stream>>>(deg, offs, partials, N);
  scan2<<<1, 256, 0, stream>>>(partials, offs, nb1, N);
  scan3<<<nb1, 256, 0, stream>>>(offs, partials, N);
  fill_csr<<<cdiv_(ET, 256), 256, 0, stream>>>(edge_index, offs, cursor, csr, E, N);

  int mb = cdiv_(N, 128);
  // ---- GAT layer 1: [xl|xr] in one GEMM ----
  gemm_bf16<<<dim3(2, mb), 256, 0, stream>>>(xb, wcat1, bcat1, xlr, N, DD, 256);
  gat_agg<<<cdiv_(N, 4), 256, 0, stream>>>(xlr, 256, csr, offs, g1_att, g1_bias, xA, N);
  hipMemsetAsync(gsum, 0, (size_t)G * DD * 8, stream);  // gsum+gsq contiguous
  gn_stats2<<<cdiv_(N, 128), 256, 0, stream>>>(xA, batch_ids, gsum, gsq, N);
  gn_apply<false><<<cdiv_(N * DD, 256), 256, 0, stream>>>(
      xA, xb, nullptr, 0, batch_ids, gsum, gsq, invcnt, gn1_w, gn1_b, gn1_ms, N);
  // ---- GAT layer 2: [xl|xr|res] in one GEMM ----
  gemm_bf16<<<dim3(3, mb), 256, 0, stream>>>(xb, wcat2, bcat2, xlr, N, DD, 384);
  gat_agg<<<cdiv_(N, 4), 256, 0, stream>>>(xlr, 384, csr, offs, g2_att, g2_bias, xA, N);
  hipMemsetAsync(gsum, 0, (size_t)G * DD * 8, stream);
  gn_stats2<<<cdiv_(N, 128), 256, 0, stream>>>(xA, batch_ids, gsum, gsq, N);
  gn_apply<true><<<cdiv_(N * DD, 256), 256, 0, stream>>>(
      xA, xb, xlr + 256, 384, batch_ids, gsum, gsq, invcnt, gn2_w, gn2_b, gn2_ms, N);
  // ---- LSTM x2: single-stage blocks, XCD-swizzled ----
  int npanel = cdiv_(N, 128);
  int lblocks = 64 * cdiv_(npanel, 8);
  lstm_big<DD><<<lblocks, 256, 0, stream>>>(xb, wl1b, bsum1, h1, N);
  lstm_big<LSTMH><<<lblocks, 256, 0, stream>>>(h1, wl2b, bsum2, h2, N);
  // ---- LN + mean pool + FC ----
  ln_pool2<<<cdiv_(N, 32), 256, 0, stream>>>(h2, batch_ids, ln_w, ln_b, invcnt, pooled, N);
  fc_lsm<<<G, 64, 0, stream>>>(pooled, fc_W, fc_b, out);
}

// Round 7
// 533.638 us; speedup vs baseline: 1.3156x; 1.0671x over previous
//
#include <hip/hip_runtime.h>
#include <cstdint>
#include <cstddef>

#define DD 128
#define LSTMH 256
#define ZG 1024

typedef __attribute__((ext_vector_type(8))) short short8v;
typedef __attribute__((ext_vector_type(4))) float float4v;

static inline int cdiv_(int a, int b) { return (a + b - 1) / b; }

__device__ __forceinline__ float sigm_(float x) { return 1.f / (1.f + __expf(-x)); }
__device__ __forceinline__ float tanh_(float x) {
  float e = __expf(-2.f * fabsf(x));
  float r = (1.f - e) / (1.f + e);
  return copysignf(r, x);
}

__device__ __forceinline__ unsigned short f2bf(float f) {
  uint32_t u = __float_as_uint(f);
  u += 0x7fffu + ((u >> 16) & 1u);
  return (unsigned short)(u >> 16);
}
__device__ __forceinline__ float bflo(uint32_t u) { return __uint_as_float(u << 16); }
__device__ __forceinline__ float bfhi(uint32_t u) { return __uint_as_float(u & 0xffff0000u); }
__device__ __forceinline__ float bfu(unsigned short u) { return __uint_as_float((uint32_t)u << 16); }

// ---------------- weight conversion ----------------
__global__ void cvt_direct(const float* __restrict__ W, unsigned short* __restrict__ o, int n) {
  int i = blockIdx.x * 256 + threadIdx.x;
  if (i < n) o[i] = f2bf(W[i]);
}

// W[K][M] row-major -> o[M][K] bf16
__global__ void cvt_transpose(const float* __restrict__ W, unsigned short* __restrict__ o,
                              int K, int M) {
  int i = blockIdx.x * 256 + threadIdx.x;
  if (i >= K * M) return;
  int m = i / K, k = i - m * K;
  o[i] = f2bf(W[(size_t)k * M + m]);
}

// bias concat + lstm bias sums
__global__ void prep_small(const float* g1bl, const float* g1br, const float* g2bl,
                           const float* g2br, const float* bres, const float* l1bih,
                           const float* l1bhh, const float* l2bih, const float* l2bhh,
                           float* bcat1, float* bcat2, float* bsum1, float* bsum2) {
  int t = blockIdx.x * 256 + threadIdx.x;
  if (t < 256) bcat1[t] = t < 128 ? g1bl[t] : g1br[t - 128];
  if (t < 384) bcat2[t] = t < 128 ? g2bl[t] : (t < 256 ? g2br[t - 128] : bres[t - 256]);
  if (t < ZG) { bsum1[t] = l1bih[t] + l1bhh[t]; bsum2[t] = l2bih[t] + l2bhh[t]; }
}

// ---------------- input embedding + W_in GEMV (K=33) -> bf16 ----------------
__global__ __launch_bounds__(128) void embed_in(
    const int* __restrict__ labels, const int* __restrict__ types,
    const float* __restrict__ nf, const float* __restrict__ embL,
    const float* __restrict__ embT, const float* __restrict__ W,
    const float* __restrict__ b, unsigned short* __restrict__ x, int N) {
  int n = blockIdx.x;
  if (n >= N) return;
  int t = threadIdx.x;
  __shared__ float f[33];
  if (t < 16) f[t] = embL[labels[n] * 16 + t];
  else if (t < 32) f[t] = embT[types[n] * 16 + (t - 16)];
  else if (t == 32) f[32] = nf[n];
  __syncthreads();
  float acc = b[t];
#pragma unroll
  for (int k = 0; k < 33; ++k) acc += f[k] * W[k * DD + t];
  x[(size_t)n * DD + t] = f2bf(acc);
}

// ---------------- CSR build ----------------
__global__ void count_deg(const int* __restrict__ ei, int* __restrict__ deg, int E_, int N_) {
  int i = blockIdx.x * 256 + threadIdx.x;
  if (i < E_) atomicAdd(&deg[ei[E_ + i]], 1);
  else if (i < E_ + N_) atomicAdd(&deg[i - E_], 1);
}

__global__ __launch_bounds__(256) void scan1(const int* __restrict__ deg, int* __restrict__ offs,
                                             int* __restrict__ partials, int N_) {
  __shared__ int buf[2][256];
  int tid = threadIdx.x;
  int i = blockIdx.x * 256 + tid;
  int v = (i < N_) ? deg[i] : 0;
  buf[0][tid] = v;
  __syncthreads();
  int cur = 0;
#pragma unroll
  for (int d = 1; d < 256; d <<= 1) {
    int xv = buf[cur][tid];
    if (tid >= d) xv += buf[cur][tid - d];
    buf[cur ^ 1][tid] = xv;
    cur ^= 1;
    __syncthreads();
  }
  int incl = buf[cur][tid];
  if (i < N_) offs[i] = incl - v;
  if (tid == 255) partials[blockIdx.x] = incl;
}

__global__ __launch_bounds__(256) void scan2(int* __restrict__ partials, int* __restrict__ offs,
                                             int nb, int N_) {
  __shared__ int buf[2][256];
  int tid = threadIdx.x;
  int v = (tid < nb) ? partials[tid] : 0;
  buf[0][tid] = v;
  __syncthreads();
  int cur = 0;
#pragma unroll
  for (int d = 1; d < 256; d <<= 1) {
    int xv = buf[cur][tid];
    if (tid >= d) xv += buf[cur][tid - d];
    buf[cur ^ 1][tid] = xv;
    cur ^= 1;
    __syncthreads();
  }
  int incl = buf[cur][tid];
  if (tid < nb) partials[tid] = incl - v;
  if (tid == 255) offs[N_] = incl;
}

__global__ void scan3(int* __restrict__ offs, const int* __restrict__ partials, int N_) {
  int i = blockIdx.x * 256 + threadIdx.x;
  if (i < N_) offs[i] += partials[blockIdx.x];
}

__global__ void fill_csr(const int* __restrict__ ei, const int* __restrict__ offs,
                         int* __restrict__ cursor, int* __restrict__ csr, int E_, int N_) {
  int i = blockIdx.x * 256 + threadIdx.x;
  int s, d;
  if (i < E_) { s = ei[i]; d = ei[E_ + i]; }
  else if (i < E_ + N_) { s = d = i - E_; }
  else return;
  int pos = offs[d] + atomicAdd(&cursor[d], 1);
  csr[pos] = s;
}

// ---------------- graph ranges ----------------
__global__ void graph_ranges(const int* __restrict__ bids, int* __restrict__ gstart,
                             float* __restrict__ invcnt, int N_, int G_) {
  int t = threadIdx.x;
  if (t <= G_) {
    int lo = 0, hi = N_;
    while (lo < hi) { int mid = (lo + hi) >> 1; if (bids[mid] < t) lo = mid + 1; else hi = mid; }
    gstart[t] = lo;
  }
  __syncthreads();
  if (t < G_) {
    int c = gstart[t + 1] - gstart[t];
    invcnt[t] = (c > 0) ? 1.f / (float)c : 0.f;
  }
}

// ---------------- bf16 MFMA GEMM: C[M,Ncols] bf16 = A[M,K]bf16 @ B'[Ncols,K]^T + bias
__global__ __launch_bounds__(256) void gemm_bf16(
    const unsigned short* __restrict__ A, const unsigned short* __restrict__ Bp,
    const float* __restrict__ bias, unsigned short* __restrict__ C, int M, int K, int Ncols) {
  __shared__ unsigned short As[128 * 40];
  __shared__ unsigned short Bs[128 * 40];
  int tid = threadIdx.x;
  int lane = tid & 63;
  int wid = tid >> 6;
  int rowBase = blockIdx.y * 128, colBase = blockIdx.x * 128;
  int wr = (wid >> 1) * 64, wc = (wid & 1) * 64;
  int fr = lane & 15, fg = lane >> 4;
  float4v acc[4][4];
#pragma unroll
  for (int i = 0; i < 4; ++i)
#pragma unroll
    for (int j = 0; j < 4; ++j) acc[i][j] = (float4v){0.f, 0.f, 0.f, 0.f};

  int sr = tid >> 2;
  int sc = tid & 3;
  int off_lo = (sc < 2) ? 32 * sc : 32 * sc - 56;

  for (int k0 = 0; k0 < K; k0 += 32) {
#pragma unroll
    for (int it = 0; it < 2; ++it) {
      int r = it * 64 + sr;
      uint4 va = make_uint4(0u, 0u, 0u, 0u);
      if (rowBase + r < M)
        va = *(const uint4*)(A + (size_t)(rowBase + r) * K + k0 + sc * 8);
      char* arow = (char*)(As + r * 40);
      *(uint2*)(arow + off_lo) = make_uint2(va.x, va.y);
      *(uint2*)(arow + off_lo + 16) = make_uint2(va.z, va.w);
      uint4 vb = *(const uint4*)(Bp + (size_t)(colBase + r) * K + k0 + sc * 8);
      char* brow = (char*)(Bs + r * 40);
      *(uint2*)(brow + off_lo) = make_uint2(vb.x, vb.y);
      *(uint2*)(brow + off_lo + 16) = make_uint2(vb.z, vb.w);
    }
    __syncthreads();
    short8v af[4], bfv[4];
#pragma unroll
    for (int i = 0; i < 4; ++i)
      af[i] = *(const short8v*)((const char*)As + (wr + 16 * i + fr) * 80 + fg * 16);
#pragma unroll
    for (int j = 0; j < 4; ++j)
      bfv[j] = *(const short8v*)((const char*)Bs + (wc + 16 * j + fr) * 80 + fg * 16);
#pragma unroll
    for (int i = 0; i < 4; ++i)
#pragma unroll
      for (int j = 0; j < 4; ++j)
        acc[i][j] = __builtin_amdgcn_mfma_f32_16x16x32_bf16(af[i], bfv[j], acc[i][j], 0, 0, 0);
    __syncthreads();
  }
#pragma unroll
  for (int j = 0; j < 4; ++j) {
    int gc = colBase + wc + 16 * j + fr;
    float bv = bias[gc];
#pragma unroll
    for (int i = 0; i < 4; ++i) {
      int gr0 = rowBase + wr + 16 * i + fg * 4;
#pragma unroll
      for (int rg = 0; rg < 4; ++rg) {
        int gr = gr0 + rg;
        if (gr < M) C[(size_t)gr * Ncols + gc] = f2bf(acc[i][j][rg] + bv);
      }
    }
  }
}

// ---------------- GATv2 aggregation: 1 wave/node, 4 edges in flight (16 lanes/edge) ------
__global__ __launch_bounds__(256) void gat_agg(
    const unsigned short* __restrict__ xlr, int stride,
    const int* __restrict__ csr, const int* __restrict__ offs,
    const float* __restrict__ att, const float* __restrict__ bias,
    float* __restrict__ out, int N) {
  int wid = (blockIdx.x * 256 + threadIdx.x) >> 6;
  if (wid >= N) return;
  int lane = threadIdx.x & 63;
  int q = lane >> 4, ql = lane & 15;   // edge slot, channel group (8 ch each)
  float4 aA = *(const float4*)&att[ql * 8];
  float4 aB = *(const float4*)&att[ql * 8 + 4];
  uint4 ur = *(const uint4*)(xlr + (size_t)wid * stride + 128 + ql * 8);
  float r0 = bflo(ur.x), r1 = bfhi(ur.x), r2 = bflo(ur.y), r3 = bfhi(ur.y);
  float r4 = bflo(ur.z), r5 = bfhi(ur.z), r6 = bflo(ur.w), r7 = bfhi(ur.w);
  float m = -1e30f, L = 0.f;
  float s0 = 0.f, s1 = 0.f, s2 = 0.f, s3 = 0.f, s4 = 0.f, s5 = 0.f, s6 = 0.f, s7 = 0.f;
  int js = offs[wid], je = offs[wid + 1];
  for (int j = js + q; j < je; j += 4) {
    int s = csr[j];
    uint4 u = *(const uint4*)(xlr + (size_t)s * stride + ql * 8);
    float x0 = bflo(u.x), x1 = bfhi(u.x), x2 = bflo(u.y), x3 = bfhi(u.y);
    float x4 = bflo(u.z), x5 = bfhi(u.z), x6 = bflo(u.w), x7 = bfhi(u.w);
    float v0 = fmaxf(r0 + x0, 0.2f * (r0 + x0));
    float v1 = fmaxf(r1 + x1, 0.2f * (r1 + x1));
    float v2 = fmaxf(r2 + x2, 0.2f * (r2 + x2));
    float v3 = fmaxf(r3 + x3, 0.2f * (r3 + x3));
    float v4 = fmaxf(r4 + x4, 0.2f * (r4 + x4));
    float v5 = fmaxf(r5 + x5, 0.2f * (r5 + x5));
    float v6 = fmaxf(r6 + x6, 0.2f * (r6 + x6));
    float v7 = fmaxf(r7 + x7, 0.2f * (r7 + x7));
    float p = aA.x * v0 + aA.y * v1 + aA.z * v2 + aA.w * v3 +
              aB.x * v4 + aB.y * v5 + aB.z * v6 + aB.w * v7;
    p += __shfl_xor(p, 1); p += __shfl_xor(p, 2);
    p += __shfl_xor(p, 4); p += __shfl_xor(p, 8);
    float mn = fmaxf(m, p);
    float ea = __expf(p - mn);
    float es = __expf(m - mn);
    L = L * es + ea;
    s0 = s0 * es + ea * x0; s1 = s1 * es + ea * x1;
    s2 = s2 * es + ea * x2; s3 = s3 * es + ea * x3;
    s4 = s4 * es + ea * x4; s5 = s5 * es + ea * x5;
    s6 = s6 * es + ea * x6; s7 = s7 * es + ea * x7;
    m = mn;
  }
#pragma unroll
  for (int d = 16; d <= 32; d <<= 1) {
    float mo = __shfl_xor(m, d), Lo = __shfl_xor(L, d);
    float t0 = __shfl_xor(s0, d), t1 = __shfl_xor(s1, d);
    float t2 = __shfl_xor(s2, d), t3 = __shfl_xor(s3, d);
    float t4 = __shfl_xor(s4, d), t5 = __shfl_xor(s5, d);
    float t6 = __shfl_xor(s6, d), t7 = __shfl_xor(s7, d);
    float mn = fmaxf(m, mo);
    float e0 = __expf(m - mn), e1 = __expf(mo - mn);
    L = L * e0 + Lo * e1;
    s0 = s0 * e0 + t0 * e1; s1 = s1 * e0 + t1 * e1;
    s2 = s2 * e0 + t2 * e1; s3 = s3 * e0 + t3 * e1;
    s4 = s4 * e0 + t4 * e1; s5 = s5 * e0 + t5 * e1;
    s6 = s6 * e0 + t6 * e1; s7 = s7 * e0 + t7 * e1;
    m = mn;
  }
  if (q == 0) {
    float inv = 1.f / L;
    float4 bA = *(const float4*)&bias[ql * 8];
    float4 bB = *(const float4*)&bias[ql * 8 + 4];
    float4 oA, oB;
    oA.x = s0 * inv + bA.x; oA.y = s1 * inv + bA.y;
    oA.z = s2 * inv + bA.z; oA.w = s3 * inv + bA.w;
    oB.x = s4 * inv + bB.x; oB.y = s5 * inv + bB.y;
    oB.z = s6 * inv + bB.z; oB.w = s7 * inv + bB.w;
    *(float4*)&out[(size_t)wid * DD + ql * 8] = oA;
    *(float4*)&out[(size_t)wid * DD + ql * 8 + 4] = oB;
  }
}

// ---------------- GraphNorm stats ----------------
__global__ __launch_bounds__(256) void gn_stats2(const float* __restrict__ x,
                                                 const int* __restrict__ bids,
                                                 float* __restrict__ gsum,
                                                 float* __restrict__ gsq, int N) {
  int base = blockIdx.x * 128;
  int ch = threadIdx.x & 127;
  int sub = threadIdx.x >> 7;
  int end = base + 128 < N ? base + 128 : N;
  int curg = -1;
  float s = 0.f, q = 0.f;
  for (int r = base + sub; r < end; r += 2) {
    int g = bids[r];
    if (g != curg) {
      if (curg >= 0) {
        atomicAdd(&gsum[curg * DD + ch], s);
        atomicAdd(&gsq[curg * DD + ch], q);
      }
      curg = g; s = 0.f; q = 0.f;
    }
    float v = x[(size_t)r * DD + ch];
    s += v; q += v * v;
  }
  if (curg >= 0) {
    atomicAdd(&gsum[curg * DD + ch], s);
    atomicAdd(&gsq[curg * DD + ch], q);
  }
}

// ---------------- GraphNorm apply + ELU (+residual bf16) -> bf16 ----------------
template <bool ADDRES>
__global__ void gn_apply(const float* __restrict__ xin, unsigned short* __restrict__ xout,
                         const unsigned short* __restrict__ res, int resStride,
                         const int* __restrict__ bids, const float* __restrict__ gsum,
                         const float* __restrict__ gsq, const float* __restrict__ invcnt,
                         const float* __restrict__ w, const float* __restrict__ b,
                         const float* __restrict__ ms, int N) {
  int idx = blockIdx.x * 256 + threadIdx.x;
  if (idx >= N * DD) return;
  int n = idx >> 7, ch = idx & 127;
  int g = bids[n];
  float ic = invcnt[g];
  float mean = gsum[g * DD + ch] * ic;
  float ex2 = gsq[g * DD + ch] * ic;
  float mm = mean * ms[ch];
  float var = ex2 - mm * (2.f * mean - mm);
  float v = (xin[idx] - mm) * rsqrtf(var + 1e-5f) * w[ch] + b[ch];
  if (ADDRES) v += bfu(res[(size_t)n * resStride + ch]);
  v = v > 0.f ? v : (__expf(v) - 1.f);
  xout[idx] = f2bf(v);
}

// ---------------- single-stage LSTM step, 512 thr, reg-prefetch, coalesced store --------
// Block: 512 thr (8 waves = 4 row-groups x 2 col-groups), 128 rows x 32 h-channels.
// Whole 128-k slab staged (A 128r, W 96 gate rows, 272B stride) -> one barrier -> MFMA.
// KD=256: phase-2 loads issued into regs BEFORE phase-1 compute (latency hidden).
// f-gate dead (c0=0). Epilogue: LDS transpose (reuse As_) -> uint4 coalesced H stores.
// XCD swizzle: 8 col-chunks of one panel stay on one XCD.
template <int KD>
__global__ __launch_bounds__(512, 4) void lstm_big(
    const unsigned short* __restrict__ A, const unsigned short* __restrict__ Bp,
    const float* __restrict__ bsum, unsigned short* __restrict__ H, int M) {
  __shared__ __attribute__((aligned(16))) char As_[128 * 272];
  __shared__ __attribute__((aligned(16))) char Ws_[96 * 272];
  const int NPH = KD / 128;
  int npanel = (M + 127) >> 7;
  int b = blockIdx.x;
  int g8 = b & 7, inner = b >> 3;
  int p = g8 + 8 * (inner >> 3);
  int cc = inner & 7;
  if (p >= npanel) return;
  int rowBase = p << 7;
  int ch0 = cc * 32;

  int tid = threadIdx.x;
  int lane = tid & 63;
  int wid = tid >> 6;
  int wr4 = wid >> 1;   // 0..3 row-group (32 rows)
  int wc2 = wid & 1;    // 0..1 col-group (16 ch -> 48 gate rows)
  int fr = lane & 15, fg = lane >> 4;

  // per-thread staging descriptors (fixed across phases)
  int ar[4], ac[4], aolo[4], aldst[4];
#pragma unroll
  for (int q = 0; q < 4; ++q) {
    int e = q * 512 + tid;
    int r = e >> 4, kk = e & 15;
    int c = kk >> 2, sc = kk & 3;
    ar[q] = r; ac[q] = c;
    aolo[q] = (sc < 2) ? 32 * sc : 32 * sc - 56;
    aldst[q] = r * 272 + c * 64;
  }
  int wgrow[3], wc_[3], wolo[3], wldst[3];
#pragma unroll
  for (int q = 0; q < 3; ++q) {
    int e = q * 512 + tid;
    int wrow = e >> 4, kk = e & 15;
    int c = kk >> 2, sc = kk & 3;
    int half = wrow >= 48 ? 1 : 0;
    int r3 = wrow - 48 * half;
    int grp = r3 >> 4;
    int goff = (grp == 0) ? 0 : (grp == 1 ? 512 : 768);
    wgrow[q] = goff + ch0 + 16 * half + (r3 & 15);
    wc_[q] = c;
    wolo[q] = (sc < 2) ? 32 * sc : 32 * sc - 56;
    wldst[q] = wrow * 272 + c * 64;
  }

  float4v acc[2][3];
#pragma unroll
  for (int i = 0; i < 2; ++i)
#pragma unroll
    for (int j = 0; j < 3; ++j) acc[i][j] = (float4v){0.f, 0.f, 0.f, 0.f};

  // prologue: load phase-0 slabs into registers
  uint4 va[4], vw[3];
#pragma unroll
  for (int q = 0; q < 4; ++q) {
    va[q] = make_uint4(0u, 0u, 0u, 0u);
    if (rowBase + ar[q] < M)
      va[q] = *(const uint4*)(A + (size_t)(rowBase + ar[q]) * KD + ac[q] * 32 + (aolo[q] == 32 || aolo[q] == 40 ? 0 : 0) + ((aolo[q] < 32) ? (aolo[q] >> 5) * 0 : 0) + 0 + ((q * 512 + tid) & 3) * 8);
  }
  // NOTE: recompute cleanly (the above folds to sc*8); do it explicitly:
#pragma unroll
  for (int q = 0; q < 4; ++q) {
    int e = q * 512 + tid;
    int sc = e & 3;
    va[q] = make_uint4(0u, 0u, 0u, 0u);
    if (rowBase + ar[q] < M)
      va[q] = *(const uint4*)(A + (size_t)(rowBase + ar[q]) * KD + ac[q] * 32 + sc * 8);
  }
#pragma unroll
  for (int q = 0; q < 3; ++q) {
    int e = q * 512 + tid;
    int sc = e & 3;
    vw[q] = *(const uint4*)(Bp + (size_t)wgrow[q] * KD + wc_[q] * 32 + sc * 8);
  }

#pragma unroll
  for (int ph = 0; ph < NPH; ++ph) {
    if (ph) __syncthreads();  // previous compute must finish before LDS overwrite
    // write staged regs to LDS
#pragma unroll
    for (int q = 0; q < 4; ++q) {
      char* dst = As_ + aldst[q];
      *(uint2*)(dst + aolo[q]) = make_uint2(va[q].x, va[q].y);
      *(uint2*)(dst + aolo[q] + 16) = make_uint2(va[q].z, va[q].w);
    }
#pragma unroll
    for (int q = 0; q < 3; ++q) {
      char* dst = Ws_ + wldst[q];
      *(uint2*)(dst + wolo[q]) = make_uint2(vw[q].x, vw[q].y);
      *(uint2*)(dst + wolo[q] + 16) = make_uint2(vw[q].z, vw[q].w);
    }
    __syncthreads();
    // prefetch next phase into regs (overlaps with compute below)
    if (ph + 1 < NPH) {
      int koff = (ph + 1) * 128;
#pragma unroll
      for (int q = 0; q < 4; ++q) {
        int e = q * 512 + tid;
        int sc = e & 3;
        va[q] = make_uint4(0u, 0u, 0u, 0u);
        if (rowBase + ar[q] < M)
          va[q] = *(const uint4*)(A + (size_t)(rowBase + ar[q]) * KD + koff + ac[q] * 32 + sc * 8);
      }
#pragma unroll
      for (int q = 0; q < 3; ++q) {
        int e = q * 512 + tid;
        int sc = e & 3;
        vw[q] = *(const uint4*)(Bp + (size_t)wgrow[q] * KD + koff + wc_[q] * 32 + sc * 8);
      }
    }
    // compute: 4 chunks x (2 a-frags x 3 gate-frags)
#pragma unroll
    for (int c = 0; c < 4; ++c) {
      short8v af[2], bf[3];
#pragma unroll
      for (int i = 0; i < 2; ++i)
        af[i] = *(const short8v*)(As_ + (32 * wr4 + 16 * i + fr) * 272 + c * 64 + fg * 16);
#pragma unroll
      for (int j = 0; j < 3; ++j)
        bf[j] = *(const short8v*)(Ws_ + (48 * wc2 + 16 * j + fr) * 272 + c * 64 + fg * 16);
#pragma unroll
      for (int i = 0; i < 2; ++i)
#pragma unroll
        for (int j = 0; j < 3; ++j)
          acc[i][j] = __builtin_amdgcn_mfma_f32_16x16x32_bf16(af[i], bf[j], acc[i][j], 0, 0, 0);
    }
  }
  // epilogue: lane owns channel ch for 8 rows; activations in registers
  int chL = 16 * wc2 + fr;
  int ch = ch0 + chL;
  float bi = bsum[ch], bg = bsum[512 + ch], bo = bsum[768 + ch];
  unsigned short hv[8];
#pragma unroll
  for (int i = 0; i < 2; ++i) {
#pragma unroll
    for (int rg = 0; rg < 4; ++rg) {
      float iv = acc[i][0][rg] + bi;
      float gv = acc[i][1][rg] + bg;
      float ov = acc[i][2][rg] + bo;
      float c = sigm_(iv) * tanh_(gv);
      hv[i * 4 + rg] = f2bf(sigm_(ov) * tanh_(c));
    }
  }
  __syncthreads();  // all compute reads of As_ done
  unsigned short* Hs = (unsigned short*)As_;  // [128][40] (80B stride, 16-aligned)
#pragma unroll
  for (int i = 0; i < 2; ++i) {
#pragma unroll
    for (int rg = 0; rg < 4; ++rg) {
      int row = 32 * wr4 + 16 * i + 4 * fg + rg;
      Hs[row * 40 + chL] = hv[i * 4 + rg];
    }
  }
  __syncthreads();
  {
    int row = tid >> 2, seg = tid & 3;
    if (rowBase + row < M) {
      uint4 v = *(const uint4*)(Hs + row * 40 + seg * 8);
      *(uint4*)(H + (size_t)(rowBase + row) * LSTMH + ch0 + seg * 8) = v;
    }
  }
}

// ---------------- LayerNorm + mean pool: 1 wave per 8 rows, register pooling ----------
__global__ __launch_bounds__(256) void ln_pool2(
    const unsigned short* __restrict__ h2, const int* __restrict__ bids,
    const float* __restrict__ lnw, const float* __restrict__ lnb,
    const float* __restrict__ invcnt, float* __restrict__ pooled, int N) {
  int wave = (blockIdx.x * 256 + threadIdx.x) >> 6;
  int lane = threadIdx.x & 63;
  int r0 = wave * 8;
  if (r0 >= N) return;
  float4 w4 = *(const float4*)&lnw[lane * 4];
  float4 b4 = *(const float4*)&lnb[lane * 4];
  float p0 = 0.f, p1 = 0.f, p2 = 0.f, p3 = 0.f;
  int curg = bids[r0];
  int rend = r0 + 8 < N ? r0 + 8 : N;
  for (int r = r0; r < rend; ++r) {
    int g = bids[r];
    if (g != curg) {
      float ic = invcnt[curg];
      atomicAdd(&pooled[curg * LSTMH + lane * 4 + 0], p0 * ic);
      atomicAdd(&pooled[curg * LSTMH + lane * 4 + 1], p1 * ic);
      atomicAdd(&pooled[curg * LSTMH + lane * 4 + 2], p2 * ic);
      atomicAdd(&pooled[curg * LSTMH + lane * 4 + 3], p3 * ic);
      p0 = p1 = p2 = p3 = 0.f;
      curg = g;
    }
    uint2 u = *(const uint2*)(h2 + (size_t)r * LSTMH + lane * 4);
    float v0 = bflo(u.x), v1 = bfhi(u.x), v2 = bflo(u.y), v3 = bfhi(u.y);
    float s = v0 + v1 + v2 + v3;
    float q = v0 * v0 + v1 * v1 + v2 * v2 + v3 * v3;
#pragma unroll
    for (int d = 1; d < 64; d <<= 1) { s += __shfl_xor(s, d); q += __shfl_xor(q, d); }
    float mu = s * (1.f / 256.f);
    float var = q * (1.f / 256.f) - mu * mu;
    float rs = rsqrtf(var + 1e-5f);
    p0 += w4.x * (v0 - mu) * rs + b4.x;
    p1 += w4.y * (v1 - mu) * rs + b4.y;
    p2 += w4.z * (v2 - mu) * rs + b4.z;
    p3 += w4.w * (v3 - mu) * rs + b4.w;
  }
  float ic = invcnt[curg];
  atomicAdd(&pooled[curg * LSTMH + lane * 4 + 0], p0 * ic);
  atomicAdd(&pooled[curg * LSTMH + lane * 4 + 1], p1 * ic);
  atomicAdd(&pooled[curg * LSTMH + lane * 4 + 2], p2 * ic);
  atomicAdd(&pooled[curg * LSTMH + lane * 4 + 3], p3 * ic);
}

// ---------------- FC + log_softmax ----------------
__global__ __launch_bounds__(64) void fc_lsm(const float* __restrict__ pooled,
                                             const float* __restrict__ W,
                                             const float* __restrict__ b, float* __restrict__ out) {
  int g = blockIdx.x;
  int t = threadIdx.x;
  float l0 = 0.f, l1 = 0.f, l2 = 0.f, l3 = 0.f;
  for (int k = t; k < LSTMH; k += 64) {
    float p = pooled[g * LSTMH + k];
    l0 += p * W[k * 4 + 0];
    l1 += p * W[k * 4 + 1];
    l2 += p * W[k * 4 + 2];
    l3 += p * W[k * 4 + 3];
  }
#pragma unroll
  for (int d = 1; d < 64; d <<= 1) {
    l0 += __shfl_xor(l0, d); l1 += __shfl_xor(l1, d);
    l2 += __shfl_xor(l2, d); l3 += __shfl_xor(l3, d);
  }
  if (t == 0) {
    float z[4] = {l0 + b[0], l1 + b[1], l2 + b[2], l3 + b[3]};
    float mx = fmaxf(fmaxf(z[0], z[1]), fmaxf(z[2], z[3]));
    float sum = __expf(z[0] - mx) + __expf(z[1] - mx) + __expf(z[2] - mx) + __expf(z[3] - mx);
    float ls = logf(sum);
#pragma unroll
    for (int o = 0; o < 4; ++o) out[g * 4 + o] = z[o] - mx - ls;
  }
}

// ---------------- host launch ----------------
extern "C" void kernel_launch(void* const* d_in, const int* in_sizes, int n_in,
                              void* d_out, int out_size, void* d_ws, size_t ws_size,
                              hipStream_t stream) {
  const int* node_labels = (const int*)d_in[0];
  const int* node_types = (const int*)d_in[1];
  const float* node_feat = (const float*)d_in[2];
  const int* edge_index = (const int*)d_in[3];
  const int* batch_ids = (const int*)d_in[4];
  const float* emb_label = (const float*)d_in[5];
  const float* emb_type = (const float*)d_in[6];
  const float* W_in = (const float*)d_in[7];
  const float* b_in = (const float*)d_in[8];
  const float* g1_Wl = (const float*)d_in[9];
  const float* g1_bl = (const float*)d_in[10];
  const float* g1_Wr = (const float*)d_in[11];
  const float* g1_br = (const float*)d_in[12];
  const float* g1_att = (const float*)d_in[13];
  const float* g1_bias = (const float*)d_in[14];
  const float* gn1_w = (const float*)d_in[15];
  const float* gn1_b = (const float*)d_in[16];
  const float* gn1_ms = (const float*)d_in[17];
  const float* g2_Wl = (const float*)d_in[18];
  const float* g2_bl = (const float*)d_in[19];
  const float* g2_Wr = (const float*)d_in[20];
  const float* g2_br = (const float*)d_in[21];
  const float* g2_att = (const float*)d_in[22];
  const float* g2_bias = (const float*)d_in[23];
  const float* gn2_w = (const float*)d_in[24];
  const float* gn2_b = (const float*)d_in[25];
  const float* gn2_ms = (const float*)d_in[26];
  const float* W_res = (const float*)d_in[27];
  const float* b_res = (const float*)d_in[28];
  const float* l1_Wih = (const float*)d_in[29];
  const float* l1_bih = (const float*)d_in[31];
  const float* l1_bhh = (const float*)d_in[32];
  const float* l2_Wih = (const float*)d_in[33];
  const float* l2_bih = (const float*)d_in[35];
  const float* l2_bhh = (const float*)d_in[36];
  const float* ln_w = (const float*)d_in[37];
  const float* ln_b = (const float*)d_in[38];
  const float* fc_W = (const float*)d_in[39];
  const float* fc_b = (const float*)d_in[40];
  float* out = (float*)d_out;

  const int N = in_sizes[0];
  const int E = in_sizes[3] / 2;
  const int G = out_size / 4;
  const int ET = E + N;

  char* wsb = (char*)d_ws;
  size_t off = 0;
  auto alloc = [&](size_t bytes) -> void* {
    void* p = (void*)(wsb + off);
    off = (off + bytes + 255) & ~(size_t)255;
    return p;
  };
  float* xA = (float*)alloc((size_t)N * DD * 4);                      // gat out f32; later h2 bf16
  unsigned short* xb = (unsigned short*)alloc((size_t)N * DD * 2);    // bf16 x / x1 / x2
  unsigned short* xlr = (unsigned short*)alloc((size_t)N * 384 * 2);  // xl|xr(|res); later h1
  int* deg = (int*)alloc((size_t)N * 4);
  int* offs = (int*)alloc((size_t)(N + 1) * 4);
  int* cursor = (int*)alloc((size_t)N * 4);
  int* partials = (int*)alloc(1024);
  int* csr = (int*)alloc((size_t)ET * 4);
  int* gstart = (int*)alloc((size_t)(G + 1) * 4);
  float* invcnt = (float*)alloc((size_t)G * 4);
  float* gsum = (float*)alloc((size_t)G * DD * 4);
  float* gsq = (float*)alloc((size_t)G * DD * 4);
  float* pooled = (float*)alloc((size_t)G * LSTMH * 4);
  float* bcat1 = (float*)alloc(256 * 4);
  float* bcat2 = (float*)alloc(384 * 4);
  float* bsum1 = (float*)alloc(ZG * 4);
  float* bsum2 = (float*)alloc(ZG * 4);
  unsigned short* wcat1 = (unsigned short*)alloc((size_t)256 * DD * 2);
  unsigned short* wcat2 = (unsigned short*)alloc((size_t)384 * DD * 2);
  unsigned short* wl1b = (unsigned short*)alloc((size_t)ZG * DD * 2);
  unsigned short* wl2b = (unsigned short*)alloc((size_t)ZG * LSTMH * 2);
  (void)ws_size; (void)n_in;

  unsigned short* h1 = xlr;                  // [N][256] bf16, written after xlr dead
  unsigned short* h2 = (unsigned short*)xA;  // [N][256] bf16, written after xA dead

  hipMemsetAsync(deg, 0, (size_t)N * 4, stream);
  hipMemsetAsync(cursor, 0, (size_t)N * 4, stream);
  hipMemsetAsync(pooled, 0, (size_t)G * LSTMH * 4, stream);

  // weight prep
  cvt_transpose<<<cdiv_(DD * DD, 256), 256, 0, stream>>>(g1_Wl, wcat1, DD, DD);
  cvt_transpose<<<cdiv_(DD * DD, 256), 256, 0, stream>>>(g1_Wr, wcat1 + DD * DD, DD, DD);
  cvt_transpose<<<cdiv_(DD * DD, 256), 256, 0, stream>>>(g2_Wl, wcat2, DD, DD);
  cvt_transpose<<<cdiv_(DD * DD, 256), 256, 0, stream>>>(g2_Wr, wcat2 + DD * DD, DD, DD);
  cvt_transpose<<<cdiv_(DD * DD, 256), 256, 0, stream>>>(W_res, wcat2 + 2 * DD * DD, DD, DD);
  cvt_direct<<<cdiv_(ZG * DD, 256), 256, 0, stream>>>(l1_Wih, wl1b, ZG * DD);
  cvt_direct<<<cdiv_(ZG * LSTMH, 256), 256, 0, stream>>>(l2_Wih, wl2b, ZG * LSTMH);
  prep_small<<<4, 256, 0, stream>>>(g1_bl, g1_br, g2_bl, g2_br, b_res, l1_bih, l1_bhh,
                                    l2_bih, l2_bhh, bcat1, bcat2, bsum1, bsum2);

  graph_ranges<<<1, 128, 0, stream>>>(batch_ids, gstart, invcnt, N, G);
  embed_in<<<N, 128, 0, stream>>>(node_labels, node_types, node_feat, emb_label, emb_type,
                                  W_in, b_in, xb, N);

  // CSR by dst
  count_deg<<<cdiv_(ET, 256), 256, 0, stream>>>(edge_index, deg, E, N);
  int nb1 = cdiv_(N, 256);
  scan1<<<nb1, 256, 0, stream>>>(deg, offs, partials, N);
  scan2<<<1, 256, 0, stream>>>(partials, offs, nb1, N);
  scan3<<<nb1, 256, 0, stream>>>(offs, partials, N);
  fill_csr<<<cdiv_(ET, 256), 256, 0, stream>>>(edge_index, offs, cursor, csr, E, N);

  int mb = cdiv_(N, 128);
  // ---- GAT layer 1: [xl|xr] in one GEMM ----
  gemm_bf16<<<dim3(2, mb), 256, 0, stream>>>(xb, wcat1, bcat1, xlr, N, DD, 256);
  gat_agg<<<cdiv_(N, 4), 256, 0, stream>>>(xlr, 256, csr, offs, g1_att, g1_bias, xA, N);
  hipMemsetAsync(gsum, 0, (size_t)G * DD * 8, stream);  // gsum+gsq contiguous
  gn_stats2<<<cdiv_(N, 128), 256, 0, stream>>>(xA, batch_ids, gsum, gsq, N);
  gn_apply<false><<<cdiv_(N * DD, 256), 256, 0, stream>>>(
      xA, xb, nullptr, 0, batch_ids, gsum, gsq, invcnt, gn1_w, gn1_b, gn1_ms, N);
  // ---- GAT layer 2: [xl|xr|res] in one GEMM ----
  gemm_bf16<<<dim3(3, mb), 256, 0, stream>>>(xb, wcat2, bcat2, xlr, N, DD, 384);
  gat_agg<<<cdiv_(N, 4), 256, 0, stream>>>(xlr, 384, csr, offs, g2_att, g2_bias, xA, N);
  hipMemsetAsync(gsum, 0, (size_t)G * DD * 8, stream);
  gn_stats2<<<cdiv_(N, 128), 256, 0, stream>>>(xA, batch_ids, gsum, gsq, N);
  gn_apply<true><<<cdiv_(N * DD, 256), 256, 0, stream>>>(
      xA, xb, xlr + 256, 384, batch_ids, gsum, gsq, invcnt, gn2_w, gn2_b, gn2_ms, N);
  // ---- LSTM x2: 512-thr single-stage blocks, reg prefetch, XCD-swizzled ----
  int npanel = cdiv_(N, 128);
  int lblocks = 64 * cdiv_(npanel, 8);
  lstm_big<DD><<<lblocks, 512, 0, stream>>>(xb, wl1b, bsum1, h1, N);
  lstm_big<LSTMH><<<lblocks, 512, 0, stream>>>(h1, wl2b, bsum2, h2, N);
  // ---- LN + mean pool + FC ----
  ln_pool2<<<cdiv_(N, 32), 256, 0, stream>>>(h2, batch_ids, ln_w, ln_b, invcnt, pooled, N);
  fc_lsm<<<G, 64, 0, stream>>>(pooled, fc_W, fc_b, out);
}

// Round 8
// 486.963 us; speedup vs baseline: 1.4418x; 1.0958x over previous
//
#include <hip/hip_runtime.h>
#include <cstdint>
#include <cstddef>

#define DD 128
#define LSTMH 256
#define ZG 1024

typedef __attribute__((ext_vector_type(8))) short short8v;
typedef __attribute__((ext_vector_type(4))) float float4v;

static inline int cdiv_(int a, int b) { return (a + b - 1) / b; }

__device__ __forceinline__ float sigm_(float x) { return 1.f / (1.f + __expf(-x)); }
__device__ __forceinline__ float tanh_(float x) {
  float e = __expf(-2.f * fabsf(x));
  float r = (1.f - e) / (1.f + e);
  return copysignf(r, x);
}

__device__ __forceinline__ unsigned short f2bf(float f) {
  uint32_t u = __float_as_uint(f);
  u += 0x7fffu + ((u >> 16) & 1u);
  return (unsigned short)(u >> 16);
}
__device__ __forceinline__ uint32_t bfpack(float a, float b) {
  return (uint32_t)f2bf(a) | ((uint32_t)f2bf(b) << 16);
}
__device__ __forceinline__ float bflo(uint32_t u) { return __uint_as_float(u << 16); }
__device__ __forceinline__ float bfhi(uint32_t u) { return __uint_as_float(u & 0xffff0000u); }

// ---------------- fused weight prep: 5 transposes + 2 casts + biases, one launch --------
__global__ void prep_all(const float* __restrict__ g1Wl, const float* __restrict__ g1Wr,
                         const float* __restrict__ g2Wl, const float* __restrict__ g2Wr,
                         const float* __restrict__ Wres, const float* __restrict__ l1Wih,
                         const float* __restrict__ l2Wih, const float* __restrict__ g1bl,
                         const float* __restrict__ g1br, const float* __restrict__ g2bl,
                         const float* __restrict__ g2br, const float* __restrict__ bres,
                         const float* __restrict__ l1bih, const float* __restrict__ l1bhh,
                         const float* __restrict__ l2bih, const float* __restrict__ l2bhh,
                         unsigned short* __restrict__ wcat1, unsigned short* __restrict__ wcat2,
                         unsigned short* __restrict__ wl1b, unsigned short* __restrict__ wl2b,
                         float* __restrict__ bcat1, float* __restrict__ bcat2,
                         float* __restrict__ bsum1, float* __restrict__ bsum2) {
  int i = blockIdx.x * 256 + threadIdx.x;
  if (i < 81920) {  // five 128x128 transposes -> [M][K] bf16
    int seg = i >> 14, j = i & 16383;
    int m = j >> 7, k = j & 127;
    const float* src = (seg == 0) ? g1Wl : (seg == 1) ? g1Wr : (seg == 2) ? g2Wl
                       : (seg == 3) ? g2Wr : Wres;
    unsigned short* dst = (seg == 0) ? wcat1 : (seg == 1) ? wcat1 + 16384
                          : (seg == 2) ? wcat2 : (seg == 3) ? wcat2 + 16384 : wcat2 + 32768;
    dst[j] = f2bf(src[k * 128 + m]);
    return;
  }
  i -= 81920;
  if (i < 131072) { wl1b[i] = f2bf(l1Wih[i]); return; }
  i -= 131072;
  if (i < 262144) { wl2b[i] = f2bf(l2Wih[i]); return; }
  i -= 262144;
  if (i < 256) { bcat1[i] = (i < 128) ? g1bl[i] : g1br[i - 128]; return; }
  i -= 256;
  if (i < 384) {
    bcat2[i] = (i < 128) ? g2bl[i] : (i < 256 ? g2br[i - 128] : bres[i - 256]);
    return;
  }
  i -= 384;
  if (i < 1024) { bsum1[i] = l1bih[i] + l1bhh[i]; return; }
  i -= 1024;
  if (i < 1024) { bsum2[i] = l2bih[i] + l2bhh[i]; return; }
}

// ---------------- embedding + W_in GEMV: 128 nodes/block, W in registers ----------------
__global__ __launch_bounds__(256) void embed_in2(
    const int* __restrict__ labels, const int* __restrict__ types,
    const float* __restrict__ nf, const float* __restrict__ embL,
    const float* __restrict__ embT, const float* __restrict__ W,
    const float* __restrict__ b, unsigned short* __restrict__ x, int N) {
  __shared__ float f[128][34];
  int base = blockIdx.x * 128;
  int tid = threadIdx.x;
  int ch = tid & 127, half = tid >> 7;
  float wr[33];
#pragma unroll
  for (int k = 0; k < 33; ++k) wr[k] = W[k * 128 + ch];
  float bb = b[ch];
  int nmax = N - base < 128 ? N - base : 128;
  for (int e = tid; e < nmax * 32; e += 256) {
    int n = e >> 5, k = e & 31;
    f[n][k] = (k < 16) ? embL[labels[base + n] * 16 + k] : embT[types[base + n] * 16 + (k - 16)];
  }
  for (int n = tid; n < nmax; n += 256) f[n][32] = nf[base + n];
  __syncthreads();
  for (int n = half; n < nmax; n += 2) {
    float acc = bb;
#pragma unroll
    for (int k = 0; k < 33; ++k) acc = fmaf(f[n][k], wr[k], acc);
    x[(size_t)(base + n) * 128 + ch] = f2bf(acc);
  }
}

// ---------------- CSR build ----------------
__global__ void count_deg(const int* __restrict__ ei, int* __restrict__ deg, int E_, int N_) {
  int i = blockIdx.x * 256 + threadIdx.x;
  if (i < E_) atomicAdd(&deg[ei[E_ + i]], 1);
  else if (i < E_ + N_) atomicAdd(&deg[i - E_], 1);
}

__global__ __launch_bounds__(256) void scan1(const int* __restrict__ deg, int* __restrict__ offs,
                                             int* __restrict__ partials, int N_) {
  __shared__ int buf[2][256];
  int tid = threadIdx.x;
  int i = blockIdx.x * 256 + tid;
  int v = (i < N_) ? deg[i] : 0;
  buf[0][tid] = v;
  __syncthreads();
  int cur = 0;
#pragma unroll
  for (int d = 1; d < 256; d <<= 1) {
    int xv = buf[cur][tid];
    if (tid >= d) xv += buf[cur][tid - d];
    buf[cur ^ 1][tid] = xv;
    cur ^= 1;
    __syncthreads();
  }
  int incl = buf[cur][tid];
  if (i < N_) offs[i] = incl - v;
  if (tid == 255) partials[blockIdx.x] = incl;
}

__global__ __launch_bounds__(256) void scan2(int* __restrict__ partials, int* __restrict__ offs,
                                             int nb, int N_) {
  __shared__ int buf[2][256];
  int tid = threadIdx.x;
  int v = (tid < nb) ? partials[tid] : 0;
  buf[0][tid] = v;
  __syncthreads();
  int cur = 0;
#pragma unroll
  for (int d = 1; d < 256; d <<= 1) {
    int xv = buf[cur][tid];
    if (tid >= d) xv += buf[cur][tid - d];
    buf[cur ^ 1][tid] = xv;
    cur ^= 1;
    __syncthreads();
  }
  int incl = buf[cur][tid];
  if (tid < nb) partials[tid] = incl - v;
  if (tid == 255) offs[N_] = incl;
}

__global__ void scan3(int* __restrict__ offs, const int* __restrict__ partials, int N_) {
  int i = blockIdx.x * 256 + threadIdx.x;
  if (i < N_) offs[i] += partials[blockIdx.x];
}

__global__ void fill_csr(const int* __restrict__ ei, const int* __restrict__ offs,
                         int* __restrict__ cursor, int* __restrict__ csr, int E_, int N_) {
  int i = blockIdx.x * 256 + threadIdx.x;
  int s, d;
  if (i < E_) { s = ei[i]; d = ei[E_ + i]; }
  else if (i < E_ + N_) { s = d = i - E_; }
  else return;
  int pos = offs[d] + atomicAdd(&cursor[d], 1);
  csr[pos] = s;
}

// ---------------- graph ranges ----------------
__global__ void graph_ranges(const int* __restrict__ bids, int* __restrict__ gstart,
                             float* __restrict__ invcnt, int N_, int G_) {
  int t = threadIdx.x;
  if (t <= G_) {
    int lo = 0, hi = N_;
    while (lo < hi) { int mid = (lo + hi) >> 1; if (bids[mid] < t) lo = mid + 1; else hi = mid; }
    gstart[t] = lo;
  }
  __syncthreads();
  if (t < G_) {
    int c = gstart[t + 1] - gstart[t];
    invcnt[t] = (c > 0) ? 1.f / (float)c : 0.f;
  }
}

// ---------------- bf16 MFMA GEMM: C[M,Ncols] bf16 = A[M,K]bf16 @ B'[Ncols,K]^T + bias
__global__ __launch_bounds__(256) void gemm_bf16(
    const unsigned short* __restrict__ A, const unsigned short* __restrict__ Bp,
    const float* __restrict__ bias, unsigned short* __restrict__ C, int M, int K, int Ncols) {
  __shared__ unsigned short As[128 * 40];
  __shared__ unsigned short Bs[128 * 40];
  int tid = threadIdx.x;
  int lane = tid & 63;
  int wid = tid >> 6;
  int rowBase = blockIdx.y * 128, colBase = blockIdx.x * 128;
  int wr = (wid >> 1) * 64, wc = (wid & 1) * 64;
  int fr = lane & 15, fg = lane >> 4;
  float4v acc[4][4];
#pragma unroll
  for (int i = 0; i < 4; ++i)
#pragma unroll
    for (int j = 0; j < 4; ++j) acc[i][j] = (float4v){0.f, 0.f, 0.f, 0.f};

  int sr = tid >> 2;
  int sc = tid & 3;
  int off_lo = (sc < 2) ? 32 * sc : 32 * sc - 56;

  for (int k0 = 0; k0 < K; k0 += 32) {
#pragma unroll
    for (int it = 0; it < 2; ++it) {
      int r = it * 64 + sr;
      uint4 va = make_uint4(0u, 0u, 0u, 0u);
      if (rowBase + r < M)
        va = *(const uint4*)(A + (size_t)(rowBase + r) * K + k0 + sc * 8);
      char* arow = (char*)(As + r * 40);
      *(uint2*)(arow + off_lo) = make_uint2(va.x, va.y);
      *(uint2*)(arow + off_lo + 16) = make_uint2(va.z, va.w);
      uint4 vb = *(const uint4*)(Bp + (size_t)(colBase + r) * K + k0 + sc * 8);
      char* brow = (char*)(Bs + r * 40);
      *(uint2*)(brow + off_lo) = make_uint2(vb.x, vb.y);
      *(uint2*)(brow + off_lo + 16) = make_uint2(vb.z, vb.w);
    }
    __syncthreads();
    short8v af[4], bfv[4];
#pragma unroll
    for (int i = 0; i < 4; ++i)
      af[i] = *(const short8v*)((const char*)As + (wr + 16 * i + fr) * 80 + fg * 16);
#pragma unroll
    for (int j = 0; j < 4; ++j)
      bfv[j] = *(const short8v*)((const char*)Bs + (wc + 16 * j + fr) * 80 + fg * 16);
#pragma unroll
    for (int i = 0; i < 4; ++i)
#pragma unroll
      for (int j = 0; j < 4; ++j)
        acc[i][j] = __builtin_amdgcn_mfma_f32_16x16x32_bf16(af[i], bfv[j], acc[i][j], 0, 0, 0);
    __syncthreads();
  }
#pragma unroll
  for (int j = 0; j < 4; ++j) {
    int gc = colBase + wc + 16 * j + fr;
    float bv = bias[gc];
#pragma unroll
    for (int i = 0; i < 4; ++i) {
      int gr0 = rowBase + wr + 16 * i + fg * 4;
#pragma unroll
      for (int rg = 0; rg < 4; ++rg) {
        int gr = gr0 + rg;
        if (gr < M) C[(size_t)gr * Ncols + gc] = f2bf(acc[i][j][rg] + bv);
      }
    }
  }
}

// ---------------- GATv2 aggregation: 1 wave/node, 4 edges in flight, per-head softmax ----
// 16 lanes/edge, 8 ch/lane; a head (32 ch) spans 4 aligned lanes -> reduce is xor 1,2 ONLY.
// Each lane keeps its head's online-softmax state; output written as bf16.
__global__ __launch_bounds__(256) void gat_agg(
    const unsigned short* __restrict__ xlr, int stride,
    const int* __restrict__ csr, const int* __restrict__ offs,
    const float* __restrict__ att, const float* __restrict__ bias,
    unsigned short* __restrict__ out, int N) {
  int wid = (blockIdx.x * 256 + threadIdx.x) >> 6;
  if (wid >= N) return;
  int lane = threadIdx.x & 63;
  int q = lane >> 4, ql = lane & 15;   // edge slot, channel group (8 ch each)
  float4 aA = *(const float4*)&att[ql * 8];
  float4 aB = *(const float4*)&att[ql * 8 + 4];
  uint4 ur = *(const uint4*)(xlr + (size_t)wid * stride + 128 + ql * 8);
  float r0 = bflo(ur.x), r1 = bfhi(ur.x), r2 = bflo(ur.y), r3 = bfhi(ur.y);
  float r4 = bflo(ur.z), r5 = bfhi(ur.z), r6 = bflo(ur.w), r7 = bfhi(ur.w);
  float m = -1e30f, L = 0.f;
  float s0 = 0.f, s1 = 0.f, s2 = 0.f, s3 = 0.f, s4 = 0.f, s5 = 0.f, s6 = 0.f, s7 = 0.f;
  int js = offs[wid], je = offs[wid + 1];
  for (int j = js + q; j < je; j += 4) {
    int s = csr[j];
    uint4 u = *(const uint4*)(xlr + (size_t)s * stride + ql * 8);
    float x0 = bflo(u.x), x1 = bfhi(u.x), x2 = bflo(u.y), x3 = bfhi(u.y);
    float x4 = bflo(u.z), x5 = bfhi(u.z), x6 = bflo(u.w), x7 = bfhi(u.w);
    float v0 = fmaxf(r0 + x0, 0.2f * (r0 + x0));
    float v1 = fmaxf(r1 + x1, 0.2f * (r1 + x1));
    float v2 = fmaxf(r2 + x2, 0.2f * (r2 + x2));
    float v3 = fmaxf(r3 + x3, 0.2f * (r3 + x3));
    float v4 = fmaxf(r4 + x4, 0.2f * (r4 + x4));
    float v5 = fmaxf(r5 + x5, 0.2f * (r5 + x5));
    float v6 = fmaxf(r6 + x6, 0.2f * (r6 + x6));
    float v7 = fmaxf(r7 + x7, 0.2f * (r7 + x7));
    float p = aA.x * v0 + aA.y * v1 + aA.z * v2 + aA.w * v3 +
              aB.x * v4 + aB.y * v5 + aB.z * v6 + aB.w * v7;
    p += __shfl_xor(p, 1); p += __shfl_xor(p, 2);   // per-head reduce (4 lanes = 32 ch)
    float mn = fmaxf(m, p);
    float ea = __expf(p - mn);
    float es = __expf(m - mn);
    L = L * es + ea;
    s0 = s0 * es + ea * x0; s1 = s1 * es + ea * x1;
    s2 = s2 * es + ea * x2; s3 = s3 * es + ea * x3;
    s4 = s4 * es + ea * x4; s5 = s5 * es + ea * x5;
    s6 = s6 * es + ea * x6; s7 = s7 * es + ea * x7;
    m = mn;
  }
  // merge the 4 edge-slot states (per head/channel-slice)
#pragma unroll
  for (int d = 16; d <= 32; d <<= 1) {
    float mo = __shfl_xor(m, d), Lo = __shfl_xor(L, d);
    float t0 = __shfl_xor(s0, d), t1 = __shfl_xor(s1, d);
    float t2 = __shfl_xor(s2, d), t3 = __shfl_xor(s3, d);
    float t4 = __shfl_xor(s4, d), t5 = __shfl_xor(s5, d);
    float t6 = __shfl_xor(s6, d), t7 = __shfl_xor(s7, d);
    float mn = fmaxf(m, mo);
    float e0 = __expf(m - mn), e1 = __expf(mo - mn);
    L = L * e0 + Lo * e1;
    s0 = s0 * e0 + t0 * e1; s1 = s1 * e0 + t1 * e1;
    s2 = s2 * e0 + t2 * e1; s3 = s3 * e0 + t3 * e1;
    s4 = s4 * e0 + t4 * e1; s5 = s5 * e0 + t5 * e1;
    s6 = s6 * e0 + t6 * e1; s7 = s7 * e0 + t7 * e1;
    m = mn;
  }
  if (q == 0) {
    float inv = 1.f / L;
    float4 bA = *(const float4*)&bias[ql * 8];
    float4 bB = *(const float4*)&bias[ql * 8 + 4];
    uint4 ov;
    ov.x = bfpack(s0 * inv + bA.x, s1 * inv + bA.y);
    ov.y = bfpack(s2 * inv + bA.z, s3 * inv + bA.w);
    ov.z = bfpack(s4 * inv + bB.x, s5 * inv + bB.y);
    ov.w = bfpack(s6 * inv + bB.z, s7 * inv + bB.w);
    *(uint4*)(out + (size_t)wid * DD + ql * 8) = ov;
  }
}

// ---------------- GraphNorm stats (bf16 input, uint-vectorized) ----------------
__global__ __launch_bounds__(256) void gn_stats2(const unsigned short* __restrict__ x,
                                                 const int* __restrict__ bids,
                                                 float* __restrict__ gsum,
                                                 float* __restrict__ gsq, int N) {
  int base = blockIdx.x * 128;
  int cp = threadIdx.x & 63;   // channel pair
  int sub = threadIdx.x >> 6;  // row offset 0..3
  int end = base + 128 < N ? base + 128 : N;
  int curg = -1;
  float s0 = 0.f, s1 = 0.f, q0 = 0.f, q1 = 0.f;
  for (int r = base + sub; r < end; r += 4) {
    int g = bids[r];
    if (g != curg) {
      if (curg >= 0) {
        atomicAdd(&gsum[curg * DD + cp * 2], s0);
        atomicAdd(&gsum[curg * DD + cp * 2 + 1], s1);
        atomicAdd(&gsq[curg * DD + cp * 2], q0);
        atomicAdd(&gsq[curg * DD + cp * 2 + 1], q1);
      }
      curg = g; s0 = s1 = q0 = q1 = 0.f;
    }
    uint32_t u = *(const uint32_t*)(x + (size_t)r * DD + cp * 2);
    float v0 = bflo(u), v1 = bfhi(u);
    s0 += v0; q0 += v0 * v0; s1 += v1; q1 += v1 * v1;
  }
  if (curg >= 0) {
    atomicAdd(&gsum[curg * DD + cp * 2], s0);
    atomicAdd(&gsum[curg * DD + cp * 2 + 1], s1);
    atomicAdd(&gsq[curg * DD + cp * 2], q0);
    atomicAdd(&gsq[curg * DD + cp * 2 + 1], q1);
  }
}

// ---------------- GraphNorm apply + ELU (+residual) : bf16 in -> bf16 out --------------
template <bool ADDRES>
__global__ void gn_apply(const unsigned short* __restrict__ xin,
                         unsigned short* __restrict__ xout,
                         const unsigned short* __restrict__ res, int resStride,
                         const int* __restrict__ bids, const float* __restrict__ gsum,
                         const float* __restrict__ gsq, const float* __restrict__ invcnt,
                         const float* __restrict__ w, const float* __restrict__ b,
                         const float* __restrict__ ms, int N) {
  int idx = blockIdx.x * 256 + threadIdx.x;
  if (idx >= N * 64) return;
  int n = idx >> 6, cp = idx & 63;
  int g = bids[n];
  float ic = invcnt[g];
  float2 sm = *(const float2*)&gsum[g * DD + cp * 2];
  float2 sq = *(const float2*)&gsq[g * DD + cp * 2];
  float2 w2 = *(const float2*)&w[cp * 2];
  float2 b2 = *(const float2*)&b[cp * 2];
  float2 m2 = *(const float2*)&ms[cp * 2];
  uint32_t u = *(const uint32_t*)(xin + (size_t)n * DD + cp * 2);
  float mean0 = sm.x * ic, mean1 = sm.y * ic;
  float mm0 = mean0 * m2.x, mm1 = mean1 * m2.y;
  float var0 = sq.x * ic - mm0 * (2.f * mean0 - mm0);
  float var1 = sq.y * ic - mm1 * (2.f * mean1 - mm1);
  float v0 = (bflo(u) - mm0) * rsqrtf(var0 + 1e-5f) * w2.x + b2.x;
  float v1 = (bfhi(u) - mm1) * rsqrtf(var1 + 1e-5f) * w2.y + b2.y;
  if (ADDRES) {
    uint32_t ur = *(const uint32_t*)(res + (size_t)n * resStride + cp * 2);
    v0 += bflo(ur); v1 += bfhi(ur);
  }
  v0 = v0 > 0.f ? v0 : (__expf(v0) - 1.f);
  v1 = v1 > 0.f ? v1 : (__expf(v1) - 1.f);
  *(uint32_t*)(xout + (size_t)n * DD + cp * 2) = bfpack(v0, v1);
}

// ---------------- single-stage LSTM step, 512 thr, reg-prefetch, coalesced store --------
template <int KD>
__global__ __launch_bounds__(512, 4) void lstm_big(
    const unsigned short* __restrict__ A, const unsigned short* __restrict__ Bp,
    const float* __restrict__ bsum, unsigned short* __restrict__ H, int M) {
  __shared__ __attribute__((aligned(16))) char As_[128 * 272];
  __shared__ __attribute__((aligned(16))) char Ws_[96 * 272];
  const int NPH = KD / 128;
  int npanel = (M + 127) >> 7;
  int b = blockIdx.x;
  int g8 = b & 7, inner = b >> 3;
  int p = g8 + 8 * (inner >> 3);
  int cc = inner & 7;
  if (p >= npanel) return;
  int rowBase = p << 7;
  int ch0 = cc * 32;

  int tid = threadIdx.x;
  int lane = tid & 63;
  int wid = tid >> 6;
  int wr4 = wid >> 1;
  int wc2 = wid & 1;
  int fr = lane & 15, fg = lane >> 4;

  int ar[4], ac[4], asc[4], aolo[4], aldst[4];
#pragma unroll
  for (int q = 0; q < 4; ++q) {
    int e = q * 512 + tid;
    int r = e >> 4, kk = e & 15;
    int c = kk >> 2, sc = kk & 3;
    ar[q] = r; ac[q] = c; asc[q] = sc;
    aolo[q] = (sc < 2) ? 32 * sc : 32 * sc - 56;
    aldst[q] = r * 272 + c * 64;
  }
  int wgrow[3], wc_[3], wsc[3], wolo[3], wldst[3];
#pragma unroll
  for (int q = 0; q < 3; ++q) {
    int e = q * 512 + tid;
    int wrow = e >> 4, kk = e & 15;
    int c = kk >> 2, sc = kk & 3;
    int half = wrow >= 48 ? 1 : 0;
    int r3 = wrow - 48 * half;
    int grp = r3 >> 4;
    int goff = (grp == 0) ? 0 : (grp == 1 ? 512 : 768);
    wgrow[q] = goff + ch0 + 16 * half + (r3 & 15);
    wc_[q] = c; wsc[q] = sc;
    wolo[q] = (sc < 2) ? 32 * sc : 32 * sc - 56;
    wldst[q] = wrow * 272 + c * 64;
  }

  float4v acc[2][3];
#pragma unroll
  for (int i = 0; i < 2; ++i)
#pragma unroll
    for (int j = 0; j < 3; ++j) acc[i][j] = (float4v){0.f, 0.f, 0.f, 0.f};

  uint4 va[4], vw[3];
#pragma unroll
  for (int q = 0; q < 4; ++q) {
    va[q] = make_uint4(0u, 0u, 0u, 0u);
    if (rowBase + ar[q] < M)
      va[q] = *(const uint4*)(A + (size_t)(rowBase + ar[q]) * KD + ac[q] * 32 + asc[q] * 8);
  }
#pragma unroll
  for (int q = 0; q < 3; ++q)
    vw[q] = *(const uint4*)(Bp + (size_t)wgrow[q] * KD + wc_[q] * 32 + wsc[q] * 8);

#pragma unroll
  for (int ph = 0; ph < NPH; ++ph) {
    if (ph) __syncthreads();
#pragma unroll
    for (int q = 0; q < 4; ++q) {
      char* dst = As_ + aldst[q];
      *(uint2*)(dst + aolo[q]) = make_uint2(va[q].x, va[q].y);
      *(uint2*)(dst + aolo[q] + 16) = make_uint2(va[q].z, va[q].w);
    }
#pragma unroll
    for (int q = 0; q < 3; ++q) {
      char* dst = Ws_ + wldst[q];
      *(uint2*)(dst + wolo[q]) = make_uint2(vw[q].x, vw[q].y);
      *(uint2*)(dst + wolo[q] + 16) = make_uint2(vw[q].z, vw[q].w);
    }
    __syncthreads();
    if (ph + 1 < NPH) {
      int koff = (ph + 1) * 128;
#pragma unroll
      for (int q = 0; q < 4; ++q) {
        va[q] = make_uint4(0u, 0u, 0u, 0u);
        if (rowBase + ar[q] < M)
          va[q] = *(const uint4*)(A + (size_t)(rowBase + ar[q]) * KD + koff + ac[q] * 32 + asc[q] * 8);
      }
#pragma unroll
      for (int q = 0; q < 3; ++q)
        vw[q] = *(const uint4*)(Bp + (size_t)wgrow[q] * KD + koff + wc_[q] * 32 + wsc[q] * 8);
    }
    __builtin_amdgcn_s_setprio(1);
#pragma unroll
    for (int c = 0; c < 4; ++c) {
      short8v af[2], bf[3];
#pragma unroll
      for (int i = 0; i < 2; ++i)
        af[i] = *(const short8v*)(As_ + (32 * wr4 + 16 * i + fr) * 272 + c * 64 + fg * 16);
#pragma unroll
      for (int j = 0; j < 3; ++j)
        bf[j] = *(const short8v*)(Ws_ + (48 * wc2 + 16 * j + fr) * 272 + c * 64 + fg * 16);
#pragma unroll
      for (int i = 0; i < 2; ++i)
#pragma unroll
        for (int j = 0; j < 3; ++j)
          acc[i][j] = __builtin_amdgcn_mfma_f32_16x16x32_bf16(af[i], bf[j], acc[i][j], 0, 0, 0);
    }
    __builtin_amdgcn_s_setprio(0);
  }
  int chL = 16 * wc2 + fr;
  int ch = ch0 + chL;
  float bi = bsum[ch], bg = bsum[512 + ch], bo = bsum[768 + ch];
  unsigned short hv[8];
#pragma unroll
  for (int i = 0; i < 2; ++i) {
#pragma unroll
    for (int rg = 0; rg < 4; ++rg) {
      float iv = acc[i][0][rg] + bi;
      float gv = acc[i][1][rg] + bg;
      float ov = acc[i][2][rg] + bo;
      float c = sigm_(iv) * tanh_(gv);
      hv[i * 4 + rg] = f2bf(sigm_(ov) * tanh_(c));
    }
  }
  __syncthreads();
  unsigned short* Hs = (unsigned short*)As_;  // [128][40]
#pragma unroll
  for (int i = 0; i < 2; ++i) {
#pragma unroll
    for (int rg = 0; rg < 4; ++rg) {
      int row = 32 * wr4 + 16 * i + 4 * fg + rg;
      Hs[row * 40 + chL] = hv[i * 4 + rg];
    }
  }
  __syncthreads();
  {
    int row = tid >> 2, seg = tid & 3;
    if (rowBase + row < M) {
      uint4 v = *(const uint4*)(Hs + row * 40 + seg * 8);
      *(uint4*)(H + (size_t)(rowBase + row) * LSTMH + ch0 + seg * 8) = v;
    }
  }
}

// ---------------- LayerNorm + mean pool: 1 wave per 8 rows, register pooling ----------
__global__ __launch_bounds__(256) void ln_pool2(
    const unsigned short* __restrict__ h2, const int* __restrict__ bids,
    const float* __restrict__ lnw, const float* __restrict__ lnb,
    const float* __restrict__ invcnt, float* __restrict__ pooled, int N) {
  int wave = (blockIdx.x * 256 + threadIdx.x) >> 6;
  int lane = threadIdx.x & 63;
  int r0 = wave * 8;
  if (r0 >= N) return;
  float4 w4 = *(const float4*)&lnw[lane * 4];
  float4 b4 = *(const float4*)&lnb[lane * 4];
  float p0 = 0.f, p1 = 0.f, p2 = 0.f, p3 = 0.f;
  int curg = bids[r0];
  int rend = r0 + 8 < N ? r0 + 8 : N;
  for (int r = r0; r < rend; ++r) {
    int g = bids[r];
    if (g != curg) {
      float ic = invcnt[curg];
      atomicAdd(&pooled[curg * LSTMH + lane * 4 + 0], p0 * ic);
      atomicAdd(&pooled[curg * LSTMH + lane * 4 + 1], p1 * ic);
      atomicAdd(&pooled[curg * LSTMH + lane * 4 + 2], p2 * ic);
      atomicAdd(&pooled[curg * LSTMH + lane * 4 + 3], p3 * ic);
      p0 = p1 = p2 = p3 = 0.f;
      curg = g;
    }
    uint2 u = *(const uint2*)(h2 + (size_t)r * LSTMH + lane * 4);
    float v0 = bflo(u.x), v1 = bfhi(u.x), v2 = bflo(u.y), v3 = bfhi(u.y);
    float s = v0 + v1 + v2 + v3;
    float q = v0 * v0 + v1 * v1 + v2 * v2 + v3 * v3;
#pragma unroll
    for (int d = 1; d < 64; d <<= 1) { s += __shfl_xor(s, d); q += __shfl_xor(q, d); }
    float mu = s * (1.f / 256.f);
    float var = q * (1.f / 256.f) - mu * mu;
    float rs = rsqrtf(var + 1e-5f);
    p0 += w4.x * (v0 - mu) * rs + b4.x;
    p1 += w4.y * (v1 - mu) * rs + b4.y;
    p2 += w4.z * (v2 - mu) * rs + b4.z;
    p3 += w4.w * (v3 - mu) * rs + b4.w;
  }
  float ic = invcnt[curg];
  atomicAdd(&pooled[curg * LSTMH + lane * 4 + 0], p0 * ic);
  atomicAdd(&pooled[curg * LSTMH + lane * 4 + 1], p1 * ic);
  atomicAdd(&pooled[curg * LSTMH + lane * 4 + 2], p2 * ic);
  atomicAdd(&pooled[curg * LSTMH + lane * 4 + 3], p3 * ic);
}

// ---------------- FC + log_softmax ----------------
__global__ __launch_bounds__(64) void fc_lsm(const float* __restrict__ pooled,
                                             const float* __restrict__ W,
                                             const float* __restrict__ b, float* __restrict__ out) {
  int g = blockIdx.x;
  int t = threadIdx.x;
  float l0 = 0.f, l1 = 0.f, l2 = 0.f, l3 = 0.f;
  for (int k = t; k < LSTMH; k += 64) {
    float p = pooled[g * LSTMH + k];
    l0 += p * W[k * 4 + 0];
    l1 += p * W[k * 4 + 1];
    l2 += p * W[k * 4 + 2];
    l3 += p * W[k * 4 + 3];
  }
#pragma unroll
  for (int d = 1; d < 64; d <<= 1) {
    l0 += __shfl_xor(l0, d); l1 += __shfl_xor(l1, d);
    l2 += __shfl_xor(l2, d); l3 += __shfl_xor(l3, d);
  }
  if (t == 0) {
    float z[4] = {l0 + b[0], l1 + b[1], l2 + b[2], l3 + b[3]};
    float mx = fmaxf(fmaxf(z[0], z[1]), fmaxf(z[2], z[3]));
    float sum = __expf(z[0] - mx) + __expf(z[1] - mx) + __expf(z[2] - mx) + __expf(z[3] - mx);
    float ls = logf(sum);
#pragma unroll
    for (int o = 0; o < 4; ++o) out[g * 4 + o] = z[o] - mx - ls;
  }
}

// ---------------- host launch ----------------
extern "C" void kernel_launch(void* const* d_in, const int* in_sizes, int n_in,
                              void* d_out, int out_size, void* d_ws, size_t ws_size,
                              hipStream_t stream) {
  const int* node_labels = (const int*)d_in[0];
  const int* node_types = (const int*)d_in[1];
  const float* node_feat = (const float*)d_in[2];
  const int* edge_index = (const int*)d_in[3];
  const int* batch_ids = (const int*)d_in[4];
  const float* emb_label = (const float*)d_in[5];
  const float* emb_type = (const float*)d_in[6];
  const float* W_in = (const float*)d_in[7];
  const float* b_in = (const float*)d_in[8];
  const float* g1_Wl = (const float*)d_in[9];
  const float* g1_bl = (const float*)d_in[10];
  const float* g1_Wr = (const float*)d_in[11];
  const float* g1_br = (const float*)d_in[12];
  const float* g1_att = (const float*)d_in[13];
  const float* g1_bias = (const float*)d_in[14];
  const float* gn1_w = (const float*)d_in[15];
  const float* gn1_b = (const float*)d_in[16];
  const float* gn1_ms = (const float*)d_in[17];
  const float* g2_Wl = (const float*)d_in[18];
  const float* g2_bl = (const float*)d_in[19];
  const float* g2_Wr = (const float*)d_in[20];
  const float* g2_br = (const float*)d_in[21];
  const float* g2_att = (const float*)d_in[22];
  const float* g2_bias = (const float*)d_in[23];
  const float* gn2_w = (const float*)d_in[24];
  const float* gn2_b = (const float*)d_in[25];
  const float* gn2_ms = (const float*)d_in[26];
  const float* W_res = (const float*)d_in[27];
  const float* b_res = (const float*)d_in[28];
  const float* l1_Wih = (const float*)d_in[29];
  const float* l1_bih = (const float*)d_in[31];
  const float* l1_bhh = (const float*)d_in[32];
  const float* l2_Wih = (const float*)d_in[33];
  const float* l2_bih = (const float*)d_in[35];
  const float* l2_bhh = (const float*)d_in[36];
  const float* ln_w = (const float*)d_in[37];
  const float* ln_b = (const float*)d_in[38];
  const float* fc_W = (const float*)d_in[39];
  const float* fc_b = (const float*)d_in[40];
  float* out = (float*)d_out;

  const int N = in_sizes[0];
  const int E = in_sizes[3] / 2;
  const int G = out_size / 4;
  const int ET = E + N;

  char* wsb = (char*)d_ws;
  size_t off = 0;
  auto alloc = [&](size_t bytes) -> void* {
    void* p = (void*)(wsb + off);
    off = (off + bytes + 255) & ~(size_t)255;
    return p;
  };
  unsigned short* xA = (unsigned short*)alloc((size_t)N * 512);       // gat out bf16; later h2
  unsigned short* xb = (unsigned short*)alloc((size_t)N * DD * 2);    // bf16 x / x1 / x2
  unsigned short* xlr = (unsigned short*)alloc((size_t)N * 384 * 2);  // xl|xr(|res); later h1
  int* deg = (int*)alloc((size_t)N * 4);
  int* offs = (int*)alloc((size_t)(N + 1) * 4);
  int* cursor = (int*)alloc((size_t)N * 4);
  int* partials = (int*)alloc(1024);
  int* csr = (int*)alloc((size_t)ET * 4);
  int* gstart = (int*)alloc((size_t)(G + 1) * 4);
  float* invcnt = (float*)alloc((size_t)G * 4);
  float* gsum = (float*)alloc((size_t)G * DD * 4);
  float* gsq = (float*)alloc((size_t)G * DD * 4);
  float* pooled = (float*)alloc((size_t)G * LSTMH * 4);
  float* bcat1 = (float*)alloc(256 * 4);
  float* bcat2 = (float*)alloc(384 * 4);
  float* bsum1 = (float*)alloc(ZG * 4);
  float* bsum2 = (float*)alloc(ZG * 4);
  unsigned short* wcat1 = (unsigned short*)alloc((size_t)256 * DD * 2);
  unsigned short* wcat2 = (unsigned short*)alloc((size_t)384 * DD * 2);
  unsigned short* wl1b = (unsigned short*)alloc((size_t)ZG * DD * 2);
  unsigned short* wl2b = (unsigned short*)alloc((size_t)ZG * LSTMH * 2);
  (void)ws_size; (void)n_in;

  unsigned short* h1 = xlr;   // [N][256] bf16, written after xlr dead
  unsigned short* h2 = xA;    // [N][256] bf16, written after xA dead

  hipMemsetAsync(deg, 0, (size_t)N * 4, stream);
  hipMemsetAsync(cursor, 0, (size_t)N * 4, stream);
  hipMemsetAsync(pooled, 0, (size_t)G * LSTMH * 4, stream);

  prep_all<<<1867, 256, 0, stream>>>(g1_Wl, g1_Wr, g2_Wl, g2_Wr, W_res, l1_Wih, l2_Wih,
                                     g1_bl, g1_br, g2_bl, g2_br, b_res, l1_bih, l1_bhh,
                                     l2_bih, l2_bhh, wcat1, wcat2, wl1b, wl2b,
                                     bcat1, bcat2, bsum1, bsum2);
  graph_ranges<<<1, 128, 0, stream>>>(batch_ids, gstart, invcnt, N, G);
  embed_in2<<<cdiv_(N, 128), 256, 0, stream>>>(node_labels, node_types, node_feat, emb_label,
                                               emb_type, W_in, b_in, xb, N);

  // CSR by dst
  count_deg<<<cdiv_(ET, 256), 256, 0, stream>>>(edge_index, deg, E, N);
  int nb1 = cdiv_(N, 256);
  scan1<<<nb1, 256, 0, stream>>>(deg, offs, partials, N);
  scan2<<<1, 256, 0, stream>>>(partials, offs, nb1, N);
  scan3<<<nb1, 256, 0, stream>>>(offs, partials, N);
  fill_csr<<<cdiv_(ET, 256), 256, 0, stream>>>(edge_index, offs, cursor, csr, E, N);

  int mb = cdiv_(N, 128);
  // ---- GAT layer 1: [xl|xr] in one GEMM ----
  gemm_bf16<<<dim3(2, mb), 256, 0, stream>>>(xb, wcat1, bcat1, xlr, N, DD, 256);
  gat_agg<<<cdiv_(N, 4), 256, 0, stream>>>(xlr, 256, csr, offs, g1_att, g1_bias, xA, N);
  hipMemsetAsync(gsum, 0, (size_t)G * DD * 8, stream);  // gsum+gsq contiguous
  gn_stats2<<<cdiv_(N, 128), 256, 0, stream>>>(xA, batch_ids, gsum, gsq, N);
  gn_apply<false><<<cdiv_(N * 64, 256), 256, 0, stream>>>(
      xA, xb, nullptr, 0, batch_ids, gsum, gsq, invcnt, gn1_w, gn1_b, gn1_ms, N);
  // ---- GAT layer 2: [xl|xr|res] in one GEMM ----
  gemm_bf16<<<dim3(3, mb), 256, 0, stream>>>(xb, wcat2, bcat2, xlr, N, DD, 384);
  gat_agg<<<cdiv_(N, 4), 256, 0, stream>>>(xlr, 384, csr, offs, g2_att, g2_bias, xA, N);
  hipMemsetAsync(gsum, 0, (size_t)G * DD * 8, stream);
  gn_stats2<<<cdiv_(N, 128), 256, 0, stream>>>(xA, batch_ids, gsum, gsq, N);
  gn_apply<true><<<cdiv_(N * 64, 256), 256, 0, stream>>>(
      xA, xb, xlr + 256, 384, batch_ids, gsum, gsq, invcnt, gn2_w, gn2_b, gn2_ms, N);
  // ---- LSTM x2: 512-thr single-stage blocks, reg prefetch, XCD-swizzled ----
  int npanel = cdiv_(N, 128);
  int lblocks = 64 * cdiv_(npanel, 8);
  lstm_big<DD><<<lblocks, 512, 0, stream>>>(xb, wl1b, bsum1, h1, N);
  lstm_big<LSTMH><<<lblocks, 512, 0, stream>>>(h1, wl2b, bsum2, h2, N);
  // ---- LN + mean pool + FC ----
  ln_pool2<<<cdiv_(N, 32), 256, 0, stream>>>(h2, batch_ids, ln_w, ln_b, invcnt, pooled, N);
  fc_lsm<<<G, 64, 0, stream>>>(pooled, fc_W, fc_b, out);
}

// Round 9
// 476.693 us; speedup vs baseline: 1.4728x; 1.0215x over previous
//
#include <hip/hip_runtime.h>
#include <cstdint>
#include <cstddef>

#define DD 128
#define LSTMH 256
#define ZG 1024

typedef __attribute__((ext_vector_type(8))) short short8v;
typedef __attribute__((ext_vector_type(4))) float float4v;

static inline int cdiv_(int a, int b) { return (a + b - 1) / b; }

__device__ __forceinline__ float sigm_(float x) { return 1.f / (1.f + __expf(-x)); }
__device__ __forceinline__ float tanh_(float x) {
  float e = __expf(-2.f * fabsf(x));
  float r = (1.f - e) / (1.f + e);
  return copysignf(r, x);
}

__device__ __forceinline__ unsigned short f2bf(float f) {
  uint32_t u = __float_as_uint(f);
  u += 0x7fffu + ((u >> 16) & 1u);
  return (unsigned short)(u >> 16);
}
__device__ __forceinline__ uint32_t bfpack(float a, float b) {
  return (uint32_t)f2bf(a) | ((uint32_t)f2bf(b) << 16);
}
__device__ __forceinline__ float bflo(uint32_t u) { return __uint_as_float(u << 16); }
__device__ __forceinline__ float bfhi(uint32_t u) { return __uint_as_float(u & 0xffff0000u); }

// ------- fused prep: 5 transposes + 2 casts + biases + deg/cursor/pooled zero, 1 launch --
__global__ void prep_all(const float* __restrict__ g1Wl, const float* __restrict__ g1Wr,
                         const float* __restrict__ g2Wl, const float* __restrict__ g2Wr,
                         const float* __restrict__ Wres, const float* __restrict__ l1Wih,
                         const float* __restrict__ l2Wih, const float* __restrict__ g1bl,
                         const float* __restrict__ g1br, const float* __restrict__ g2bl,
                         const float* __restrict__ g2br, const float* __restrict__ bres,
                         const float* __restrict__ l1bih, const float* __restrict__ l1bhh,
                         const float* __restrict__ l2bih, const float* __restrict__ l2bhh,
                         unsigned short* __restrict__ wcat1, unsigned short* __restrict__ wcat2,
                         unsigned short* __restrict__ wl1b, unsigned short* __restrict__ wl2b,
                         float* __restrict__ bcat1, float* __restrict__ bcat2,
                         float* __restrict__ bsum1, float* __restrict__ bsum2,
                         int* __restrict__ deg, int* __restrict__ cursor,
                         float* __restrict__ pooled, int Nn) {
  int i = blockIdx.x * 256 + threadIdx.x;
  if (i < 81920) {  // five 128x128 transposes -> [M][K] bf16
    int seg = i >> 14, j = i & 16383;
    int m = j >> 7, k = j & 127;
    const float* src = (seg == 0) ? g1Wl : (seg == 1) ? g1Wr : (seg == 2) ? g2Wl
                       : (seg == 3) ? g2Wr : Wres;
    unsigned short* dst = (seg == 0) ? wcat1 : (seg == 1) ? wcat1 + 16384
                          : (seg == 2) ? wcat2 : (seg == 3) ? wcat2 + 16384 : wcat2 + 32768;
    dst[j] = f2bf(src[k * 128 + m]);
    return;
  }
  i -= 81920;
  if (i < 131072) { wl1b[i] = f2bf(l1Wih[i]); return; }
  i -= 131072;
  if (i < 262144) { wl2b[i] = f2bf(l2Wih[i]); return; }
  i -= 262144;
  if (i < 256) { bcat1[i] = (i < 128) ? g1bl[i] : g1br[i - 128]; return; }
  i -= 256;
  if (i < 384) {
    bcat2[i] = (i < 128) ? g2bl[i] : (i < 256 ? g2br[i - 128] : bres[i - 256]);
    return;
  }
  i -= 384;
  if (i < 1024) { bsum1[i] = l1bih[i] + l1bhh[i]; return; }
  i -= 1024;
  if (i < 1024) { bsum2[i] = l2bih[i] + l2bhh[i]; return; }
  i -= 1024;
  if (i < Nn) { deg[i] = 0; return; }
  i -= Nn;
  if (i < Nn) { cursor[i] = 0; return; }
  i -= Nn;
  if (i < 16384) { pooled[i] = 0.f; return; }
}

// ---------------- embedding + W_in GEMV: 128 nodes/block, W in registers ----------------
__global__ __launch_bounds__(256) void embed_in2(
    const int* __restrict__ labels, const int* __restrict__ types,
    const float* __restrict__ nf, const float* __restrict__ embL,
    const float* __restrict__ embT, const float* __restrict__ W,
    const float* __restrict__ b, unsigned short* __restrict__ x, int N) {
  __shared__ float f[128][34];
  int base = blockIdx.x * 128;
  int tid = threadIdx.x;
  int ch = tid & 127, half = tid >> 7;
  float wr[33];
#pragma unroll
  for (int k = 0; k < 33; ++k) wr[k] = W[k * 128 + ch];
  float bb = b[ch];
  int nmax = N - base < 128 ? N - base : 128;
  for (int e = tid; e < nmax * 32; e += 256) {
    int n = e >> 5, k = e & 31;
    f[n][k] = (k < 16) ? embL[labels[base + n] * 16 + k] : embT[types[base + n] * 16 + (k - 16)];
  }
  for (int n = tid; n < nmax; n += 256) f[n][32] = nf[base + n];
  __syncthreads();
  for (int n = half; n < nmax; n += 2) {
    float acc = bb;
#pragma unroll
    for (int k = 0; k < 33; ++k) acc = fmaf(f[n][k], wr[k], acc);
    x[(size_t)(base + n) * 128 + ch] = f2bf(acc);
  }
}

// ---------------- CSR build ----------------
__global__ void count_deg(const int* __restrict__ ei, int* __restrict__ deg, int E_, int N_) {
  int i = blockIdx.x * 256 + threadIdx.x;
  if (i < E_) atomicAdd(&deg[ei[E_ + i]], 1);
  else if (i < E_ + N_) atomicAdd(&deg[i - E_], 1);
}

__global__ __launch_bounds__(256) void scan1(const int* __restrict__ deg, int* __restrict__ offs,
                                             int* __restrict__ partials, int N_) {
  __shared__ int buf[2][256];
  int tid = threadIdx.x;
  int i = blockIdx.x * 256 + tid;
  int v = (i < N_) ? deg[i] : 0;
  buf[0][tid] = v;
  __syncthreads();
  int cur = 0;
#pragma unroll
  for (int d = 1; d < 256; d <<= 1) {
    int xv = buf[cur][tid];
    if (tid >= d) xv += buf[cur][tid - d];
    buf[cur ^ 1][tid] = xv;
    cur ^= 1;
    __syncthreads();
  }
  int incl = buf[cur][tid];
  if (i < N_) offs[i] = incl - v;
  if (tid == 255) partials[blockIdx.x] = incl;
}

__global__ __launch_bounds__(256) void scan2(int* __restrict__ partials, int* __restrict__ offs,
                                             int nb, int N_) {
  __shared__ int buf[2][256];
  int tid = threadIdx.x;
  int v = (tid < nb) ? partials[tid] : 0;
  buf[0][tid] = v;
  __syncthreads();
  int cur = 0;
#pragma unroll
  for (int d = 1; d < 256; d <<= 1) {
    int xv = buf[cur][tid];
    if (tid >= d) xv += buf[cur][tid - d];
    buf[cur ^ 1][tid] = xv;
    cur ^= 1;
    __syncthreads();
  }
  int incl = buf[cur][tid];
  if (tid < nb) partials[tid] = incl - v;
  if (tid == 255) offs[N_] = incl;
}

__global__ void scan3(int* __restrict__ offs, const int* __restrict__ partials, int N_) {
  int i = blockIdx.x * 256 + threadIdx.x;
  if (i < N_) offs[i] += partials[blockIdx.x];
}

__global__ void fill_csr(const int* __restrict__ ei, const int* __restrict__ offs,
                         int* __restrict__ cursor, int* __restrict__ csr, int E_, int N_) {
  int i = blockIdx.x * 256 + threadIdx.x;
  int s, d;
  if (i < E_) { s = ei[i]; d = ei[E_ + i]; }
  else if (i < E_ + N_) { s = d = i - E_; }
  else return;
  int pos = offs[d] + atomicAdd(&cursor[d], 1);
  csr[pos] = s;
}

// ---------------- graph ranges ----------------
__global__ void graph_ranges(const int* __restrict__ bids, int* __restrict__ gstart,
                             float* __restrict__ invcnt, int N_, int G_) {
  int t = threadIdx.x;
  if (t <= G_) {
    int lo = 0, hi = N_;
    while (lo < hi) { int mid = (lo + hi) >> 1; if (bids[mid] < t) lo = mid + 1; else hi = mid; }
    gstart[t] = lo;
  }
  __syncthreads();
  if (t < G_) {
    int c = gstart[t + 1] - gstart[t];
    invcnt[t] = (c > 0) ? 1.f / (float)c : 0.f;
  }
}

// ---------------- bf16 MFMA GEMM: C[M,Ncols] bf16 = A[M,K]bf16 @ B'[Ncols,K]^T + bias
__global__ __launch_bounds__(256) void gemm_bf16(
    const unsigned short* __restrict__ A, const unsigned short* __restrict__ Bp,
    const float* __restrict__ bias, unsigned short* __restrict__ C, int M, int K, int Ncols) {
  __shared__ unsigned short As[128 * 40];
  __shared__ unsigned short Bs[128 * 40];
  int tid = threadIdx.x;
  int lane = tid & 63;
  int wid = tid >> 6;
  int rowBase = blockIdx.y * 128, colBase = blockIdx.x * 128;
  int wr = (wid >> 1) * 64, wc = (wid & 1) * 64;
  int fr = lane & 15, fg = lane >> 4;
  float4v acc[4][4];
#pragma unroll
  for (int i = 0; i < 4; ++i)
#pragma unroll
    for (int j = 0; j < 4; ++j) acc[i][j] = (float4v){0.f, 0.f, 0.f, 0.f};

  int sr = tid >> 2;
  int sc = tid & 3;
  int off_lo = (sc < 2) ? 32 * sc : 32 * sc - 56;

  for (int k0 = 0; k0 < K; k0 += 32) {
#pragma unroll
    for (int it = 0; it < 2; ++it) {
      int r = it * 64 + sr;
      uint4 va = make_uint4(0u, 0u, 0u, 0u);
      if (rowBase + r < M)
        va = *(const uint4*)(A + (size_t)(rowBase + r) * K + k0 + sc * 8);
      char* arow = (char*)(As + r * 40);
      *(uint2*)(arow + off_lo) = make_uint2(va.x, va.y);
      *(uint2*)(arow + off_lo + 16) = make_uint2(va.z, va.w);
      uint4 vb = *(const uint4*)(Bp + (size_t)(colBase + r) * K + k0 + sc * 8);
      char* brow = (char*)(Bs + r * 40);
      *(uint2*)(brow + off_lo) = make_uint2(vb.x, vb.y);
      *(uint2*)(brow + off_lo + 16) = make_uint2(vb.z, vb.w);
    }
    __syncthreads();
    short8v af[4], bfv[4];
#pragma unroll
    for (int i = 0; i < 4; ++i)
      af[i] = *(const short8v*)((const char*)As + (wr + 16 * i + fr) * 80 + fg * 16);
#pragma unroll
    for (int j = 0; j < 4; ++j)
      bfv[j] = *(const short8v*)((const char*)Bs + (wc + 16 * j + fr) * 80 + fg * 16);
#pragma unroll
    for (int i = 0; i < 4; ++i)
#pragma unroll
      for (int j = 0; j < 4; ++j)
        acc[i][j] = __builtin_amdgcn_mfma_f32_16x16x32_bf16(af[i], bfv[j], acc[i][j], 0, 0, 0);
    __syncthreads();
  }
#pragma unroll
  for (int j = 0; j < 4; ++j) {
    int gc = colBase + wc + 16 * j + fr;
    float bv = bias[gc];
#pragma unroll
    for (int i = 0; i < 4; ++i) {
      int gr0 = rowBase + wr + 16 * i + fg * 4;
#pragma unroll
      for (int rg = 0; rg < 4; ++rg) {
        int gr = gr0 + rg;
        if (gr < M) C[(size_t)gr * Ncols + gc] = f2bf(acc[i][j][rg] + bv);
      }
    }
  }
}

// ---------------- GATv2 aggregation: 1 wave/node, 4 edges in flight, per-head softmax ----
// Also zeroes gsum+gsq (64KB) in the first 16 blocks (safe: prior layer's gn_apply done).
__global__ __launch_bounds__(256) void gat_agg(
    const unsigned short* __restrict__ xlr, int stride,
    const int* __restrict__ csr, const int* __restrict__ offs,
    const float* __restrict__ att, const float* __restrict__ bias,
    unsigned short* __restrict__ out, float* __restrict__ gz, int N) {
  int zt = blockIdx.x * 256 + threadIdx.x;
  if (zt < 4096) *(float4*)(gz + zt * 4) = make_float4(0.f, 0.f, 0.f, 0.f);
  int wid = zt >> 6;
  if (wid >= N) return;
  int lane = threadIdx.x & 63;
  int q = lane >> 4, ql = lane & 15;   // edge slot, channel group (8 ch each)
  float4 aA = *(const float4*)&att[ql * 8];
  float4 aB = *(const float4*)&att[ql * 8 + 4];
  uint4 ur = *(const uint4*)(xlr + (size_t)wid * stride + 128 + ql * 8);
  float r0 = bflo(ur.x), r1 = bfhi(ur.x), r2 = bflo(ur.y), r3 = bfhi(ur.y);
  float r4 = bflo(ur.z), r5 = bfhi(ur.z), r6 = bflo(ur.w), r7 = bfhi(ur.w);
  float m = -1e30f, L = 0.f;
  float s0 = 0.f, s1 = 0.f, s2 = 0.f, s3 = 0.f, s4 = 0.f, s5 = 0.f, s6 = 0.f, s7 = 0.f;
  int js = offs[wid], je = offs[wid + 1];
  for (int j = js + q; j < je; j += 4) {
    int s = csr[j];
    uint4 u = *(const uint4*)(xlr + (size_t)s * stride + ql * 8);
    float x0 = bflo(u.x), x1 = bfhi(u.x), x2 = bflo(u.y), x3 = bfhi(u.y);
    float x4 = bflo(u.z), x5 = bfhi(u.z), x6 = bflo(u.w), x7 = bfhi(u.w);
    float v0 = fmaxf(r0 + x0, 0.2f * (r0 + x0));
    float v1 = fmaxf(r1 + x1, 0.2f * (r1 + x1));
    float v2 = fmaxf(r2 + x2, 0.2f * (r2 + x2));
    float v3 = fmaxf(r3 + x3, 0.2f * (r3 + x3));
    float v4 = fmaxf(r4 + x4, 0.2f * (r4 + x4));
    float v5 = fmaxf(r5 + x5, 0.2f * (r5 + x5));
    float v6 = fmaxf(r6 + x6, 0.2f * (r6 + x6));
    float v7 = fmaxf(r7 + x7, 0.2f * (r7 + x7));
    float p = aA.x * v0 + aA.y * v1 + aA.z * v2 + aA.w * v3 +
              aB.x * v4 + aB.y * v5 + aB.z * v6 + aB.w * v7;
    p += __shfl_xor(p, 1); p += __shfl_xor(p, 2);   // per-head reduce (4 lanes = 32 ch)
    float mn = fmaxf(m, p);
    float ea = __expf(p - mn);
    float es = __expf(m - mn);
    L = L * es + ea;
    s0 = s0 * es + ea * x0; s1 = s1 * es + ea * x1;
    s2 = s2 * es + ea * x2; s3 = s3 * es + ea * x3;
    s4 = s4 * es + ea * x4; s5 = s5 * es + ea * x5;
    s6 = s6 * es + ea * x6; s7 = s7 * es + ea * x7;
    m = mn;
  }
  // merge the 4 edge-slot states (per head/channel-slice)
#pragma unroll
  for (int d = 16; d <= 32; d <<= 1) {
    float mo = __shfl_xor(m, d), Lo = __shfl_xor(L, d);
    float t0 = __shfl_xor(s0, d), t1 = __shfl_xor(s1, d);
    float t2 = __shfl_xor(s2, d), t3 = __shfl_xor(s3, d);
    float t4 = __shfl_xor(s4, d), t5 = __shfl_xor(s5, d);
    float t6 = __shfl_xor(s6, d), t7 = __shfl_xor(s7, d);
    float mn = fmaxf(m, mo);
    float e0 = __expf(m - mn), e1 = __expf(mo - mn);
    L = L * e0 + Lo * e1;
    s0 = s0 * e0 + t0 * e1; s1 = s1 * e0 + t1 * e1;
    s2 = s2 * e0 + t2 * e1; s3 = s3 * e0 + t3 * e1;
    s4 = s4 * e0 + t4 * e1; s5 = s5 * e0 + t5 * e1;
    s6 = s6 * e0 + t6 * e1; s7 = s7 * e0 + t7 * e1;
    m = mn;
  }
  if (q == 0) {
    float inv = 1.f / L;
    float4 bA = *(const float4*)&bias[ql * 8];
    float4 bB = *(const float4*)&bias[ql * 8 + 4];
    uint4 ov;
    ov.x = bfpack(s0 * inv + bA.x, s1 * inv + bA.y);
    ov.y = bfpack(s2 * inv + bA.z, s3 * inv + bA.w);
    ov.z = bfpack(s4 * inv + bB.x, s5 * inv + bB.y);
    ov.w = bfpack(s6 * inv + bB.z, s7 * inv + bB.w);
    *(uint4*)(out + (size_t)wid * DD + ql * 8) = ov;
  }
}

// ---------------- GraphNorm stats (bf16 input, uint-vectorized) ----------------
__global__ __launch_bounds__(256) void gn_stats2(const unsigned short* __restrict__ x,
                                                 const int* __restrict__ bids,
                                                 float* __restrict__ gsum,
                                                 float* __restrict__ gsq, int N) {
  int base = blockIdx.x * 128;
  int cp = threadIdx.x & 63;   // channel pair
  int sub = threadIdx.x >> 6;  // row offset 0..3
  int end = base + 128 < N ? base + 128 : N;
  int curg = -1;
  float s0 = 0.f, s1 = 0.f, q0 = 0.f, q1 = 0.f;
  for (int r = base + sub; r < end; r += 4) {
    int g = bids[r];
    if (g != curg) {
      if (curg >= 0) {
        atomicAdd(&gsum[curg * DD + cp * 2], s0);
        atomicAdd(&gsum[curg * DD + cp * 2 + 1], s1);
        atomicAdd(&gsq[curg * DD + cp * 2], q0);
        atomicAdd(&gsq[curg * DD + cp * 2 + 1], q1);
      }
      curg = g; s0 = s1 = q0 = q1 = 0.f;
    }
    uint32_t u = *(const uint32_t*)(x + (size_t)r * DD + cp * 2);
    float v0 = bflo(u), v1 = bfhi(u);
    s0 += v0; q0 += v0 * v0; s1 += v1; q1 += v1 * v1;
  }
  if (curg >= 0) {
    atomicAdd(&gsum[curg * DD + cp * 2], s0);
    atomicAdd(&gsum[curg * DD + cp * 2 + 1], s1);
    atomicAdd(&gsq[curg * DD + cp * 2], q0);
    atomicAdd(&gsq[curg * DD + cp * 2 + 1], q1);
  }
}

// ---------------- GraphNorm apply + ELU (+residual) : bf16 in -> bf16 out --------------
template <bool ADDRES>
__global__ void gn_apply(const unsigned short* __restrict__ xin,
                         unsigned short* __restrict__ xout,
                         const unsigned short* __restrict__ res, int resStride,
                         const int* __restrict__ bids, const float* __restrict__ gsum,
                         const float* __restrict__ gsq, const float* __restrict__ invcnt,
                         const float* __restrict__ w, const float* __restrict__ b,
                         const float* __restrict__ ms, int N) {
  int idx = blockIdx.x * 256 + threadIdx.x;
  if (idx >= N * 64) return;
  int n = idx >> 6, cp = idx & 63;
  int g = bids[n];
  float ic = invcnt[g];
  float2 sm = *(const float2*)&gsum[g * DD + cp * 2];
  float2 sq = *(const float2*)&gsq[g * DD + cp * 2];
  float2 w2 = *(const float2*)&w[cp * 2];
  float2 b2 = *(const float2*)&b[cp * 2];
  float2 m2 = *(const float2*)&ms[cp * 2];
  uint32_t u = *(const uint32_t*)(xin + (size_t)n * DD + cp * 2);
  float mean0 = sm.x * ic, mean1 = sm.y * ic;
  float mm0 = mean0 * m2.x, mm1 = mean1 * m2.y;
  float var0 = sq.x * ic - mm0 * (2.f * mean0 - mm0);
  float var1 = sq.y * ic - mm1 * (2.f * mean1 - mm1);
  float v0 = (bflo(u) - mm0) * rsqrtf(var0 + 1e-5f) * w2.x + b2.x;
  float v1 = (bfhi(u) - mm1) * rsqrtf(var1 + 1e-5f) * w2.y + b2.y;
  if (ADDRES) {
    uint32_t ur = *(const uint32_t*)(res + (size_t)n * resStride + cp * 2);
    v0 += bflo(ur); v1 += bfhi(ur);
  }
  v0 = v0 > 0.f ? v0 : (__expf(v0) - 1.f);
  v1 = v1 > 0.f ? v1 : (__expf(v1) - 1.f);
  *(uint32_t*)(xout + (size_t)n * DD + cp * 2) = bfpack(v0, v1);
}

// ---------------- LSTM step: BK=64 phases, 30.5KB LDS (3 blocks/CU), reg-prefetch --------
// Block: 512 thr (8 waves = 4 row x 2 col), 128 rows x 32 h-channels (96 gate rows i|g|o).
// Per 64-k phase: stage A 128x64 + W 96x64 (136B row stride), 1 barrier pair, 12 MFMA/thr.
// Next phase's loads issued into regs before compute. f-gate dead (c0=0).
// Coalesced H store via LDS transpose. XCD swizzle keeps a panel's 8 col-chunks on 1 XCD.
template <int KD>
__global__ __launch_bounds__(512, 6) void lstm_big(
    const unsigned short* __restrict__ A, const unsigned short* __restrict__ Bp,
    const float* __restrict__ bsum, unsigned short* __restrict__ H, int M) {
  __shared__ __attribute__((aligned(16))) char As_[128 * 136];
  __shared__ __attribute__((aligned(16))) char Ws_[96 * 136];
  const int NPH = KD / 64;
  int npanel = (M + 127) >> 7;
  int b = blockIdx.x;
  int g8 = b & 7, inner = b >> 3;
  int p = g8 + 8 * (inner >> 3);
  int cc = inner & 7;
  if (p >= npanel) return;
  int rowBase = p << 7;
  int ch0 = cc * 32;

  int tid = threadIdx.x;
  int lane = tid & 63;
  int wid = tid >> 6;
  int wr4 = wid >> 1;
  int wc2 = wid & 1;
  int fr = lane & 15, fg = lane >> 4;

  // A staging: 2 16B units/thread (1024 units = 128 rows x 8)
  int aldst[2], agoff[2];
  bool aval[2];
#pragma unroll
  for (int q = 0; q < 2; ++q) {
    int e = q * 512 + tid;
    int r = e >> 3, kk = e & 7;
    int c = kk >> 2, sc = kk & 3;
    int olo = (sc < 2) ? 32 * sc : 32 * sc - 56;
    aldst[q] = r * 136 + c * 64 + olo;
    aval[q] = (rowBase + r) < M;
    agoff[q] = (rowBase + r) * KD + c * 32 + sc * 8;
  }
  // W staging: 768 units; q=0 all threads, q=1 tid<256
  bool wact1 = tid < 256;
  int wldst[2], wgoff[2];
#pragma unroll
  for (int q = 0; q < 2; ++q) {
    int e = q * 512 + tid;
    int wrow = e >> 3, kk = e & 7;
    int c = kk >> 2, sc = kk & 3;
    int half = wrow >= 48 ? 1 : 0;
    int r3 = wrow - 48 * half;
    int grp = r3 >> 4;
    int goff = (grp == 0) ? 0 : (grp == 1 ? 512 : 768);
    int grow = goff + ch0 + 16 * half + (r3 & 15);
    int olo = (sc < 2) ? 32 * sc : 32 * sc - 56;
    wldst[q] = wrow * 136 + c * 64 + olo;
    wgoff[q] = grow * KD + c * 32 + sc * 8;
  }

  float4v acc[2][3];
#pragma unroll
  for (int i = 0; i < 2; ++i)
#pragma unroll
    for (int j = 0; j < 3; ++j) acc[i][j] = (float4v){0.f, 0.f, 0.f, 0.f};

  uint4 va[2], vw[2];
#pragma unroll
  for (int q = 0; q < 2; ++q) {
    va[q] = make_uint4(0u, 0u, 0u, 0u);
    if (aval[q]) va[q] = *(const uint4*)(A + agoff[q]);
  }
  vw[0] = *(const uint4*)(Bp + wgoff[0]);
  if (wact1) vw[1] = *(const uint4*)(Bp + wgoff[1]);

#pragma unroll
  for (int ph = 0; ph < NPH; ++ph) {
    if (ph) __syncthreads();
#pragma unroll
    for (int q = 0; q < 2; ++q) {
      char* dst = As_ + aldst[q];
      *(uint2*)(dst) = make_uint2(va[q].x, va[q].y);
      *(uint2*)(dst + 16) = make_uint2(va[q].z, va[q].w);
    }
    {
      char* dst = Ws_ + wldst[0];
      *(uint2*)(dst) = make_uint2(vw[0].x, vw[0].y);
      *(uint2*)(dst + 16) = make_uint2(vw[0].z, vw[0].w);
    }
    if (wact1) {
      char* dst = Ws_ + wldst[1];
      *(uint2*)(dst) = make_uint2(vw[1].x, vw[1].y);
      *(uint2*)(dst + 16) = make_uint2(vw[1].z, vw[1].w);
    }
    __syncthreads();
    if (ph + 1 < NPH) {
      int koff = (ph + 1) * 64;
#pragma unroll
      for (int q = 0; q < 2; ++q) {
        va[q] = make_uint4(0u, 0u, 0u, 0u);
        if (aval[q]) va[q] = *(const uint4*)(A + agoff[q] + koff);
      }
      vw[0] = *(const uint4*)(Bp + wgoff[0] + koff);
      if (wact1) vw[1] = *(const uint4*)(Bp + wgoff[1] + koff);
    }
    __builtin_amdgcn_s_setprio(1);
#pragma unroll
    for (int c = 0; c < 2; ++c) {
      short8v af[2], bf[3];
#pragma unroll
      for (int i = 0; i < 2; ++i)
        af[i] = *(const short8v*)(As_ + (32 * wr4 + 16 * i + fr) * 136 + c * 64 + fg * 16);
#pragma unroll
      for (int j = 0; j < 3; ++j)
        bf[j] = *(const short8v*)(Ws_ + (48 * wc2 + 16 * j + fr) * 136 + c * 64 + fg * 16);
#pragma unroll
      for (int i = 0; i < 2; ++i)
#pragma unroll
        for (int j = 0; j < 3; ++j)
          acc[i][j] = __builtin_amdgcn_mfma_f32_16x16x32_bf16(af[i], bf[j], acc[i][j], 0, 0, 0);
    }
    __builtin_amdgcn_s_setprio(0);
  }
  // epilogue: lane owns channel ch for 8 rows; activations in registers
  int chL = 16 * wc2 + fr;
  int ch = ch0 + chL;
  float bi = bsum[ch], bg = bsum[512 + ch], bo = bsum[768 + ch];
  unsigned short hv[8];
#pragma unroll
  for (int i = 0; i < 2; ++i) {
#pragma unroll
    for (int rg = 0; rg < 4; ++rg) {
      float iv = acc[i][0][rg] + bi;
      float gv = acc[i][1][rg] + bg;
      float ov = acc[i][2][rg] + bo;
      float c = sigm_(iv) * tanh_(gv);
      hv[i * 4 + rg] = f2bf(sigm_(ov) * tanh_(c));
    }
  }
  __syncthreads();
  unsigned short* Hs = (unsigned short*)As_;  // [128][40] = 10240B <= 17408B
#pragma unroll
  for (int i = 0; i < 2; ++i) {
#pragma unroll
    for (int rg = 0; rg < 4; ++rg) {
      int row = 32 * wr4 + 16 * i + 4 * fg + rg;
      Hs[row * 40 + chL] = hv[i * 4 + rg];
    }
  }
  __syncthreads();
  {
    int row = tid >> 2, seg = tid & 3;
    if (rowBase + row < M) {
      uint4 v = *(const uint4*)(Hs + row * 40 + seg * 8);
      *(uint4*)(H + (size_t)(rowBase + row) * LSTMH + ch0 + seg * 8) = v;
    }
  }
}

// ---------------- LayerNorm + mean pool: 1 wave per 8 rows, register pooling ----------
__global__ __launch_bounds__(256) void ln_pool2(
    const unsigned short* __restrict__ h2, const int* __restrict__ bids,
    const float* __restrict__ lnw, const float* __restrict__ lnb,
    const float* __restrict__ invcnt, float* __restrict__ pooled, int N) {
  int wave = (blockIdx.x * 256 + threadIdx.x) >> 6;
  int lane = threadIdx.x & 63;
  int r0 = wave * 8;
  if (r0 >= N) return;
  float4 w4 = *(const float4*)&lnw[lane * 4];
  float4 b4 = *(const float4*)&lnb[lane * 4];
  float p0 = 0.f, p1 = 0.f, p2 = 0.f, p3 = 0.f;
  int curg = bids[r0];
  int rend = r0 + 8 < N ? r0 + 8 : N;
  for (int r = r0; r < rend; ++r) {
    int g = bids[r];
    if (g != curg) {
      float ic = invcnt[curg];
      atomicAdd(&pooled[curg * LSTMH + lane * 4 + 0], p0 * ic);
      atomicAdd(&pooled[curg * LSTMH + lane * 4 + 1], p1 * ic);
      atomicAdd(&pooled[curg * LSTMH + lane * 4 + 2], p2 * ic);
      atomicAdd(&pooled[curg * LSTMH + lane * 4 + 3], p3 * ic);
      p0 = p1 = p2 = p3 = 0.f;
      curg = g;
    }
    uint2 u = *(const uint2*)(h2 + (size_t)r * LSTMH + lane * 4);
    float v0 = bflo(u.x), v1 = bfhi(u.x), v2 = bflo(u.y), v3 = bfhi(u.y);
    float s = v0 + v1 + v2 + v3;
    float q = v0 * v0 + v1 * v1 + v2 * v2 + v3 * v3;
#pragma unroll
    for (int d = 1; d < 64; d <<= 1) { s += __shfl_xor(s, d); q += __shfl_xor(q, d); }
    float mu = s * (1.f / 256.f);
    float var = q * (1.f / 256.f) - mu * mu;
    float rs = rsqrtf(var + 1e-5f);
    p0 += w4.x * (v0 - mu) * rs + b4.x;
    p1 += w4.y * (v1 - mu) * rs + b4.y;
    p2 += w4.z * (v2 - mu) * rs + b4.z;
    p3 += w4.w * (v3 - mu) * rs + b4.w;
  }
  float ic = invcnt[curg];
  atomicAdd(&pooled[curg * LSTMH + lane * 4 + 0], p0 * ic);
  atomicAdd(&pooled[curg * LSTMH + lane * 4 + 1], p1 * ic);
  atomicAdd(&pooled[curg * LSTMH + lane * 4 + 2], p2 * ic);
  atomicAdd(&pooled[curg * LSTMH + lane * 4 + 3], p3 * ic);
}

// ---------------- FC + log_softmax ----------------
__global__ __launch_bounds__(64) void fc_lsm(const float* __restrict__ pooled,
                                             const float* __restrict__ W,
                                             const float* __restrict__ b, float* __restrict__ out) {
  int g = blockIdx.x;
  int t = threadIdx.x;
  float l0 = 0.f, l1 = 0.f, l2 = 0.f, l3 = 0.f;
  for (int k = t; k < LSTMH; k += 64) {
    float p = pooled[g * LSTMH + k];
    l0 += p * W[k * 4 + 0];
    l1 += p * W[k * 4 + 1];
    l2 += p * W[k * 4 + 2];
    l3 += p * W[k * 4 + 3];
  }
#pragma unroll
  for (int d = 1; d < 64; d <<= 1) {
    l0 += __shfl_xor(l0, d); l1 += __shfl_xor(l1, d);
    l2 += __shfl_xor(l2, d); l3 += __shfl_xor(l3, d);
  }
  if (t == 0) {
    float z[4] = {l0 + b[0], l1 + b[1], l2 + b[2], l3 + b[3]};
    float mx = fmaxf(fmaxf(z[0], z[1]), fmaxf(z[2], z[3]));
    float sum = __expf(z[0] - mx) + __expf(z[1] - mx) + __expf(z[2] - mx) + __expf(z[3] - mx);
    float ls = logf(sum);
#pragma unroll
    for (int o = 0; o < 4; ++o) out[g * 4 + o] = z[o] - mx - ls;
  }
}

// ---------------- host launch ----------------
extern "C" void kernel_launch(void* const* d_in, const int* in_sizes, int n_in,
                              void* d_out, int out_size, void* d_ws, size_t ws_size,
                              hipStream_t stream) {
  const int* node_labels = (const int*)d_in[0];
  const int* node_types = (const int*)d_in[1];
  const float* node_feat = (const float*)d_in[2];
  const int* edge_index = (const int*)d_in[3];
  const int* batch_ids = (const int*)d_in[4];
  const float* emb_label = (const float*)d_in[5];
  const float* emb_type = (const float*)d_in[6];
  const float* W_in = (const float*)d_in[7];
  const float* b_in = (const float*)d_in[8];
  const float* g1_Wl = (const float*)d_in[9];
  const float* g1_bl = (const float*)d_in[10];
  const float* g1_Wr = (const float*)d_in[11];
  const float* g1_br = (const float*)d_in[12];
  const float* g1_att = (const float*)d_in[13];
  const float* g1_bias = (const float*)d_in[14];
  const float* gn1_w = (const float*)d_in[15];
  const float* gn1_b = (const float*)d_in[16];
  const float* gn1_ms = (const float*)d_in[17];
  const float* g2_Wl = (const float*)d_in[18];
  const float* g2_bl = (const float*)d_in[19];
  const float* g2_Wr = (const float*)d_in[20];
  const float* g2_br = (const float*)d_in[21];
  const float* g2_att = (const float*)d_in[22];
  const float* g2_bias = (const float*)d_in[23];
  const float* gn2_w = (const float*)d_in[24];
  const float* gn2_b = (const float*)d_in[25];
  const float* gn2_ms = (const float*)d_in[26];
  const float* W_res = (const float*)d_in[27];
  const float* b_res = (const float*)d_in[28];
  const float* l1_Wih = (const float*)d_in[29];
  const float* l1_bih = (const float*)d_in[31];
  const float* l1_bhh = (const float*)d_in[32];
  const float* l2_Wih = (const float*)d_in[33];
  const float* l2_bih = (const float*)d_in[35];
  const float* l2_bhh = (const float*)d_in[36];
  const float* ln_w = (const float*)d_in[37];
  const float* ln_b = (const float*)d_in[38];
  const float* fc_W = (const float*)d_in[39];
  const float* fc_b = (const float*)d_in[40];
  float* out = (float*)d_out;

  const int N = in_sizes[0];
  const int E = in_sizes[3] / 2;
  const int G = out_size / 4;
  const int ET = E + N;

  char* wsb = (char*)d_ws;
  size_t off = 0;
  auto alloc = [&](size_t bytes) -> void* {
    void* p = (void*)(wsb + off);
    off = (off + bytes + 255) & ~(size_t)255;
    return p;
  };
  unsigned short* xA = (unsigned short*)alloc((size_t)N * 512);       // gat out bf16; later h2
  unsigned short* xb = (unsigned short*)alloc((size_t)N * DD * 2);    // bf16 x / x1 / x2
  unsigned short* xlr = (unsigned short*)alloc((size_t)N * 384 * 2);  // xl|xr(|res); later h1
  int* deg = (int*)alloc((size_t)N * 4);
  int* offs = (int*)alloc((size_t)(N + 1) * 4);
  int* cursor = (int*)alloc((size_t)N * 4);
  int* partials = (int*)alloc(1024);
  int* csr = (int*)alloc((size_t)ET * 4);
  int* gstart = (int*)alloc((size_t)(G + 1) * 4);
  float* invcnt = (float*)alloc((size_t)G * 4);
  float* gsum = (float*)alloc((size_t)G * DD * 4);   // contiguous with gsq (32KB each)
  float* gsq = (float*)alloc((size_t)G * DD * 4);
  float* pooled = (float*)alloc((size_t)G * LSTMH * 4);
  float* bcat1 = (float*)alloc(256 * 4);
  float* bcat2 = (float*)alloc(384 * 4);
  float* bsum1 = (float*)alloc(ZG * 4);
  float* bsum2 = (float*)alloc(ZG * 4);
  unsigned short* wcat1 = (unsigned short*)alloc((size_t)256 * DD * 2);
  unsigned short* wcat2 = (unsigned short*)alloc((size_t)384 * DD * 2);
  unsigned short* wl1b = (unsigned short*)alloc((size_t)ZG * DD * 2);
  unsigned short* wl2b = (unsigned short*)alloc((size_t)ZG * LSTMH * 2);
  (void)ws_size; (void)n_in;

  unsigned short* h1 = xlr;   // [N][256] bf16, written after xlr dead
  unsigned short* h2 = xA;    // [N][256] bf16, written after xA dead

  int prepTotal = 477824 + 2 * N + 16384;
  prep_all<<<cdiv_(prepTotal, 256), 256, 0, stream>>>(
      g1_Wl, g1_Wr, g2_Wl, g2_Wr, W_res, l1_Wih, l2_Wih,
      g1_bl, g1_br, g2_bl, g2_br, b_res, l1_bih, l1_bhh, l2_bih, l2_bhh,
      wcat1, wcat2, wl1b, wl2b, bcat1, bcat2, bsum1, bsum2,
      deg, cursor, pooled, N);
  graph_ranges<<<1, 128, 0, stream>>>(batch_ids, gstart, invcnt, N, G);
  embed_in2<<<cdiv_(N, 128), 256, 0, stream>>>(node_labels, node_types, node_feat, emb_label,
                                               emb_type, W_in, b_in, xb, N);

  // CSR by dst
  count_deg<<<cdiv_(ET, 256), 256, 0, stream>>>(edge_index, deg, E, N);
  int nb1 = cdiv_(N, 256);
  scan1<<<nb1, 256, 0, stream>>>(deg, offs, partials, N);
  scan2<<<1, 256, 0, stream>>>(partials, offs, nb1, N);
  scan3<<<nb1, 256, 0, stream>>>(offs, partials, N);
  fill_csr<<<cdiv_(ET, 256), 256, 0, stream>>>(edge_index, offs, cursor, csr, E, N);

  int mb = cdiv_(N, 128);
  // ---- GAT layer 1: [xl|xr] in one GEMM ----
  gemm_bf16<<<dim3(2, mb), 256, 0, stream>>>(xb, wcat1, bcat1, xlr, N, DD, 256);
  gat_agg<<<cdiv_(N, 4), 256, 0, stream>>>(xlr, 256, csr, offs, g1_att, g1_bias, xA, gsum, N);
  gn_stats2<<<cdiv_(N, 128), 256, 0, stream>>>(xA, batch_ids, gsum, gsq, N);
  gn_apply<false><<<cdiv_(N * 64, 256), 256, 0, stream>>>(
      xA, xb, nullptr, 0, batch_ids, gsum, gsq, invcnt, gn1_w, gn1_b, gn1_ms, N);
  // ---- GAT layer 2: [xl|xr|res] in one GEMM ----
  gemm_bf16<<<dim3(3, mb), 256, 0, stream>>>(xb, wcat2, bcat2, xlr, N, DD, 384);
  gat_agg<<<cdiv_(N, 4), 256, 0, stream>>>(xlr, 384, csr, offs, g2_att, g2_bias, xA, gsum, N);
  gn_stats2<<<cdiv_(N, 128), 256, 0, stream>>>(xA, batch_ids, gsum, gsq, N);
  gn_apply<true><<<cdiv_(N * 64, 256), 256, 0, stream>>>(
      xA, xb, xlr + 256, 384, batch_ids, gsum, gsq, invcnt, gn2_w, gn2_b, gn2_ms, N);
  // ---- LSTM x2: BK=64 pipelined blocks, 3/CU, XCD-swizzled ----
  int npanel = cdiv_(N, 128);
  int lblocks = 64 * cdiv_(npanel, 8);
  lstm_big<DD><<<lblocks, 512, 0, stream>>>(xb, wl1b, bsum1, h1, N);
  lstm_big<LSTMH><<<lblocks, 512, 0, stream>>>(h1, wl2b, bsum2, h2, N);
  // ---- LN + mean pool + FC ----
  ln_pool2<<<cdiv_(N, 32), 256, 0, stream>>>(h2, batch_ids, ln_w, ln_b, invcnt, pooled, N);
  fc_lsm<<<G, 64, 0, stream>>>(pooled, fc_W, fc_b, out);
}